// Round 8
// baseline (490.054 us; speedup 1.0000x reference)
//
#include <hip/hip_runtime.h>

#define NUC 8.0e-4f   // MIU/(U*L)

typedef __attribute__((ext_vector_type(8))) short   bf16x8;
typedef __attribute__((ext_vector_type(8))) unsigned short u16x8;
typedef __attribute__((ext_vector_type(4))) float   f32x4;

struct KP {
  const float *W0,*b0,*W1,*b1,*W2,*b2,*W3,*b3,*W4,*b4,*W5,*b5,*W6,*b6;
  const float *bc1,*bc2,*bc3,*bc4,*bc5,*f1,*inp,*real;
  const unsigned short *Wfh,*Wfl;     // frag-ordered bf16 hi/lo W1..W5
  const unsigned short *W6fh,*W6fl;   // frag-ordered bf16 hi/lo W6 (N padded to 16)
  float *wsBC,*wsDA,*wsF;
};

__device__ __forceinline__ float ftanh(float a){
  float e = __expf(2.0f*a);
  return 1.0f - 2.0f/(e + 1.0f);
}
__device__ __forceinline__ void splitf(float v, unsigned short& h, unsigned short& l){
  unsigned int b = __float_as_uint(v);
  h = (unsigned short)(b >> 16);
  float lo = v - __uint_as_float(b & 0xFFFF0000u);
  l = (unsigned short)(__float_as_uint(lo) >> 16);
}
// A byte addr in [80][256] bf16 (row stride 512B), swizzled (reads spread all
// 32 banks; epilogue q-groups land in distinct 16B slots via the row&8 fold).
__device__ __forceinline__ int aswz(int row, int kbyte){
  int f = ((row & 7) ^ ((row & 8) >> 2)) << 4;
  return (row*512 + kbyte) ^ f;
}

// ---------------- prep: split W1..W5 (+W6 padded) into frag-ordered bf16 hi/lo ----------------
// frag order: [ks(8)][ntile][lane(64)][e(8)]; lane=((k&31)>>3)*16+(col&15), e=k&7
__global__ void prep_kernel(const float* W1, const float* W2, const float* W3,
                            const float* W4, const float* W5, const float* W6,
                            unsigned short* Wfh, unsigned short* Wfl,
                            unsigned short* W6fh, unsigned short* W6fl){
  int idx = blockIdx.x*256 + threadIdx.x;      // 0..331775
  if (idx < 327680){
    int li  = idx >> 16;
    int rem = idx & 65535;
    int k   = rem >> 8;
    int col = rem & 255;
    const float* Ws[5] = {W1,W2,W3,W4,W5};
    float v = Ws[li][k*256 + col];
    unsigned short hi, lo;
    splitf(v, hi, lo);
    int ks = k >> 5, kr = k & 31, qq = kr >> 3, e = kr & 7;
    int lane = qq*16 + (col & 15), nt = col >> 4;
    int pos = li*65536 + (ks*16 + nt)*512 + lane*8 + e;
    Wfh[pos] = hi; Wfl[pos] = lo;
  } else {
    int t = idx - 327680;            // 0..4095: [ks(8)][lane(64)][e(8)]
    int ks = t >> 9, lane = (t & 511) >> 3, e = t & 7;
    int k = ks*32 + (lane >> 4)*8 + e;
    int col = lane & 15;
    float v = (col < 4) ? W6[k*4 + col] : 0.f;
    unsigned short hi, lo;
    splitf(v, hi, lo);
    W6fh[t] = hi; W6fl[t] = lo;
  }
}

// ---------------- fused main kernel: 256 thr = 4 waves, M=80, N=256 ----------------
// wave owns 4 N-tiles (acc 5m x 4n); A hi/lo in LDS; W frags from global/L2.
__global__ __launch_bounds__(256,2) void fused_kernel(KP P, int nbP){
  __shared__ unsigned char Abuf[81920];   // hi [80][256]bf16 @0, lo @40960; union'd tail
  const int tid  = threadIdx.x;
  const int lane = tid & 63;
  const int wv   = tid >> 6;          // 0..3
  const int q    = lane >> 4;         // 0..3
  const int lrow = lane & 15;
  const bool isP = (int)blockIdx.x < nbP;
  const int bid  = isP ? (int)blockIdx.x : (int)blockIdx.x - nbP;

  // ---- layer 0 (2 -> 256), write A hi/lo ----
  {
    const int pt = tid >> 4;      // 0..15
    const int cg = tid & 15;      // 16-col group
    const int c0f = cg*16;
    float wz[16], wr[16], bb[16];
    #pragma unroll
    for (int jj=0;jj<16;++jj){ wz[jj]=P.W0[c0f+jj]; wr[jj]=P.W0[256+c0f+jj]; bb[jj]=P.b0[c0f+jj]; }
    if (isP){
      int g = bid*16 + pt;
      float x0 = P.f1[2*g], x1 = P.f1[2*g+1];
      u16x8 hv[5][2], lv[5][2];
      #pragma unroll
      for (int jj=0;jj<16;++jj){
        float a = x0*wz[jj] + x1*wr[jj] + bb[jj];
        float t = ftanh(a), s = 1.f - t*t, cc = -2.f*t*s;
        float o[5] = {t, s*wz[jj], s*wr[jj], cc*wz[jj]*wz[jj], cc*wr[jj]*wr[jj]};
        #pragma unroll
        for (int s_=0;s_<5;++s_){
          unsigned short h_,l_; splitf(o[s_],h_,l_);
          hv[s_][jj>>3][jj&7]=h_; lv[s_][jj>>3][jj&7]=l_;
        }
      }
      #pragma unroll
      for (int s_=0;s_<5;++s_)
        #pragma unroll
        for (int hh=0;hh<2;++hh){
          int byte = aswz(s_*16 + pt, cg*32 + hh*16);
          *(u16x8*)(Abuf + byte)         = hv[s_][hh];
          *(u16x8*)(Abuf + 40960 + byte) = lv[s_][hh];
        }
    } else {
      #pragma unroll
      for (int pp=0;pp<5;++pp){
        int row = pt + 16*pp;
        int g = bid*80 + row;
        float x0 = 0.f, x1 = 0.f;
        if (g < 37000){
          const float* src; int li2;
          if      (g <  1000){ src=P.bc1; li2=g; }
          else if (g <  2000){ src=P.bc2; li2=g-1000; }
          else if (g <  7000){ src=P.bc3; li2=g-2000; }
          else if (g < 12000){ src=P.bc4; li2=g-7000; }
          else if (g < 17000){ src=P.bc5; li2=g-12000; }
          else               { src=P.inp; li2=g-17000; }
          x0 = src[2*li2]; x1 = src[2*li2+1];
        }
        u16x8 hv[2], lv[2];
        #pragma unroll
        for (int jj=0;jj<16;++jj){
          float t = ftanh(x0*wz[jj] + x1*wr[jj] + bb[jj]);
          unsigned short h_,l_; splitf(t,h_,l_);
          hv[jj>>3][jj&7]=h_; lv[jj>>3][jj&7]=l_;
        }
        #pragma unroll
        for (int hh=0;hh<2;++hh){
          int byte = aswz(row, cg*32 + hh*16);
          *(u16x8*)(Abuf + byte)         = hv[hh];
          *(u16x8*)(Abuf + 40960 + byte) = lv[hh];
        }
      }
    }
  }

  // ---- layers 1..5: C = A_hi*W_hi + A_hi*W_lo + A_lo*W_hi ----
  for (int li=0; li<5; ++li){
    const float* bl = (li==0)?P.b1:(li==1)?P.b2:(li==2)?P.b3:(li==3)?P.b4:P.b5;
    const unsigned short* WH = P.Wfh + li*65536;
    const unsigned short* WL = P.Wfl + li*65536;
    f32x4 acc[5][4];
    #pragma unroll
    for (int m=0;m<5;++m)
      #pragma unroll
      for (int n=0;n<4;++n){ acc[m][n][0]=0.f; acc[m][n][1]=0.f; acc[m][n][2]=0.f; acc[m][n][3]=0.f; }
    __syncthreads();   // A of previous layer visible
    #pragma unroll
    for (int ks=0; ks<8; ++ks){
      bf16x8 bh[4], bo[4];
      #pragma unroll
      for (int n=0;n<4;++n){
        int idx = (ks*16 + wv*4 + n)*512 + lane*8;
        bh[n] = *(const bf16x8*)(WH + idx);
        bo[n] = *(const bf16x8*)(WL + idx);
      }
      __builtin_amdgcn_sched_group_barrier(0x020, 8, 0);   // the 8 VMEM reads first
      __builtin_amdgcn_s_setprio(1);
      #pragma unroll
      for (int m=0;m<5;++m){
        int byte = aswz(m*16 + lrow, ks*64 + q*16);
        bf16x8 ah = *(const bf16x8*)(Abuf + byte);
        bf16x8 al = *(const bf16x8*)(Abuf + 40960 + byte);
        #pragma unroll
        for (int n=0;n<4;++n){
          acc[m][n] = __builtin_amdgcn_mfma_f32_16x16x32_bf16(ah, bh[n], acc[m][n], 0,0,0);
          acc[m][n] = __builtin_amdgcn_mfma_f32_16x16x32_bf16(ah, bo[n], acc[m][n], 0,0,0);
          acc[m][n] = __builtin_amdgcn_mfma_f32_16x16x32_bf16(al, bh[n], acc[m][n], 0,0,0);
        }
        // one m-tile's A live at a time: 2 DS reads then 12 MFMAs
        __builtin_amdgcn_sched_group_barrier(0x100, 2, 0);
        __builtin_amdgcn_sched_group_barrier(0x008, 12, 0);
      }
      __builtin_amdgcn_s_setprio(0);
    }
    __syncthreads();   // all A reads done before overwrite
    #pragma unroll
    for (int n=0;n<4;++n){
      int col = (wv*4+n)*16 + lrow;
      float bias = bl[col];
      #pragma unroll
      for (int r=0;r<4;++r){
        int rw = q*4 + r;
        if (isP){
          float a  = acc[0][n][r] + bias;
          float Dz = acc[1][n][r], Dr = acc[2][n][r];
          float Dzz= acc[3][n][r], Drr= acc[4][n][r];
          float t = ftanh(a), s = 1.f - t*t, cc = -2.f*t*s;
          float o[5] = {t, s*Dz, s*Dr, s*Dzz + cc*Dz*Dz, s*Drr + cc*Dr*Dr};
          #pragma unroll
          for (int s_=0;s_<5;++s_){
            int row = s_*16 + rw;
            unsigned short h_,l_; splitf(o[s_],h_,l_);
            *(unsigned short*)(Abuf + aswz(row, col*2)) = h_;
            *(unsigned short*)(Abuf + 40960 + aswz(row, col*2)) = l_;
          }
        } else {
          #pragma unroll
          for (int m=0;m<5;++m){
            int row = m*16 + rw;
            float t = ftanh(acc[m][n][r] + bias);
            unsigned short h_,l_; splitf(t,h_,l_);
            *(unsigned short*)(Abuf + aswz(row, col*2)) = h_;
            *(unsigned short*)(Abuf + 40960 + aswz(row, col*2)) = l_;
          }
        }
      }
    }
  }
  __syncthreads();   // layer-5 A visible

  // ---- layer 6 via MFMA: wave handles m-tiles {wv, wv+4}; N-tile 0 (cols 0..3) ----
  f32x4 a6[2];
  #pragma unroll
  for (int t_=0; t_<2; ++t_){ a6[t_][0]=0.f; a6[t_][1]=0.f; a6[t_][2]=0.f; a6[t_][3]=0.f; }
  #pragma unroll
  for (int t_=0; t_<2; ++t_){
    int mt = wv + t_*4;
    if (mt < 5){
      #pragma unroll
      for (int ks=0; ks<8; ++ks){
        bf16x8 bh = *(const bf16x8*)(P.W6fh + ks*512 + lane*8);
        bf16x8 bo = *(const bf16x8*)(P.W6fl + ks*512 + lane*8);
        int byte = aswz(mt*16 + lrow, ks*64 + q*16);
        bf16x8 ah = *(const bf16x8*)(Abuf + byte);
        bf16x8 al = *(const bf16x8*)(Abuf + 40960 + byte);
        a6[t_] = __builtin_amdgcn_mfma_f32_16x16x32_bf16(ah, bh, a6[t_], 0,0,0);
        a6[t_] = __builtin_amdgcn_mfma_f32_16x16x32_bf16(ah, bo, a6[t_], 0,0,0);
        a6[t_] = __builtin_amdgcn_mfma_f32_16x16x32_bf16(al, bh, a6[t_], 0,0,0);
      }
    }
  }
  __syncthreads();   // ALL layer-6 A reads done before fin/red union overwrite

  float* fin  = (float*)Abuf;            // pde [16][20]; fwd [80][4]
  float* red  = (float*)(Abuf + 4096);
  float* redB = (float*)(Abuf + 6144);

  if (lrow < 4){
    #pragma unroll
    for (int t_=0; t_<2; ++t_){
      int mt = wv + t_*4;
      if (mt < 5){
        #pragma unroll
        for (int r=0;r<4;++r){
          if (isP){
            int pt = q*4 + r;
            float v = a6[t_][r] + ((mt==0) ? P.b6[lrow] : 0.f);
            fin[pt*20 + mt*4 + lrow] = v;
          } else {
            int row = mt*16 + q*4 + r;
            fin[row*4 + lrow] = a6[t_][r] + P.b6[lrow];
          }
        }
      }
    }
  }
  __syncthreads();

  // ---- loss terms ----
  if (isP){
    if (tid < 16){
      const float* F = &fin[tid*20];
      float r = P.f1[2*(bid*16 + tid) + 1];
      float uz=F[0],  us=F[1],  ur=F[2];
      float uz_z=F[4],us_z=F[5],ur_z=F[6],p_z=F[7];
      float uz_r=F[8],us_r=F[9],ur_r=F[10],p_r=F[11];
      float uz_zz=F[12],us_zz=F[13],ur_zz=F[14];
      float uz_rr=F[16],us_rr=F[17],ur_rr=F[18];
      float invr = 1.f/r;
      float eq1 = ur*ur_r + uz*ur_z - us*us*invr + p_r
                - NUC*invr*ur_r - NUC*ur_rr - NUC*ur_zz + NUC*ur*invr*invr;
      float eq2 = ur*us_r + uz*us_z + ur*us*invr
                - NUC*invr*us_r - NUC*us_rr - NUC*us_zz + NUC*us*invr*invr;
      float eq3 = ur*uz_r + uz*uz_z + p_z
                - NUC*invr*uz_r - NUC*uz_rr - NUC*uz_zz;
      float eq4 = ur + r*ur_r + r*uz_z;
      red[tid] = (eq1*eq1 + eq2*eq2 + eq3*eq3 + eq4*eq4) * (1.0f/80000.f);
    }
    __syncthreads();
    if (tid == 0){
      float s = 0.f;
      #pragma unroll
      for (int i=0;i<16;++i) s += red[i];
      P.wsF[bid] = s;
    }
  } else {
    if (tid < 80){
      float dj0 = fin[tid*4+0], dj1 = fin[tid*4+1];
      float dj2 = fin[tid*4+2], dj3 = fin[tid*4+3];
      float bcp = 0.f, dap = 0.f;
      int g = bid*80 + tid;
      if (g < 37000){
        if      (g <  2000){ bcp = (dj0*dj0 + dj1*dj1 + dj2*dj2)*(1.0f/1000.f); }
        else if (g <  7000){ float d1 = dj1 - 1.f;
                             bcp = (dj0*dj0 + d1*d1 + dj2*dj2)*(1.0f/5000.f); }
        else if (g < 12000){ bcp = (dj0*dj0 + dj1*dj1 + dj2*dj2)*(1.0f/5000.f); }
        else if (g < 17000){ bcp = dj3*dj3*(1.0f/5000.f); }
        else { const float* rr = P.real + (g-17000)*4;
               float e0=dj0-rr[0], e1=dj1-rr[1], e2=dj2-rr[2], e3=dj3-rr[3];
               dap = (e0*e0 + e1*e1 + e2*e2 + e3*e3)*(1.0f/80000.f); }
      }
      red[tid] = bcp; redB[tid] = dap;
    }
    __syncthreads();
    if (tid == 0){
      float sA=0.f, sB=0.f;
      #pragma unroll
      for (int i=0;i<80;++i){ sA += red[i]; sB += redB[i]; }
      P.wsBC[bid] = sA; P.wsDA[bid] = sB;
    }
  }
}

// ---------------- final deterministic reduction ----------------
__global__ void reduce_kernel(const float* wsBC, const float* wsDA, const float* wsF,
                              float* out, int nbBC, int nbP){
  __shared__ float sm[256];
  const int tid = threadIdx.x;
  float a;

  a = 0.f; for (int i=tid;i<nbBC;i+=256) a += wsBC[i];
  sm[tid]=a; __syncthreads();
  for (int off=128; off>0; off>>=1){ if (tid<off) sm[tid]+=sm[tid+off]; __syncthreads(); }
  if (tid==0) out[0]=sm[0];
  __syncthreads();

  a = 0.f; for (int i=tid;i<nbBC;i+=256) a += wsDA[i];
  sm[tid]=a; __syncthreads();
  for (int off=128; off>0; off>>=1){ if (tid<off) sm[tid]+=sm[tid+off]; __syncthreads(); }
  if (tid==0) out[1]=sm[0];
  __syncthreads();

  a = 0.f; for (int i=tid;i<nbP;i+=256) a += wsF[i];
  sm[tid]=a; __syncthreads();
  for (int off=128; off>0; off>>=1){ if (tid<off) sm[tid]+=sm[tid+off]; __syncthreads(); }
  if (tid==0) out[2]=sm[0];
}

extern "C" void kernel_launch(void* const* d_in, const int* in_sizes, int n_in,
                              void* d_out, int out_size, void* d_ws, size_t ws_size,
                              hipStream_t stream){
  KP P;
  P.W0=(const float*)d_in[0];  P.b0=(const float*)d_in[1];
  P.W1=(const float*)d_in[2];  P.b1=(const float*)d_in[3];
  P.W2=(const float*)d_in[4];  P.b2=(const float*)d_in[5];
  P.W3=(const float*)d_in[6];  P.b3=(const float*)d_in[7];
  P.W4=(const float*)d_in[8];  P.b4=(const float*)d_in[9];
  P.W5=(const float*)d_in[10]; P.b5=(const float*)d_in[11];
  P.W6=(const float*)d_in[12]; P.b6=(const float*)d_in[13];
  P.bc1=(const float*)d_in[14]; P.bc2=(const float*)d_in[15];
  P.bc3=(const float*)d_in[16]; P.bc4=(const float*)d_in[17];
  P.bc5=(const float*)d_in[18]; P.f1=(const float*)d_in[19];
  P.inp=(const float*)d_in[20]; P.real=(const float*)d_in[21];

  unsigned short* wf = (unsigned short*)d_ws;
  P.Wfh  = wf;                  // 327680 ush
  P.Wfl  = wf + 327680;         // 327680 ush
  P.W6fh = wf + 655360;         // 4096 ush
  P.W6fl = wf + 659456;         // 4096 ush
  float* pb = (float*)((char*)d_ws + 1327104);
  P.wsBC = pb; P.wsDA = pb + 512; P.wsF = pb + 1024;   // 463,463,1250 used

  const int nbP  = 20000 / 16;           // 1250 pde blocks (16 pts)
  const int nbBC = (37000 + 79) / 80;    // 463 fwd blocks (80 pts)

  prep_kernel<<<dim3(1296), dim3(256), 0, stream>>>(
      P.W1, P.W2, P.W3, P.W4, P.W5, P.W6,
      (unsigned short*)wf, (unsigned short*)(wf + 327680),
      (unsigned short*)(wf + 655360), (unsigned short*)(wf + 659456));
  fused_kernel<<<dim3(nbP + nbBC), dim3(256), 0, stream>>>(P, nbP);
  reduce_kernel<<<dim3(1), dim3(256), 0, stream>>>(P.wsBC, P.wsDA, P.wsF,
                                                   (float*)d_out, nbBC, nbP);
}

// Round 9
// 473.900 us; speedup vs baseline: 1.0341x; 1.0341x over previous
//
#include <hip/hip_runtime.h>

#define NUC 8.0e-4f   // MIU/(U*L)

typedef __attribute__((ext_vector_type(8))) short   bf16x8;
typedef __attribute__((ext_vector_type(8))) unsigned short u16x8;
typedef __attribute__((ext_vector_type(4))) float   f32x4;

#define LOOFF  40960
#define STGOFF 81920
#define FINOFF 98304
#define REDOFF 99584
#define REDBOFF 99904
#define LDSSZ  100352

struct KP {
  const float *W0,*b0,*W1,*b1,*W2,*b2,*W3,*b3,*W4,*b4,*W5,*b5,*W6,*b6;
  const float *bc1,*bc2,*bc3,*bc4,*bc5,*f1,*inp,*real;
  const unsigned short *Wfh,*Wfl;     // frag-ordered bf16 hi/lo W1..W5
  const unsigned short *W6fh,*W6fl;   // frag-ordered bf16 hi/lo W6 (N padded to 16)
  float *wsBC,*wsDA,*wsF;
};

__device__ __forceinline__ float ftanh(float a){
  float e = __expf(2.0f*a);
  return 1.0f - 2.0f/(e + 1.0f);
}
__device__ __forceinline__ void splitf(float v, unsigned short& h, unsigned short& l){
  unsigned int b = __float_as_uint(v);
  h = (unsigned short)(b >> 16);
  float lo = v - __uint_as_float(b & 0xFFFF0000u);
  l = (unsigned short)(__float_as_uint(lo) >> 16);
}
// A byte addr in [80][256] bf16 (row stride 512B), bank-swizzled
__device__ __forceinline__ int aswz(int row, int kbyte){
  int f = ((row & 7) ^ ((row & 8) >> 2)) << 4;
  return (row*512 + kbyte) ^ f;
}
// drr staging f32 [16][256], swizzled
__device__ __forceinline__ int sswz(int row, int col){
  int off = ((row*256 + col)*4) ^ ((row & 3) << 6);
  return STGOFF + off;
}

// ---------------- prep: split W1..W5 (+W6 padded) into frag-ordered bf16 hi/lo ----------------
__global__ void prep_kernel(const float* W1, const float* W2, const float* W3,
                            const float* W4, const float* W5, const float* W6,
                            unsigned short* Wfh, unsigned short* Wfl,
                            unsigned short* W6fh, unsigned short* W6fl){
  int idx = blockIdx.x*256 + threadIdx.x;      // 0..331775
  if (idx < 327680){
    int li  = idx >> 16;
    int rem = idx & 65535;
    int k   = rem >> 8;
    int col = rem & 255;
    const float* Ws[5] = {W1,W2,W3,W4,W5};
    float v = Ws[li][k*256 + col];
    unsigned short hi, lo;
    splitf(v, hi, lo);
    int ks = k >> 5, kr = k & 31, qq = kr >> 3, e = kr & 7;
    int lane = qq*16 + (col & 15), nt = col >> 4;
    int pos = li*65536 + (ks*16 + nt)*512 + lane*8 + e;
    Wfh[pos] = hi; Wfl[pos] = lo;
  } else {
    int t = idx - 327680;            // 0..4095: [ks(8)][lane(64)][e(8)]
    int ks = t >> 9, lane = (t & 511) >> 3, e = t & 7;
    int k = ks*32 + (lane >> 4)*8 + e;
    int col = lane & 15;
    float v = (col < 4) ? W6[k*4 + col] : 0.f;
    unsigned short hi, lo;
    splitf(v, hi, lo);
    W6fh[t] = hi; W6fl[t] = lo;
  }
}

// K-loop: MC m-tiles starting at mbase, 4 n-tiles at nb*4.. ; manual 2-deep B dbuf.
template<int MC>
__device__ __forceinline__ void mm_tiles(f32x4 (&acc)[MC][4],
    const unsigned short* WH, const unsigned short* WL,
    const unsigned char* Ab, const int mbase, const int nb,
    const int lane, const int q, const int lrow){
  #pragma unroll
  for (int mi=0;mi<MC;++mi)
    #pragma unroll
    for (int n=0;n<4;++n){ acc[mi][n][0]=0.f; acc[mi][n][1]=0.f; acc[mi][n][2]=0.f; acc[mi][n][3]=0.f; }

  auto loadB = [&](int ks, bf16x8 (&h)[4], bf16x8 (&o)[4]){
    #pragma unroll
    for (int n=0;n<4;++n){
      int idx = (ks*16 + nb*4 + n)*512 + lane*8;
      h[n] = *(const bf16x8*)(WH + idx);
      o[n] = *(const bf16x8*)(WL + idx);
    }
  };
  auto mmBlk = [&](int ks, bf16x8 (&h)[4], bf16x8 (&o)[4]){
    __builtin_amdgcn_s_setprio(1);
    #pragma unroll
    for (int mi=0;mi<MC;++mi){
      int byte = aswz((mbase+mi)*16 + lrow, ks*64 + q*16);
      bf16x8 ah = *(const bf16x8*)(Ab + byte);
      bf16x8 al = *(const bf16x8*)(Ab + LOOFF + byte);
      #pragma unroll
      for (int n=0;n<4;++n){
        acc[mi][n] = __builtin_amdgcn_mfma_f32_16x16x32_bf16(ah, h[n], acc[mi][n], 0,0,0);
        acc[mi][n] = __builtin_amdgcn_mfma_f32_16x16x32_bf16(ah, o[n], acc[mi][n], 0,0,0);
        acc[mi][n] = __builtin_amdgcn_mfma_f32_16x16x32_bf16(al, h[n], acc[mi][n], 0,0,0);
      }
    }
    __builtin_amdgcn_s_setprio(0);
  };

  bf16x8 b0h[4], b0o[4], b1h[4], b1o[4];
  loadB(0, b0h, b0o);
  #pragma unroll 1
  for (int ks=0; ks<8; ks+=2){
    loadB(ks+1, b1h, b1o);
    mmBlk(ks, b0h, b0o);
    if (ks+2 < 8) loadB(ks+2, b0h, b0o);
    mmBlk(ks+1, b1h, b1o);
  }
}

// ---------------- fused main kernel: 512 thr = 8 waves, M=80, N=256 ----------------
// wave wv: grp = wv>>2 (m-set), nb = wv&3 (4 n-tiles). pde m-split {0..3}/{4}+stage;
// fwd m-split {0,1,2}/{3,4}. 1 block/CU (reg-bound), LDS ~98KB.
__global__ __launch_bounds__(512,2) void fused_kernel(KP P, int nbP){
  __shared__ unsigned char Abuf[LDSSZ];
  const int tid  = threadIdx.x;
  const int lane = tid & 63;
  const int wv   = tid >> 6;          // 0..7
  const int q    = lane >> 4;
  const int lrow = lane & 15;
  const int grp  = wv >> 2;
  const int nb   = wv & 3;
  const bool isP = (int)blockIdx.x < nbP;
  const int bid  = isP ? (int)blockIdx.x : (int)blockIdx.x - nbP;

  // ---- layer 0 (2 -> 256), write A hi/lo ----
  {
    const int pt = tid >> 5;      // 0..15
    const int jg = tid & 31;      // 8-col group
    const int j0 = jg*8;
    float wz[8], wr[8], bb[8];
    #pragma unroll
    for (int jj=0;jj<8;++jj){ wz[jj]=P.W0[j0+jj]; wr[jj]=P.W0[256+j0+jj]; bb[jj]=P.b0[j0+jj]; }
    if (isP){
      int g = bid*16 + pt;
      float x0 = P.f1[2*g], x1 = P.f1[2*g+1];
      u16x8 hv[5], lv[5];
      #pragma unroll
      for (int jj=0;jj<8;++jj){
        float a = x0*wz[jj] + x1*wr[jj] + bb[jj];
        float t = ftanh(a), s = 1.f - t*t, cc = -2.f*t*s;
        float o[5] = {t, s*wz[jj], s*wr[jj], cc*wz[jj]*wz[jj], cc*wr[jj]*wr[jj]};
        #pragma unroll
        for (int s_=0;s_<5;++s_){ unsigned short h_,l_; splitf(o[s_],h_,l_); hv[s_][jj]=h_; lv[s_][jj]=l_; }
      }
      #pragma unroll
      for (int s_=0;s_<5;++s_){
        int byte = aswz(s_*16 + pt, jg*16);
        *(u16x8*)(Abuf + byte)         = hv[s_];
        *(u16x8*)(Abuf + LOOFF + byte) = lv[s_];
      }
    } else {
      #pragma unroll
      for (int pp=0;pp<5;++pp){
        int row = pt + 16*pp;
        int g = bid*80 + row;
        float x0 = 0.f, x1 = 0.f;
        if (g < 37000){
          const float* src; int li2;
          if      (g <  1000){ src=P.bc1; li2=g; }
          else if (g <  2000){ src=P.bc2; li2=g-1000; }
          else if (g <  7000){ src=P.bc3; li2=g-2000; }
          else if (g < 12000){ src=P.bc4; li2=g-7000; }
          else if (g < 17000){ src=P.bc5; li2=g-12000; }
          else               { src=P.inp; li2=g-17000; }
          x0 = src[2*li2]; x1 = src[2*li2+1];
        }
        u16x8 hv, lv;
        #pragma unroll
        for (int jj=0;jj<8;++jj){
          float t = ftanh(x0*wz[jj] + x1*wr[jj] + bb[jj]);
          unsigned short h_,l_; splitf(t,h_,l_); hv[jj]=h_; lv[jj]=l_;
        }
        int byte = aswz(row, jg*16);
        *(u16x8*)(Abuf + byte)         = hv;
        *(u16x8*)(Abuf + LOOFF + byte) = lv;
      }
    }
  }

  // ---- layers 1..5 ----
  for (int li=0; li<5; ++li){
    const float* bl = (li==0)?P.b1:(li==1)?P.b2:(li==2)?P.b3:(li==3)?P.b4:P.b5;
    const unsigned short* WH = P.Wfh + li*65536;
    const unsigned short* WL = P.Wfl + li*65536;
    __syncthreads();   // S1: A of previous layer visible
    if (isP){
      if (grp == 0){
        f32x4 acc[4][4];                       // m 0..3 = h,dz,dr,dzz
        mm_tiles<4>(acc, WH, WL, Abuf, 0, nb, lane, q, lrow);
        __syncthreads();   // S2: all A reads done
        __syncthreads();   // S3: drr stage ready
        #pragma unroll
        for (int n=0;n<4;++n){
          const int col = (nb*4+n)*16 + lrow;
          const float bias = bl[col];
          #pragma unroll
          for (int r=0;r<4;++r){
            const int rp = q*4 + r;
            float a   = acc[0][n][r] + bias;
            float Dz  = acc[1][n][r], Dr = acc[2][n][r], Dzz = acc[3][n][r];
            float Drr = *(const float*)(Abuf + sswz(rp, col));
            float t = ftanh(a), s = 1.f - t*t, cc = -2.f*t*s;
            float o[5] = {t, s*Dz, s*Dr, s*Dzz + cc*Dz*Dz, s*Drr + cc*Dr*Dr};
            #pragma unroll
            for (int s_=0;s_<5;++s_){
              int row = s_*16 + rp;
              unsigned short h_,l_; splitf(o[s_],h_,l_);
              *(unsigned short*)(Abuf + aswz(row, col*2)) = h_;
              *(unsigned short*)(Abuf + LOOFF + aswz(row, col*2)) = l_;
            }
          }
        }
      } else {
        f32x4 acc[1][4];                       // m 4 = drr
        mm_tiles<1>(acc, WH, WL, Abuf, 4, nb, lane, q, lrow);
        __syncthreads();   // S2
        #pragma unroll
        for (int n=0;n<4;++n){
          const int col = (nb*4+n)*16 + lrow;
          #pragma unroll
          for (int r=0;r<4;++r)
            *(float*)(Abuf + sswz(q*4+r, col)) = acc[0][n][r];
        }
        __syncthreads();   // S3
      }
    } else {
      if (grp == 0){
        f32x4 acc[3][4];                       // m 0..2
        mm_tiles<3>(acc, WH, WL, Abuf, 0, nb, lane, q, lrow);
        __syncthreads();   // S2
        #pragma unroll
        for (int n=0;n<4;++n){
          const int col = (nb*4+n)*16 + lrow;
          const float bias = bl[col];
          #pragma unroll
          for (int mi=0;mi<3;++mi)
            #pragma unroll
            for (int r=0;r<4;++r){
              int row = mi*16 + q*4 + r;
              float t = ftanh(acc[mi][n][r] + bias);
              unsigned short h_,l_; splitf(t,h_,l_);
              *(unsigned short*)(Abuf + aswz(row, col*2)) = h_;
              *(unsigned short*)(Abuf + LOOFF + aswz(row, col*2)) = l_;
            }
        }
      } else {
        f32x4 acc[2][4];                       // m 3..4
        mm_tiles<2>(acc, WH, WL, Abuf, 3, nb, lane, q, lrow);
        __syncthreads();   // S2
        #pragma unroll
        for (int n=0;n<4;++n){
          const int col = (nb*4+n)*16 + lrow;
          const float bias = bl[col];
          #pragma unroll
          for (int mi=0;mi<2;++mi)
            #pragma unroll
            for (int r=0;r<4;++r){
              int row = (3+mi)*16 + q*4 + r;
              float t = ftanh(acc[mi][n][r] + bias);
              unsigned short h_,l_; splitf(t,h_,l_);
              *(unsigned short*)(Abuf + aswz(row, col*2)) = h_;
              *(unsigned short*)(Abuf + LOOFF + aswz(row, col*2)) = l_;
            }
        }
      }
    }
  }
  __syncthreads();   // layer-5 A visible

  // ---- layer 6 via MFMA: wave wv<5 owns m-tile wv; N-tile 0 (cols 0..3 valid) ----
  float* fin  = (float*)(Abuf + FINOFF);     // pde [16][20]; fwd [80][4]
  float* red  = (float*)(Abuf + REDOFF);
  float* redB = (float*)(Abuf + REDBOFF);
  if (wv < 5){
    f32x4 a6; a6[0]=0.f; a6[1]=0.f; a6[2]=0.f; a6[3]=0.f;
    #pragma unroll 1
    for (int ks=0; ks<8; ++ks){
      bf16x8 bh = *(const bf16x8*)(P.W6fh + ks*512 + lane*8);
      bf16x8 bo = *(const bf16x8*)(P.W6fl + ks*512 + lane*8);
      int byte = aswz(wv*16 + lrow, ks*64 + q*16);
      bf16x8 ah = *(const bf16x8*)(Abuf + byte);
      bf16x8 al = *(const bf16x8*)(Abuf + LOOFF + byte);
      a6 = __builtin_amdgcn_mfma_f32_16x16x32_bf16(ah, bh, a6, 0,0,0);
      a6 = __builtin_amdgcn_mfma_f32_16x16x32_bf16(ah, bo, a6, 0,0,0);
      a6 = __builtin_amdgcn_mfma_f32_16x16x32_bf16(al, bh, a6, 0,0,0);
    }
    if (lrow < 4){
      #pragma unroll
      for (int r=0;r<4;++r){
        if (isP){
          int pt = q*4 + r;
          float v = a6[r] + ((wv==0) ? P.b6[lrow] : 0.f);
          fin[pt*20 + wv*4 + lrow] = v;
        } else {
          int row = wv*16 + q*4 + r;
          fin[row*4 + lrow] = a6[r] + P.b6[lrow];
        }
      }
    }
  }
  __syncthreads();

  // ---- loss terms ----
  if (isP){
    if (tid < 16){
      const float* F = &fin[tid*20];
      float r = P.f1[2*(bid*16 + tid) + 1];
      float uz=F[0],  us=F[1],  ur=F[2];
      float uz_z=F[4],us_z=F[5],ur_z=F[6],p_z=F[7];
      float uz_r=F[8],us_r=F[9],ur_r=F[10],p_r=F[11];
      float uz_zz=F[12],us_zz=F[13],ur_zz=F[14];
      float uz_rr=F[16],us_rr=F[17],ur_rr=F[18];
      float invr = 1.f/r;
      float eq1 = ur*ur_r + uz*ur_z - us*us*invr + p_r
                - NUC*invr*ur_r - NUC*ur_rr - NUC*ur_zz + NUC*ur*invr*invr;
      float eq2 = ur*us_r + uz*us_z + ur*us*invr
                - NUC*invr*us_r - NUC*us_rr - NUC*us_zz + NUC*us*invr*invr;
      float eq3 = ur*uz_r + uz*uz_z + p_z
                - NUC*invr*uz_r - NUC*uz_rr - NUC*uz_zz;
      float eq4 = ur + r*ur_r + r*uz_z;
      red[tid] = (eq1*eq1 + eq2*eq2 + eq3*eq3 + eq4*eq4) * (1.0f/80000.f);
    }
    __syncthreads();
    if (tid == 0){
      float s = 0.f;
      #pragma unroll
      for (int i=0;i<16;++i) s += red[i];
      P.wsF[bid] = s;
    }
  } else {
    if (tid < 80){
      float dj0 = fin[tid*4+0], dj1 = fin[tid*4+1];
      float dj2 = fin[tid*4+2], dj3 = fin[tid*4+3];
      float bcp = 0.f, dap = 0.f;
      int g = bid*80 + tid;
      if (g < 37000){
        if      (g <  2000){ bcp = (dj0*dj0 + dj1*dj1 + dj2*dj2)*(1.0f/1000.f); }
        else if (g <  7000){ float d1 = dj1 - 1.f;
                             bcp = (dj0*dj0 + d1*d1 + dj2*dj2)*(1.0f/5000.f); }
        else if (g < 12000){ bcp = (dj0*dj0 + dj1*dj1 + dj2*dj2)*(1.0f/5000.f); }
        else if (g < 17000){ bcp = dj3*dj3*(1.0f/5000.f); }
        else { const float* rr = P.real + (g-17000)*4;
               float e0=dj0-rr[0], e1=dj1-rr[1], e2=dj2-rr[2], e3=dj3-rr[3];
               dap = (e0*e0 + e1*e1 + e2*e2 + e3*e3)*(1.0f/80000.f); }
      }
      red[tid] = bcp; redB[tid] = dap;
    }
    __syncthreads();
    if (tid == 0){
      float sA=0.f, sB=0.f;
      #pragma unroll
      for (int i=0;i<80;++i){ sA += red[i]; sB += redB[i]; }
      P.wsBC[bid] = sA; P.wsDA[bid] = sB;
    }
  }
}

// ---------------- final deterministic reduction ----------------
__global__ void reduce_kernel(const float* wsBC, const float* wsDA, const float* wsF,
                              float* out, int nbBC, int nbP){
  __shared__ float sm[256];
  const int tid = threadIdx.x;
  float a;

  a = 0.f; for (int i=tid;i<nbBC;i+=256) a += wsBC[i];
  sm[tid]=a; __syncthreads();
  for (int off=128; off>0; off>>=1){ if (tid<off) sm[tid]+=sm[tid+off]; __syncthreads(); }
  if (tid==0) out[0]=sm[0];
  __syncthreads();

  a = 0.f; for (int i=tid;i<nbBC;i+=256) a += wsDA[i];
  sm[tid]=a; __syncthreads();
  for (int off=128; off>0; off>>=1){ if (tid<off) sm[tid]+=sm[tid+off]; __syncthreads(); }
  if (tid==0) out[1]=sm[0];
  __syncthreads();

  a = 0.f; for (int i=tid;i<nbP;i+=256) a += wsF[i];
  sm[tid]=a; __syncthreads();
  for (int off=128; off>0; off>>=1){ if (tid<off) sm[tid]+=sm[tid+off]; __syncthreads(); }
  if (tid==0) out[2]=sm[0];
}

extern "C" void kernel_launch(void* const* d_in, const int* in_sizes, int n_in,
                              void* d_out, int out_size, void* d_ws, size_t ws_size,
                              hipStream_t stream){
  KP P;
  P.W0=(const float*)d_in[0];  P.b0=(const float*)d_in[1];
  P.W1=(const float*)d_in[2];  P.b1=(const float*)d_in[3];
  P.W2=(const float*)d_in[4];  P.b2=(const float*)d_in[5];
  P.W3=(const float*)d_in[6];  P.b3=(const float*)d_in[7];
  P.W4=(const float*)d_in[8];  P.b4=(const float*)d_in[9];
  P.W5=(const float*)d_in[10]; P.b5=(const float*)d_in[11];
  P.W6=(const float*)d_in[12]; P.b6=(const float*)d_in[13];
  P.bc1=(const float*)d_in[14]; P.bc2=(const float*)d_in[15];
  P.bc3=(const float*)d_in[16]; P.bc4=(const float*)d_in[17];
  P.bc5=(const float*)d_in[18]; P.f1=(const float*)d_in[19];
  P.inp=(const float*)d_in[20]; P.real=(const float*)d_in[21];

  unsigned short* wf = (unsigned short*)d_ws;
  P.Wfh  = wf;                  // 327680 ush
  P.Wfl  = wf + 327680;         // 327680 ush
  P.W6fh = wf + 655360;         // 4096 ush
  P.W6fl = wf + 659456;         // 4096 ush
  float* pb = (float*)((char*)d_ws + 1327104);
  P.wsBC = pb; P.wsDA = pb + 512; P.wsF = pb + 1024;

  const int nbP  = 20000 / 16;           // 1250 pde blocks (16 pts)
  const int nbBC = (37000 + 79) / 80;    // 463 fwd blocks (80 pts)

  prep_kernel<<<dim3(1296), dim3(256), 0, stream>>>(
      P.W1, P.W2, P.W3, P.W4, P.W5, P.W6,
      (unsigned short*)wf, (unsigned short*)(wf + 327680),
      (unsigned short*)(wf + 655360), (unsigned short*)(wf + 659456));
  fused_kernel<<<dim3(nbP + nbBC), dim3(512), 0, stream>>>(P, nbP);
  reduce_kernel<<<dim3(1), dim3(256), 0, stream>>>(P.wsBC, P.wsDA, P.wsF,
                                                   (float*)d_out, nbBC, nbP);
}

// Round 10
// 252.052 us; speedup vs baseline: 1.9443x; 1.8802x over previous
//
#include <hip/hip_runtime.h>

#define NUC 8.0e-4f   // MIU/(U*L)

typedef __attribute__((ext_vector_type(8))) short   bf16x8;
typedef __attribute__((ext_vector_type(8))) unsigned short u16x8;
typedef __attribute__((ext_vector_type(4))) float   f32x4;

struct KP {
  const float *W0,*b0,*W1,*b1,*W2,*b2,*W3,*b3,*W4,*b4,*W5,*b5,*W6,*b6;
  const float *bc1,*bc2,*bc3,*bc4,*bc5,*f1,*inp,*real;
  const unsigned short *Wfh,*Wfl;     // frag-ordered bf16 hi/lo W1..W5
  const unsigned short *W6fh,*W6fl;   // frag-ordered bf16 hi/lo W6 (N padded to 16)
  float *wsBC,*wsDA,*wsF;
};

__device__ __forceinline__ float ftanh(float a){
  float e = __expf(2.0f*a);
  return 1.0f - 2.0f/(e + 1.0f);
}
__device__ __forceinline__ void splitf(float v, unsigned short& h, unsigned short& l){
  unsigned int b = __float_as_uint(v);
  h = (unsigned short)(b >> 16);
  float lo = v - __uint_as_float(b & 0xFFFF0000u);
  l = (unsigned short)(__float_as_uint(lo) >> 16);
}
// A byte addr in [80][256] bf16 (row stride 512B), swizzled: reads spread
// 8 consecutive rows over 8 distinct 16B slots; epilogue q-groups (row bit 3)
// land in distinct slots via the row&8 fold.
__device__ __forceinline__ int aswz(int row, int kbyte){
  int f = ((row & 7) ^ ((row & 8) >> 2)) << 4;
  return (row*512 + kbyte) ^ f;
}

// ---------------- prep: split W1..W5 (+W6 padded) into frag-ordered bf16 hi/lo ----------------
// frag order: [ks(8)][ntile][lane(64)][e(8)]; lane=((k&31)>>3)*16+(col&15), e=k&7
__global__ void prep_kernel(const float* W1, const float* W2, const float* W3,
                            const float* W4, const float* W5, const float* W6,
                            unsigned short* Wfh, unsigned short* Wfl,
                            unsigned short* W6fh, unsigned short* W6fl){
  int idx = blockIdx.x*256 + threadIdx.x;      // 0..331775
  if (idx < 327680){
    int li  = idx >> 16;
    int rem = idx & 65535;
    int k   = rem >> 8;
    int col = rem & 255;
    const float* Ws[5] = {W1,W2,W3,W4,W5};
    float v = Ws[li][k*256 + col];
    unsigned short hi, lo;
    splitf(v, hi, lo);
    int ks = k >> 5, kr = k & 31, qq = kr >> 3, e = kr & 7;
    int lane = qq*16 + (col & 15), nt = col >> 4;
    int pos = li*65536 + (ks*16 + nt)*512 + lane*8 + e;
    Wfh[pos] = hi; Wfl[pos] = lo;
  } else {
    int t = idx - 327680;            // 0..4095: [ks(8)][lane(64)][e(8)]
    int ks = t >> 9, lane = (t & 511) >> 3, e = t & 7;
    int k = ks*32 + (lane >> 4)*8 + e;
    int col = lane & 15;
    float v = (col < 4) ? W6[k*4 + col] : 0.f;
    unsigned short hi, lo;
    splitf(v, hi, lo);
    W6fh[t] = hi; W6fl[t] = lo;
  }
}

// ---------------- fused main kernel: 512 thr = 8 waves, M=80, N=256 ----------------
// r5-proven register shape: wave owns 2 N-tiles (acc[5][2]); rolled ks loop,
// just-in-time B loads, no SGB. LDS = Abuf only (81920) -> 2 blocks/CU.
__global__ __launch_bounds__(512,4) void fused_kernel(KP P, int nbP){
  __shared__ unsigned char Abuf[81920];   // hi [80][256]bf16 @0, lo @40960; union'd tail
  const int tid  = threadIdx.x;
  const int lane = tid & 63;
  const int wv   = tid >> 6;          // 0..7
  const int q    = lane >> 4;         // 0..3
  const int lrow = lane & 15;
  const bool isP = (int)blockIdx.x < nbP;
  const int bid  = isP ? (int)blockIdx.x : (int)blockIdx.x - nbP;

  // ---- layer 0 (2 -> 256), write A hi/lo ----
  {
    const int pt = tid >> 5;      // 0..15
    const int jg = tid & 31;      // 8-col group
    const int j0 = jg*8;
    float wz[8], wr[8], bb[8];
    #pragma unroll
    for (int jj=0;jj<8;++jj){ wz[jj]=P.W0[j0+jj]; wr[jj]=P.W0[256+j0+jj]; bb[jj]=P.b0[j0+jj]; }
    if (isP){
      int g = bid*16 + pt;
      float x0 = P.f1[2*g], x1 = P.f1[2*g+1];
      u16x8 hv[5], lv[5];
      #pragma unroll
      for (int jj=0;jj<8;++jj){
        float a = x0*wz[jj] + x1*wr[jj] + bb[jj];
        float t = ftanh(a), s = 1.f - t*t, cc = -2.f*t*s;
        float o[5] = {t, s*wz[jj], s*wr[jj], cc*wz[jj]*wz[jj], cc*wr[jj]*wr[jj]};
        #pragma unroll
        for (int s_=0;s_<5;++s_){ unsigned short h_,l_; splitf(o[s_],h_,l_); hv[s_][jj]=h_; lv[s_][jj]=l_; }
      }
      #pragma unroll
      for (int s_=0;s_<5;++s_){
        int byte = aswz(s_*16 + pt, jg*16);
        *(u16x8*)(Abuf + byte)         = hv[s_];
        *(u16x8*)(Abuf + 40960 + byte) = lv[s_];
      }
    } else {
      #pragma unroll
      for (int pp=0;pp<5;++pp){
        int row = pt + 16*pp;
        int g = bid*80 + row;
        float x0 = 0.f, x1 = 0.f;
        if (g < 37000){
          const float* src; int li2;
          if      (g <  1000){ src=P.bc1; li2=g; }
          else if (g <  2000){ src=P.bc2; li2=g-1000; }
          else if (g <  7000){ src=P.bc3; li2=g-2000; }
          else if (g < 12000){ src=P.bc4; li2=g-7000; }
          else if (g < 17000){ src=P.bc5; li2=g-12000; }
          else               { src=P.inp; li2=g-17000; }
          x0 = src[2*li2]; x1 = src[2*li2+1];
        }
        u16x8 hv, lv;
        #pragma unroll
        for (int jj=0;jj<8;++jj){
          float t = ftanh(x0*wz[jj] + x1*wr[jj] + bb[jj]);
          unsigned short h_,l_; splitf(t,h_,l_); hv[jj]=h_; lv[jj]=l_;
        }
        int byte = aswz(row, jg*16);
        *(u16x8*)(Abuf + byte)         = hv;
        *(u16x8*)(Abuf + 40960 + byte) = lv;
      }
    }
  }

  // ---- layers 1..5: C = A_hi*W_hi + A_hi*W_lo + A_lo*W_hi ----
  for (int li=0; li<5; ++li){
    const float* bl = (li==0)?P.b1:(li==1)?P.b2:(li==2)?P.b3:(li==3)?P.b4:P.b5;
    const unsigned short* WH = P.Wfh + li*65536;
    const unsigned short* WL = P.Wfl + li*65536;
    f32x4 acc[5][2];
    #pragma unroll
    for (int m=0;m<5;++m)
      #pragma unroll
      for (int n=0;n<2;++n){ acc[m][n][0]=0.f; acc[m][n][1]=0.f; acc[m][n][2]=0.f; acc[m][n][3]=0.f; }
    __syncthreads();   // A of previous layer visible
    #pragma unroll 1
    for (int ks=0; ks<8; ++ks){
      bf16x8 bh0, bo0, bh1, bo1;
      {
        int idx = (ks*16 + wv*2)*512 + lane*8;
        bh0 = *(const bf16x8*)(WH + idx);
        bo0 = *(const bf16x8*)(WL + idx);
        bh1 = *(const bf16x8*)(WH + idx + 512);
        bo1 = *(const bf16x8*)(WL + idx + 512);
      }
      __builtin_amdgcn_s_setprio(1);
      #pragma unroll
      for (int m=0;m<5;++m){
        int byte = aswz(m*16 + lrow, ks*64 + q*16);
        bf16x8 ah = *(const bf16x8*)(Abuf + byte);
        bf16x8 al = *(const bf16x8*)(Abuf + 40960 + byte);
        acc[m][0] = __builtin_amdgcn_mfma_f32_16x16x32_bf16(ah, bh0, acc[m][0], 0,0,0);
        acc[m][0] = __builtin_amdgcn_mfma_f32_16x16x32_bf16(ah, bo0, acc[m][0], 0,0,0);
        acc[m][0] = __builtin_amdgcn_mfma_f32_16x16x32_bf16(al, bh0, acc[m][0], 0,0,0);
        acc[m][1] = __builtin_amdgcn_mfma_f32_16x16x32_bf16(ah, bh1, acc[m][1], 0,0,0);
        acc[m][1] = __builtin_amdgcn_mfma_f32_16x16x32_bf16(ah, bo1, acc[m][1], 0,0,0);
        acc[m][1] = __builtin_amdgcn_mfma_f32_16x16x32_bf16(al, bh1, acc[m][1], 0,0,0);
      }
      __builtin_amdgcn_s_setprio(0);
    }
    __syncthreads();   // all A reads done before overwrite
    #pragma unroll
    for (int n=0;n<2;++n){
      int col = (wv*2+n)*16 + lrow;
      float bias = bl[col];
      #pragma unroll
      for (int r=0;r<4;++r){
        int rw = q*4 + r;
        if (isP){
          float a  = acc[0][n][r] + bias;
          float Dz = acc[1][n][r], Dr = acc[2][n][r];
          float Dzz= acc[3][n][r], Drr= acc[4][n][r];
          float t = ftanh(a), s = 1.f - t*t, cc = -2.f*t*s;
          float o[5] = {t, s*Dz, s*Dr, s*Dzz + cc*Dz*Dz, s*Drr + cc*Dr*Dr};
          #pragma unroll
          for (int s_=0;s_<5;++s_){
            int row = s_*16 + rw;
            unsigned short h_,l_; splitf(o[s_],h_,l_);
            *(unsigned short*)(Abuf + aswz(row, col*2)) = h_;
            *(unsigned short*)(Abuf + 40960 + aswz(row, col*2)) = l_;
          }
        } else {
          #pragma unroll
          for (int m=0;m<5;++m){
            int row = m*16 + rw;
            float t = ftanh(acc[m][n][r] + bias);
            unsigned short h_,l_; splitf(t,h_,l_);
            *(unsigned short*)(Abuf + aswz(row, col*2)) = h_;
            *(unsigned short*)(Abuf + 40960 + aswz(row, col*2)) = l_;
          }
        }
      }
    }
  }
  __syncthreads();   // layer-5 A visible

  // ---- layer 6 via MFMA: wave m (0..4) owns M-tile m, single N-tile (cols 0..3) ----
  f32x4 a6; a6[0]=0.f; a6[1]=0.f; a6[2]=0.f; a6[3]=0.f;
  if (wv < 5){
    #pragma unroll 1
    for (int ks=0; ks<8; ++ks){
      bf16x8 bh = *(const bf16x8*)(P.W6fh + ks*512 + lane*8);
      bf16x8 bo = *(const bf16x8*)(P.W6fl + ks*512 + lane*8);
      int byte = aswz(wv*16 + lrow, ks*64 + q*16);
      bf16x8 ah = *(const bf16x8*)(Abuf + byte);
      bf16x8 al = *(const bf16x8*)(Abuf + 40960 + byte);
      a6 = __builtin_amdgcn_mfma_f32_16x16x32_bf16(ah, bh, a6, 0,0,0);
      a6 = __builtin_amdgcn_mfma_f32_16x16x32_bf16(ah, bo, a6, 0,0,0);
      a6 = __builtin_amdgcn_mfma_f32_16x16x32_bf16(al, bh, a6, 0,0,0);
    }
  }
  __syncthreads();   // all layer-6 A reads done; Abuf reusable as union

  float* fin  = (float*)Abuf;            // pde [16][20]; fwd [80][4]
  float* red  = (float*)(Abuf + 4096);
  float* redB = (float*)(Abuf + 6144);

  if (wv < 5 && lrow < 4){
    #pragma unroll
    for (int r=0;r<4;++r){
      if (isP){
        int pt = q*4 + r;
        float v = a6[r] + ((wv==0) ? P.b6[lrow] : 0.f);
        fin[pt*20 + wv*4 + lrow] = v;
      } else {
        int row = wv*16 + q*4 + r;
        fin[row*4 + lrow] = a6[r] + P.b6[lrow];
      }
    }
  }
  __syncthreads();

  // ---- loss terms ----
  if (isP){
    if (tid < 16){
      const float* F = &fin[tid*20];
      float r = P.f1[2*(bid*16 + tid) + 1];
      float uz=F[0],  us=F[1],  ur=F[2];
      float uz_z=F[4],us_z=F[5],ur_z=F[6],p_z=F[7];
      float uz_r=F[8],us_r=F[9],ur_r=F[10],p_r=F[11];
      float uz_zz=F[12],us_zz=F[13],ur_zz=F[14];
      float uz_rr=F[16],us_rr=F[17],ur_rr=F[18];
      float invr = 1.f/r;
      float eq1 = ur*ur_r + uz*ur_z - us*us*invr + p_r
                - NUC*invr*ur_r - NUC*ur_rr - NUC*ur_zz + NUC*ur*invr*invr;
      float eq2 = ur*us_r + uz*us_z + ur*us*invr
                - NUC*invr*us_r - NUC*us_rr - NUC*us_zz + NUC*us*invr*invr;
      float eq3 = ur*uz_r + uz*uz_z + p_z
                - NUC*invr*uz_r - NUC*uz_rr - NUC*uz_zz;
      float eq4 = ur + r*ur_r + r*uz_z;
      red[tid] = (eq1*eq1 + eq2*eq2 + eq3*eq3 + eq4*eq4) * (1.0f/80000.f);
    }
    __syncthreads();
    if (tid == 0){
      float s = 0.f;
      #pragma unroll
      for (int i=0;i<16;++i) s += red[i];
      P.wsF[bid] = s;
    }
  } else {
    if (tid < 80){
      float dj0 = fin[tid*4+0], dj1 = fin[tid*4+1];
      float dj2 = fin[tid*4+2], dj3 = fin[tid*4+3];
      float bcp = 0.f, dap = 0.f;
      int g = bid*80 + tid;
      if (g < 37000){
        if      (g <  2000){ bcp = (dj0*dj0 + dj1*dj1 + dj2*dj2)*(1.0f/1000.f); }
        else if (g <  7000){ float d1 = dj1 - 1.f;
                             bcp = (dj0*dj0 + d1*d1 + dj2*dj2)*(1.0f/5000.f); }
        else if (g < 12000){ bcp = (dj0*dj0 + dj1*dj1 + dj2*dj2)*(1.0f/5000.f); }
        else if (g < 17000){ bcp = dj3*dj3*(1.0f/5000.f); }
        else { const float* rr = P.real + (g-17000)*4;
               float e0=dj0-rr[0], e1=dj1-rr[1], e2=dj2-rr[2], e3=dj3-rr[3];
               dap = (e0*e0 + e1*e1 + e2*e2 + e3*e3)*(1.0f/80000.f); }
      }
      red[tid] = bcp; redB[tid] = dap;
    }
    __syncthreads();
    if (tid == 0){
      float sA=0.f, sB=0.f;
      #pragma unroll
      for (int i=0;i<80;++i){ sA += red[i]; sB += redB[i]; }
      P.wsBC[bid] = sA; P.wsDA[bid] = sB;
    }
  }
}

// ---------------- final deterministic reduction ----------------
__global__ void reduce_kernel(const float* wsBC, const float* wsDA, const float* wsF,
                              float* out, int nbBC, int nbP){
  __shared__ float sm[256];
  const int tid = threadIdx.x;
  float a;

  a = 0.f; for (int i=tid;i<nbBC;i+=256) a += wsBC[i];
  sm[tid]=a; __syncthreads();
  for (int off=128; off>0; off>>=1){ if (tid<off) sm[tid]+=sm[tid+off]; __syncthreads(); }
  if (tid==0) out[0]=sm[0];
  __syncthreads();

  a = 0.f; for (int i=tid;i<nbBC;i+=256) a += wsDA[i];
  sm[tid]=a; __syncthreads();
  for (int off=128; off>0; off>>=1){ if (tid<off) sm[tid]+=sm[tid+off]; __syncthreads(); }
  if (tid==0) out[1]=sm[0];
  __syncthreads();

  a = 0.f; for (int i=tid;i<nbP;i+=256) a += wsF[i];
  sm[tid]=a; __syncthreads();
  for (int off=128; off>0; off>>=1){ if (tid<off) sm[tid]+=sm[tid+off]; __syncthreads(); }
  if (tid==0) out[2]=sm[0];
}

extern "C" void kernel_launch(void* const* d_in, const int* in_sizes, int n_in,
                              void* d_out, int out_size, void* d_ws, size_t ws_size,
                              hipStream_t stream){
  KP P;
  P.W0=(const float*)d_in[0];  P.b0=(const float*)d_in[1];
  P.W1=(const float*)d_in[2];  P.b1=(const float*)d_in[3];
  P.W2=(const float*)d_in[4];  P.b2=(const float*)d_in[5];
  P.W3=(const float*)d_in[6];  P.b3=(const float*)d_in[7];
  P.W4=(const float*)d_in[8];  P.b4=(const float*)d_in[9];
  P.W5=(const float*)d_in[10]; P.b5=(const float*)d_in[11];
  P.W6=(const float*)d_in[12]; P.b6=(const float*)d_in[13];
  P.bc1=(const float*)d_in[14]; P.bc2=(const float*)d_in[15];
  P.bc3=(const float*)d_in[16]; P.bc4=(const float*)d_in[17];
  P.bc5=(const float*)d_in[18]; P.f1=(const float*)d_in[19];
  P.inp=(const float*)d_in[20]; P.real=(const float*)d_in[21];

  unsigned short* wf = (unsigned short*)d_ws;
  P.Wfh  = wf;                  // 327680 ush
  P.Wfl  = wf + 327680;         // 327680 ush
  P.W6fh = wf + 655360;         // 4096 ush
  P.W6fl = wf + 659456;         // 4096 ush
  float* pb = (float*)((char*)d_ws + 1327104);
  P.wsBC = pb; P.wsDA = pb + 512; P.wsF = pb + 1024;   // 463,463,1250 used

  const int nbP  = 20000 / 16;           // 1250 pde blocks (16 pts)
  const int nbBC = (37000 + 79) / 80;    // 463 fwd blocks (80 pts)

  prep_kernel<<<dim3(1296), dim3(256), 0, stream>>>(
      P.W1, P.W2, P.W3, P.W4, P.W5, P.W6,
      (unsigned short*)wf, (unsigned short*)(wf + 327680),
      (unsigned short*)(wf + 655360), (unsigned short*)(wf + 659456));
  fused_kernel<<<dim3(nbP + nbBC), dim3(512), 0, stream>>>(P, nbP);
  reduce_kernel<<<dim3(1), dim3(256), 0, stream>>>(P.wsBC, P.wsDA, P.wsF,
                                                   (float*)d_out, nbBC, nbP);
}

// Round 11
// 201.354 us; speedup vs baseline: 2.4338x; 1.2518x over previous
//
#include <hip/hip_runtime.h>

#define NUC 8.0e-4f   // MIU/(U*L)

typedef _Float16 __attribute__((ext_vector_type(8))) f16x8;
typedef __attribute__((ext_vector_type(8))) unsigned short u16x8;
typedef __attribute__((ext_vector_type(4))) float   f32x4;

struct KP {
  const float *W0,*b0,*W1,*b1,*W2,*b2,*W3,*b3,*W4,*b4,*W5,*b5,*W6,*b6;
  const float *bc1,*bc2,*bc3,*bc4,*bc5,*f1,*inp,*real;
  const unsigned short *Wfh,*Wfl;     // frag-ordered fp16 hi/lo W1..W5
  const unsigned short *W6fh,*W6fl;   // frag-ordered fp16 hi/lo W6 (N padded to 16)
  float *wsBC,*wsDA,*wsF;
};

__device__ __forceinline__ float ftanh(float a){
  float e = __expf(2.0f*a);
  return 1.0f - 2.0f/(e + 1.0f);
}
// fp16 split: hi = rne(v), lo = rne(v - hi)  (w ≈ hi+lo to ~2^-22)
__device__ __forceinline__ void splith(float v, unsigned short& h, unsigned short& l){
  _Float16 hh = (_Float16)v;
  float rem = v - (float)hh;
  _Float16 ll = (_Float16)rem;
  h = __builtin_bit_cast(unsigned short, hh);
  l = __builtin_bit_cast(unsigned short, ll);
}
__device__ __forceinline__ unsigned short cvth(float v){
  _Float16 hh = (_Float16)v;
  return __builtin_bit_cast(unsigned short, hh);
}
// A byte addr in [80][256] fp16 (row stride 512B), swizzled: reads spread
// 8 consecutive rows over 8 distinct 16B slots; epilogue q-groups (row bit 3)
// land in distinct slots via the row&8 fold.
__device__ __forceinline__ int aswz(int row, int kbyte){
  int f = ((row & 7) ^ ((row & 8) >> 2)) << 4;
  return (row*512 + kbyte) ^ f;
}

// ---------------- prep: split W1..W5 (+W6 padded) into frag-ordered fp16 hi/lo ----------------
// frag order: [ks(8)][ntile][lane(64)][e(8)]; lane=((k&31)>>3)*16+(col&15), e=k&7
__global__ void prep_kernel(const float* W1, const float* W2, const float* W3,
                            const float* W4, const float* W5, const float* W6,
                            unsigned short* Wfh, unsigned short* Wfl,
                            unsigned short* W6fh, unsigned short* W6fl){
  int idx = blockIdx.x*256 + threadIdx.x;      // 0..331775
  if (idx < 327680){
    int li  = idx >> 16;
    int rem = idx & 65535;
    int k   = rem >> 8;
    int col = rem & 255;
    const float* Ws[5] = {W1,W2,W3,W4,W5};
    float v = Ws[li][k*256 + col];
    unsigned short hi, lo;
    splith(v, hi, lo);
    int ks = k >> 5, kr = k & 31, qq = kr >> 3, e = kr & 7;
    int lane = qq*16 + (col & 15), nt = col >> 4;
    int pos = li*65536 + (ks*16 + nt)*512 + lane*8 + e;
    Wfh[pos] = hi; Wfl[pos] = lo;
  } else {
    int t = idx - 327680;            // 0..4095: [ks(8)][lane(64)][e(8)]
    int ks = t >> 9, lane = (t & 511) >> 3, e = t & 7;
    int k = ks*32 + (lane >> 4)*8 + e;
    int col = lane & 15;
    float v = (col < 4) ? W6[k*4 + col] : 0.f;
    unsigned short hi, lo;
    splith(v, hi, lo);
    W6fh[t] = hi; W6fl[t] = lo;
  }
}

// ---------------- fused main kernel: 512 thr = 8 waves, M=80, N=256 ----------------
// fp16 2-term: C = A_hi*(W_hi + W_lo). A hi only in LDS (40 KB). Wave owns
// 2 N-tiles (acc[5][2]); rolled ks loop, just-in-time B loads.
__global__ __launch_bounds__(512,4) void fused_kernel(KP P, int nbP){
  __shared__ unsigned char Abuf[40960];   // fp16 A_hi [80][256]; union'd tail
  const int tid  = threadIdx.x;
  const int lane = tid & 63;
  const int wv   = tid >> 6;          // 0..7
  const int q    = lane >> 4;         // 0..3
  const int lrow = lane & 15;
  const bool isP = (int)blockIdx.x < nbP;
  const int bid  = isP ? (int)blockIdx.x : (int)blockIdx.x - nbP;

  // ---- layer 0 (2 -> 256), write A_hi ----
  {
    const int pt = tid >> 5;      // 0..15
    const int jg = tid & 31;      // 8-col group
    const int j0 = jg*8;
    float wz[8], wr[8], bb[8];
    #pragma unroll
    for (int jj=0;jj<8;++jj){ wz[jj]=P.W0[j0+jj]; wr[jj]=P.W0[256+j0+jj]; bb[jj]=P.b0[j0+jj]; }
    if (isP){
      int g = bid*16 + pt;
      float x0 = P.f1[2*g], x1 = P.f1[2*g+1];
      u16x8 hv[5];
      #pragma unroll
      for (int jj=0;jj<8;++jj){
        float a = x0*wz[jj] + x1*wr[jj] + bb[jj];
        float t = ftanh(a), s = 1.f - t*t, cc = -2.f*t*s;
        float o[5] = {t, s*wz[jj], s*wr[jj], cc*wz[jj]*wz[jj], cc*wr[jj]*wr[jj]};
        #pragma unroll
        for (int s_=0;s_<5;++s_) hv[s_][jj] = cvth(o[s_]);
      }
      #pragma unroll
      for (int s_=0;s_<5;++s_){
        int byte = aswz(s_*16 + pt, jg*16);
        *(u16x8*)(Abuf + byte) = hv[s_];
      }
    } else {
      #pragma unroll
      for (int pp=0;pp<5;++pp){
        int row = pt + 16*pp;
        int g = bid*80 + row;
        float x0 = 0.f, x1 = 0.f;
        if (g < 37000){
          const float* src; int li2;
          if      (g <  1000){ src=P.bc1; li2=g; }
          else if (g <  2000){ src=P.bc2; li2=g-1000; }
          else if (g <  7000){ src=P.bc3; li2=g-2000; }
          else if (g < 12000){ src=P.bc4; li2=g-7000; }
          else if (g < 17000){ src=P.bc5; li2=g-12000; }
          else               { src=P.inp; li2=g-17000; }
          x0 = src[2*li2]; x1 = src[2*li2+1];
        }
        u16x8 hv;
        #pragma unroll
        for (int jj=0;jj<8;++jj)
          hv[jj] = cvth(ftanh(x0*wz[jj] + x1*wr[jj] + bb[jj]));
        int byte = aswz(row, jg*16);
        *(u16x8*)(Abuf + byte) = hv;
      }
    }
  }

  // ---- layers 1..5: C = A_hi*W_hi + A_hi*W_lo ----
  for (int li=0; li<5; ++li){
    const float* bl = (li==0)?P.b1:(li==1)?P.b2:(li==2)?P.b3:(li==3)?P.b4:P.b5;
    const unsigned short* WH = P.Wfh + li*65536;
    const unsigned short* WL = P.Wfl + li*65536;
    f32x4 acc[5][2];
    #pragma unroll
    for (int m=0;m<5;++m)
      #pragma unroll
      for (int n=0;n<2;++n){ acc[m][n][0]=0.f; acc[m][n][1]=0.f; acc[m][n][2]=0.f; acc[m][n][3]=0.f; }
    __syncthreads();   // A of previous layer visible
    #pragma unroll 1
    for (int ks=0; ks<8; ++ks){
      f16x8 bh0, bo0, bh1, bo1;
      {
        int idx = (ks*16 + wv*2)*512 + lane*8;
        bh0 = *(const f16x8*)(WH + idx);
        bo0 = *(const f16x8*)(WL + idx);
        bh1 = *(const f16x8*)(WH + idx + 512);
        bo1 = *(const f16x8*)(WL + idx + 512);
      }
      __builtin_amdgcn_s_setprio(1);
      #pragma unroll
      for (int m=0;m<5;++m){
        int byte = aswz(m*16 + lrow, ks*64 + q*16);
        f16x8 ah = *(const f16x8*)(Abuf + byte);
        acc[m][0] = __builtin_amdgcn_mfma_f32_16x16x32_f16(ah, bh0, acc[m][0], 0,0,0);
        acc[m][0] = __builtin_amdgcn_mfma_f32_16x16x32_f16(ah, bo0, acc[m][0], 0,0,0);
        acc[m][1] = __builtin_amdgcn_mfma_f32_16x16x32_f16(ah, bh1, acc[m][1], 0,0,0);
        acc[m][1] = __builtin_amdgcn_mfma_f32_16x16x32_f16(ah, bo1, acc[m][1], 0,0,0);
      }
      __builtin_amdgcn_s_setprio(0);
    }
    __syncthreads();   // all A reads done before overwrite
    #pragma unroll
    for (int n=0;n<2;++n){
      int col = (wv*2+n)*16 + lrow;
      float bias = bl[col];
      #pragma unroll
      for (int r=0;r<4;++r){
        int rw = q*4 + r;
        if (isP){
          float a  = acc[0][n][r] + bias;
          float Dz = acc[1][n][r], Dr = acc[2][n][r];
          float Dzz= acc[3][n][r], Drr= acc[4][n][r];
          float t = ftanh(a), s = 1.f - t*t, cc = -2.f*t*s;
          float o[5] = {t, s*Dz, s*Dr, s*Dzz + cc*Dz*Dz, s*Drr + cc*Dr*Dr};
          #pragma unroll
          for (int s_=0;s_<5;++s_){
            int row = s_*16 + rw;
            *(unsigned short*)(Abuf + aswz(row, col*2)) = cvth(o[s_]);
          }
        } else {
          #pragma unroll
          for (int m=0;m<5;++m){
            int row = m*16 + rw;
            float t = ftanh(acc[m][n][r] + bias);
            *(unsigned short*)(Abuf + aswz(row, col*2)) = cvth(t);
          }
        }
      }
    }
  }
  __syncthreads();   // layer-5 A visible

  // ---- layer 6 via MFMA: wave m (0..4) owns M-tile m, single N-tile (cols 0..3) ----
  f32x4 a6; a6[0]=0.f; a6[1]=0.f; a6[2]=0.f; a6[3]=0.f;
  if (wv < 5){
    #pragma unroll 1
    for (int ks=0; ks<8; ++ks){
      f16x8 bh = *(const f16x8*)(P.W6fh + ks*512 + lane*8);
      f16x8 bo = *(const f16x8*)(P.W6fl + ks*512 + lane*8);
      int byte = aswz(wv*16 + lrow, ks*64 + q*16);
      f16x8 ah = *(const f16x8*)(Abuf + byte);
      a6 = __builtin_amdgcn_mfma_f32_16x16x32_f16(ah, bh, a6, 0,0,0);
      a6 = __builtin_amdgcn_mfma_f32_16x16x32_f16(ah, bo, a6, 0,0,0);
    }
  }
  __syncthreads();   // all layer-6 A reads done; Abuf reusable as union

  float* fin  = (float*)Abuf;            // pde [16][20]; fwd [80][4]
  float* red  = (float*)(Abuf + 4096);
  float* redB = (float*)(Abuf + 6144);

  if (wv < 5 && lrow < 4){
    #pragma unroll
    for (int r=0;r<4;++r){
      if (isP){
        int pt = q*4 + r;
        float v = a6[r] + ((wv==0) ? P.b6[lrow] : 0.f);
        fin[pt*20 + wv*4 + lrow] = v;
      } else {
        int row = wv*16 + q*4 + r;
        fin[row*4 + lrow] = a6[r] + P.b6[lrow];
      }
    }
  }
  __syncthreads();

  // ---- loss terms ----
  if (isP){
    if (tid < 16){
      const float* F = &fin[tid*20];
      float r = P.f1[2*(bid*16 + tid) + 1];
      float uz=F[0],  us=F[1],  ur=F[2];
      float uz_z=F[4],us_z=F[5],ur_z=F[6],p_z=F[7];
      float uz_r=F[8],us_r=F[9],ur_r=F[10],p_r=F[11];
      float uz_zz=F[12],us_zz=F[13],ur_zz=F[14];
      float uz_rr=F[16],us_rr=F[17],ur_rr=F[18];
      float invr = 1.f/r;
      float eq1 = ur*ur_r + uz*ur_z - us*us*invr + p_r
                - NUC*invr*ur_r - NUC*ur_rr - NUC*ur_zz + NUC*ur*invr*invr;
      float eq2 = ur*us_r + uz*us_z + ur*us*invr
                - NUC*invr*us_r - NUC*us_rr - NUC*us_zz + NUC*us*invr*invr;
      float eq3 = ur*uz_r + uz*uz_z + p_z
                - NUC*invr*uz_r - NUC*uz_rr - NUC*uz_zz;
      float eq4 = ur + r*ur_r + r*uz_z;
      red[tid] = (eq1*eq1 + eq2*eq2 + eq3*eq3 + eq4*eq4) * (1.0f/80000.f);
    }
    __syncthreads();
    if (tid == 0){
      float s = 0.f;
      #pragma unroll
      for (int i=0;i<16;++i) s += red[i];
      P.wsF[bid] = s;
    }
  } else {
    if (tid < 80){
      float dj0 = fin[tid*4+0], dj1 = fin[tid*4+1];
      float dj2 = fin[tid*4+2], dj3 = fin[tid*4+3];
      float bcp = 0.f, dap = 0.f;
      int g = bid*80 + tid;
      if (g < 37000){
        if      (g <  2000){ bcp = (dj0*dj0 + dj1*dj1 + dj2*dj2)*(1.0f/1000.f); }
        else if (g <  7000){ float d1 = dj1 - 1.f;
                             bcp = (dj0*dj0 + d1*d1 + dj2*dj2)*(1.0f/5000.f); }
        else if (g < 12000){ bcp = (dj0*dj0 + dj1*dj1 + dj2*dj2)*(1.0f/5000.f); }
        else if (g < 17000){ bcp = dj3*dj3*(1.0f/5000.f); }
        else { const float* rr = P.real + (g-17000)*4;
               float e0=dj0-rr[0], e1=dj1-rr[1], e2=dj2-rr[2], e3=dj3-rr[3];
               dap = (e0*e0 + e1*e1 + e2*e2 + e3*e3)*(1.0f/80000.f); }
      }
      red[tid] = bcp; redB[tid] = dap;
    }
    __syncthreads();
    if (tid == 0){
      float sA=0.f, sB=0.f;
      #pragma unroll
      for (int i=0;i<80;++i){ sA += red[i]; sB += redB[i]; }
      P.wsBC[bid] = sA; P.wsDA[bid] = sB;
    }
  }
}

// ---------------- final deterministic reduction ----------------
__global__ void reduce_kernel(const float* wsBC, const float* wsDA, const float* wsF,
                              float* out, int nbBC, int nbP){
  __shared__ float sm[256];
  const int tid = threadIdx.x;
  float a;

  a = 0.f; for (int i=tid;i<nbBC;i+=256) a += wsBC[i];
  sm[tid]=a; __syncthreads();
  for (int off=128; off>0; off>>=1){ if (tid<off) sm[tid]+=sm[tid+off]; __syncthreads(); }
  if (tid==0) out[0]=sm[0];
  __syncthreads();

  a = 0.f; for (int i=tid;i<nbBC;i+=256) a += wsDA[i];
  sm[tid]=a; __syncthreads();
  for (int off=128; off>0; off>>=1){ if (tid<off) sm[tid]+=sm[tid+off]; __syncthreads(); }
  if (tid==0) out[1]=sm[0];
  __syncthreads();

  a = 0.f; for (int i=tid;i<nbP;i+=256) a += wsF[i];
  sm[tid]=a; __syncthreads();
  for (int off=128; off>0; off>>=1){ if (tid<off) sm[tid]+=sm[tid+off]; __syncthreads(); }
  if (tid==0) out[2]=sm[0];
}

extern "C" void kernel_launch(void* const* d_in, const int* in_sizes, int n_in,
                              void* d_out, int out_size, void* d_ws, size_t ws_size,
                              hipStream_t stream){
  KP P;
  P.W0=(const float*)d_in[0];  P.b0=(const float*)d_in[1];
  P.W1=(const float*)d_in[2];  P.b1=(const float*)d_in[3];
  P.W2=(const float*)d_in[4];  P.b2=(const float*)d_in[5];
  P.W3=(const float*)d_in[6];  P.b3=(const float*)d_in[7];
  P.W4=(const float*)d_in[8];  P.b4=(const float*)d_in[9];
  P.W5=(const float*)d_in[10]; P.b5=(const float*)d_in[11];
  P.W6=(const float*)d_in[12]; P.b6=(const float*)d_in[13];
  P.bc1=(const float*)d_in[14]; P.bc2=(const float*)d_in[15];
  P.bc3=(const float*)d_in[16]; P.bc4=(const float*)d_in[17];
  P.bc5=(const float*)d_in[18]; P.f1=(const float*)d_in[19];
  P.inp=(const float*)d_in[20]; P.real=(const float*)d_in[21];

  unsigned short* wf = (unsigned short*)d_ws;
  P.Wfh  = wf;                  // 327680 ush
  P.Wfl  = wf + 327680;         // 327680 ush
  P.W6fh = wf + 655360;         // 4096 ush
  P.W6fl = wf + 659456;         // 4096 ush
  float* pb = (float*)((char*)d_ws + 1327104);
  P.wsBC = pb; P.wsDA = pb + 512; P.wsF = pb + 1024;   // 463,463,1250 used

  const int nbP  = 20000 / 16;           // 1250 pde blocks (16 pts)
  const int nbBC = (37000 + 79) / 80;    // 463 fwd blocks (80 pts)

  prep_kernel<<<dim3(1296), dim3(256), 0, stream>>>(
      P.W1, P.W2, P.W3, P.W4, P.W5, P.W6,
      (unsigned short*)wf, (unsigned short*)(wf + 327680),
      (unsigned short*)(wf + 655360), (unsigned short*)(wf + 659456));
  fused_kernel<<<dim3(nbP + nbBC), dim3(512), 0, stream>>>(P, nbP);
  reduce_kernel<<<dim3(1), dim3(256), 0, stream>>>(P.wsBC, P.wsDA, P.wsF,
                                                   (float*)d_out, nbBC, nbP);
}

// Round 12
// 172.912 us; speedup vs baseline: 2.8341x; 1.1645x over previous
//
#include <hip/hip_runtime.h>

#define NUC 8.0e-4f   // MIU/(U*L)

typedef _Float16 __attribute__((ext_vector_type(8))) f16x8;
typedef __attribute__((ext_vector_type(8))) unsigned short u16x8;
typedef __attribute__((ext_vector_type(4))) float   f32x4;

struct KP {
  const float *W0,*b0,*W1,*b1,*W2,*b2,*W3,*b3,*W4,*b4,*W5,*b5,*W6,*b6;
  const float *bc1,*bc2,*bc3,*bc4,*bc5,*f1,*inp,*real;
  const unsigned short *Wfh,*Wfl;     // frag-ordered fp16 hi/lo W1..W5
  const unsigned short *W6fh,*W6fl;   // frag-ordered fp16 hi/lo W6 (N padded to 16)
  float *wsBC,*wsDA,*wsF;
};

__device__ __forceinline__ float ftanh(float a){
  float e = __expf(2.0f*a);
  return 1.0f - 2.0f/(e + 1.0f);
}
// fp16 split: hi = rne(v), lo = rne(v - hi)  (hi+lo ≈ v to ~2^-22)
__device__ __forceinline__ void splith(float v, unsigned short& h, unsigned short& l){
  _Float16 hh = (_Float16)v;
  float rem = v - (float)hh;
  _Float16 ll = (_Float16)rem;
  h = __builtin_bit_cast(unsigned short, hh);
  l = __builtin_bit_cast(unsigned short, ll);
}
__device__ __forceinline__ unsigned short cvth(float v){
  _Float16 hh = (_Float16)v;
  return __builtin_bit_cast(unsigned short, hh);
}
// A byte addr in [80][256] fp16 (row stride 512B), swizzled (f depends only on
// row&15 = per-thread lane row -> compiler folds m*8192 into ds_read offsets).
__device__ __forceinline__ int aswz(int row, int kbyte){
  int f = ((row & 7) ^ ((row & 8) >> 2)) << 4;
  return (row*512 + kbyte) ^ f;
}

// ---------------- prep: split W1..W5 (+W6 padded) into frag-ordered fp16 hi/lo ----------------
// frag order: [ks(8)][ntile][lane(64)][e(8)]; lane=((k&31)>>3)*16+(col&15), e=k&7
__global__ void prep_kernel(const float* W1, const float* W2, const float* W3,
                            const float* W4, const float* W5, const float* W6,
                            unsigned short* Wfh, unsigned short* Wfl,
                            unsigned short* W6fh, unsigned short* W6fl){
  int idx = blockIdx.x*256 + threadIdx.x;      // 0..331775
  if (idx < 327680){
    int li  = idx >> 16;
    int rem = idx & 65535;
    int k   = rem >> 8;
    int col = rem & 255;
    const float* Ws[5] = {W1,W2,W3,W4,W5};
    float v = Ws[li][k*256 + col];
    unsigned short hi, lo;
    splith(v, hi, lo);
    int ks = k >> 5, kr = k & 31, qq = kr >> 3, e = kr & 7;
    int lane = qq*16 + (col & 15), nt = col >> 4;
    int pos = li*65536 + (ks*16 + nt)*512 + lane*8 + e;
    Wfh[pos] = hi; Wfl[pos] = lo;
  } else {
    int t = idx - 327680;            // 0..4095: [ks(8)][lane(64)][e(8)]
    int ks = t >> 9, lane = (t & 511) >> 3, e = t & 7;
    int k = ks*32 + (lane >> 4)*8 + e;
    int col = lane & 15;
    float v = (col < 4) ? W6[k*4 + col] : 0.f;
    unsigned short hi, lo;
    splith(v, hi, lo);
    W6fh[t] = hi; W6fl[t] = lo;
  }
}

// ---------------- fused main kernel: 512 thr = 8 waves, M=80, N=256 ----------------
// fp16 selective precision: pde h-stream (m=0) = A*(W_hi+W_lo) 2-term;
// pde derivative streams (m=1..4) and all fwd rows = A*W_hi 1-term.
__global__ __launch_bounds__(512,4) void fused_kernel(KP P, int nbP){
  __shared__ unsigned char Abuf[40960];   // fp16 A_hi [80][256]; union'd tail
  const int tid  = threadIdx.x;
  const int lane = tid & 63;
  const int wv   = tid >> 6;          // 0..7
  const int q    = lane >> 4;         // 0..3
  const int lrow = lane & 15;
  const bool isP = (int)blockIdx.x < nbP;
  const int bid  = isP ? (int)blockIdx.x : (int)blockIdx.x - nbP;

  // ---- layer 0 (2 -> 256), write A_hi ----
  {
    const int pt = tid >> 5;      // 0..15
    const int jg = tid & 31;      // 8-col group
    const int j0 = jg*8;
    float wz[8], wr[8], bb[8];
    #pragma unroll
    for (int jj=0;jj<8;++jj){ wz[jj]=P.W0[j0+jj]; wr[jj]=P.W0[256+j0+jj]; bb[jj]=P.b0[j0+jj]; }
    if (isP){
      int g = bid*16 + pt;
      float x0 = P.f1[2*g], x1 = P.f1[2*g+1];
      u16x8 hv[5];
      #pragma unroll
      for (int jj=0;jj<8;++jj){
        float a = x0*wz[jj] + x1*wr[jj] + bb[jj];
        float t = ftanh(a), s = 1.f - t*t, cc = -2.f*t*s;
        float o[5] = {t, s*wz[jj], s*wr[jj], cc*wz[jj]*wz[jj], cc*wr[jj]*wr[jj]};
        #pragma unroll
        for (int s_=0;s_<5;++s_) hv[s_][jj] = cvth(o[s_]);
      }
      #pragma unroll
      for (int s_=0;s_<5;++s_){
        int byte = aswz(s_*16 + pt, jg*16);
        *(u16x8*)(Abuf + byte) = hv[s_];
      }
    } else {
      #pragma unroll
      for (int pp=0;pp<5;++pp){
        int row = pt + 16*pp;
        int g = bid*80 + row;
        float x0 = 0.f, x1 = 0.f;
        if (g < 37000){
          const float* src; int li2;
          if      (g <  1000){ src=P.bc1; li2=g; }
          else if (g <  2000){ src=P.bc2; li2=g-1000; }
          else if (g <  7000){ src=P.bc3; li2=g-2000; }
          else if (g < 12000){ src=P.bc4; li2=g-7000; }
          else if (g < 17000){ src=P.bc5; li2=g-12000; }
          else               { src=P.inp; li2=g-17000; }
          x0 = src[2*li2]; x1 = src[2*li2+1];
        }
        u16x8 hv;
        #pragma unroll
        for (int jj=0;jj<8;++jj)
          hv[jj] = cvth(ftanh(x0*wz[jj] + x1*wr[jj] + bb[jj]));
        int byte = aswz(row, jg*16);
        *(u16x8*)(Abuf + byte) = hv;
      }
    }
  }

  // ---- layers 1..5 ----
  for (int li=0; li<5; ++li){
    const float* bl = (li==0)?P.b1:(li==1)?P.b2:(li==2)?P.b3:(li==3)?P.b4:P.b5;
    const unsigned short* WH = P.Wfh + li*65536;
    const unsigned short* WL = P.Wfl + li*65536;
    f32x4 acc[5][2];
    #pragma unroll
    for (int m=0;m<5;++m)
      #pragma unroll
      for (int n=0;n<2;++n){ acc[m][n][0]=0.f; acc[m][n][1]=0.f; acc[m][n][2]=0.f; acc[m][n][3]=0.f; }
    __syncthreads();   // A of previous layer visible
    #pragma unroll 1
    for (int ks=0; ks<8; ++ks){
      f16x8 bh0, bh1, bo0, bo1;
      {
        int idx = (ks*16 + wv*2)*512 + lane*8;
        bh0 = *(const f16x8*)(WH + idx);
        bh1 = *(const f16x8*)(WH + idx + 512);
        if (isP){
          bo0 = *(const f16x8*)(WL + idx);
          bo1 = *(const f16x8*)(WL + idx + 512);
        }
      }
      __builtin_amdgcn_s_setprio(1);
      #pragma unroll
      for (int m=0;m<5;++m){
        int byte = aswz(m*16 + lrow, ks*64 + q*16);
        f16x8 ah = *(const f16x8*)(Abuf + byte);
        acc[m][0] = __builtin_amdgcn_mfma_f32_16x16x32_f16(ah, bh0, acc[m][0], 0,0,0);
        acc[m][1] = __builtin_amdgcn_mfma_f32_16x16x32_f16(ah, bh1, acc[m][1], 0,0,0);
        if (m == 0 && isP){
          acc[0][0] = __builtin_amdgcn_mfma_f32_16x16x32_f16(ah, bo0, acc[0][0], 0,0,0);
          acc[0][1] = __builtin_amdgcn_mfma_f32_16x16x32_f16(ah, bo1, acc[0][1], 0,0,0);
        }
      }
      __builtin_amdgcn_s_setprio(0);
    }
    __syncthreads();   // all A reads done before overwrite
    #pragma unroll
    for (int n=0;n<2;++n){
      int col = (wv*2+n)*16 + lrow;
      float bias = bl[col];
      #pragma unroll
      for (int r=0;r<4;++r){
        int rw = q*4 + r;
        if (isP){
          float a  = acc[0][n][r] + bias;
          float Dz = acc[1][n][r], Dr = acc[2][n][r];
          float Dzz= acc[3][n][r], Drr= acc[4][n][r];
          float t = ftanh(a), s = 1.f - t*t, cc = -2.f*t*s;
          float o[5] = {t, s*Dz, s*Dr, s*Dzz + cc*Dz*Dz, s*Drr + cc*Dr*Dr};
          #pragma unroll
          for (int s_=0;s_<5;++s_){
            int row = s_*16 + rw;
            *(unsigned short*)(Abuf + aswz(row, col*2)) = cvth(o[s_]);
          }
        } else {
          #pragma unroll
          for (int m=0;m<5;++m){
            int row = m*16 + rw;
            float t = ftanh(acc[m][n][r] + bias);
            *(unsigned short*)(Abuf + aswz(row, col*2)) = cvth(t);
          }
        }
      }
    }
  }
  __syncthreads();   // layer-5 A visible

  // ---- layer 6 via MFMA: wave m (0..4) owns M-tile m, single N-tile (cols 0..3) ----
  f32x4 a6; a6[0]=0.f; a6[1]=0.f; a6[2]=0.f; a6[3]=0.f;
  if (wv < 5){
    #pragma unroll 1
    for (int ks=0; ks<8; ++ks){
      f16x8 bh = *(const f16x8*)(P.W6fh + ks*512 + lane*8);
      f16x8 bo = *(const f16x8*)(P.W6fl + ks*512 + lane*8);
      int byte = aswz(wv*16 + lrow, ks*64 + q*16);
      f16x8 ah = *(const f16x8*)(Abuf + byte);
      a6 = __builtin_amdgcn_mfma_f32_16x16x32_f16(ah, bh, a6, 0,0,0);
      a6 = __builtin_amdgcn_mfma_f32_16x16x32_f16(ah, bo, a6, 0,0,0);
    }
  }
  __syncthreads();   // all layer-6 A reads done; Abuf reusable as union

  float* fin  = (float*)Abuf;            // pde [16][20]; fwd [80][4]
  float* red  = (float*)(Abuf + 4096);
  float* redB = (float*)(Abuf + 6144);

  if (wv < 5 && lrow < 4){
    #pragma unroll
    for (int r=0;r<4;++r){
      if (isP){
        int pt = q*4 + r;
        float v = a6[r] + ((wv==0) ? P.b6[lrow] : 0.f);
        fin[pt*20 + wv*4 + lrow] = v;
      } else {
        int row = wv*16 + q*4 + r;
        fin[row*4 + lrow] = a6[r] + P.b6[lrow];
      }
    }
  }
  __syncthreads();

  // ---- loss terms ----
  if (isP){
    if (tid < 16){
      const float* F = &fin[tid*20];
      float r = P.f1[2*(bid*16 + tid) + 1];
      float uz=F[0],  us=F[1],  ur=F[2];
      float uz_z=F[4],us_z=F[5],ur_z=F[6],p_z=F[7];
      float uz_r=F[8],us_r=F[9],ur_r=F[10],p_r=F[11];
      float uz_zz=F[12],us_zz=F[13],ur_zz=F[14];
      float uz_rr=F[16],us_rr=F[17],ur_rr=F[18];
      float invr = 1.f/r;
      float eq1 = ur*ur_r + uz*ur_z - us*us*invr + p_r
                - NUC*invr*ur_r - NUC*ur_rr - NUC*ur_zz + NUC*ur*invr*invr;
      float eq2 = ur*us_r + uz*us_z + ur*us*invr
                - NUC*invr*us_r - NUC*us_rr - NUC*us_zz + NUC*us*invr*invr;
      float eq3 = ur*uz_r + uz*uz_z + p_z
                - NUC*invr*uz_r - NUC*uz_rr - NUC*uz_zz;
      float eq4 = ur + r*ur_r + r*uz_z;
      red[tid] = (eq1*eq1 + eq2*eq2 + eq3*eq3 + eq4*eq4) * (1.0f/80000.f);
    }
    __syncthreads();
    if (tid == 0){
      float s = 0.f;
      #pragma unroll
      for (int i=0;i<16;++i) s += red[i];
      P.wsF[bid] = s;
    }
  } else {
    if (tid < 80){
      float dj0 = fin[tid*4+0], dj1 = fin[tid*4+1];
      float dj2 = fin[tid*4+2], dj3 = fin[tid*4+3];
      float bcp = 0.f, dap = 0.f;
      int g = bid*80 + tid;
      if (g < 37000){
        if      (g <  2000){ bcp = (dj0*dj0 + dj1*dj1 + dj2*dj2)*(1.0f/1000.f); }
        else if (g <  7000){ float d1 = dj1 - 1.f;
                             bcp = (dj0*dj0 + d1*d1 + dj2*dj2)*(1.0f/5000.f); }
        else if (g < 12000){ bcp = (dj0*dj0 + dj1*dj1 + dj2*dj2)*(1.0f/5000.f); }
        else if (g < 17000){ bcp = dj3*dj3*(1.0f/5000.f); }
        else { const float* rr = P.real + (g-17000)*4;
               float e0=dj0-rr[0], e1=dj1-rr[1], e2=dj2-rr[2], e3=dj3-rr[3];
               dap = (e0*e0 + e1*e1 + e2*e2 + e3*e3)*(1.0f/80000.f); }
      }
      red[tid] = bcp; redB[tid] = dap;
    }
    __syncthreads();
    if (tid == 0){
      float sA=0.f, sB=0.f;
      #pragma unroll
      for (int i=0;i<80;++i){ sA += red[i]; sB += redB[i]; }
      P.wsBC[bid] = sA; P.wsDA[bid] = sB;
    }
  }
}

// ---------------- final deterministic reduction ----------------
__global__ void reduce_kernel(const float* wsBC, const float* wsDA, const float* wsF,
                              float* out, int nbBC, int nbP){
  __shared__ float sm[256];
  const int tid = threadIdx.x;
  float a;

  a = 0.f; for (int i=tid;i<nbBC;i+=256) a += wsBC[i];
  sm[tid]=a; __syncthreads();
  for (int off=128; off>0; off>>=1){ if (tid<off) sm[tid]+=sm[tid+off]; __syncthreads(); }
  if (tid==0) out[0]=sm[0];
  __syncthreads();

  a = 0.f; for (int i=tid;i<nbBC;i+=256) a += wsDA[i];
  sm[tid]=a; __syncthreads();
  for (int off=128; off>0; off>>=1){ if (tid<off) sm[tid]+=sm[tid+off]; __syncthreads(); }
  if (tid==0) out[1]=sm[0];
  __syncthreads();

  a = 0.f; for (int i=tid;i<nbP;i+=256) a += wsF[i];
  sm[tid]=a; __syncthreads();
  for (int off=128; off>0; off>>=1){ if (tid<off) sm[tid]+=sm[tid+off]; __syncthreads(); }
  if (tid==0) out[2]=sm[0];
}

extern "C" void kernel_launch(void* const* d_in, const int* in_sizes, int n_in,
                              void* d_out, int out_size, void* d_ws, size_t ws_size,
                              hipStream_t stream){
  KP P;
  P.W0=(const float*)d_in[0];  P.b0=(const float*)d_in[1];
  P.W1=(const float*)d_in[2];  P.b1=(const float*)d_in[3];
  P.W2=(const float*)d_in[4];  P.b2=(const float*)d_in[5];
  P.W3=(const float*)d_in[6];  P.b3=(const float*)d_in[7];
  P.W4=(const float*)d_in[8];  P.b4=(const float*)d_in[9];
  P.W5=(const float*)d_in[10]; P.b5=(const float*)d_in[11];
  P.W6=(const float*)d_in[12]; P.b6=(const float*)d_in[13];
  P.bc1=(const float*)d_in[14]; P.bc2=(const float*)d_in[15];
  P.bc3=(const float*)d_in[16]; P.bc4=(const float*)d_in[17];
  P.bc5=(const float*)d_in[18]; P.f1=(const float*)d_in[19];
  P.inp=(const float*)d_in[20]; P.real=(const float*)d_in[21];

  unsigned short* wf = (unsigned short*)d_ws;
  P.Wfh  = wf;                  // 327680 ush
  P.Wfl  = wf + 327680;         // 327680 ush
  P.W6fh = wf + 655360;         // 4096 ush
  P.W6fl = wf + 659456;         // 4096 ush
  float* pb = (float*)((char*)d_ws + 1327104);
  P.wsBC = pb; P.wsDA = pb + 512; P.wsF = pb + 1024;   // 463,463,1250 used

  const int nbP  = 20000 / 16;           // 1250 pde blocks (16 pts)
  const int nbBC = (37000 + 79) / 80;    // 463 fwd blocks (80 pts)

  prep_kernel<<<dim3(1296), dim3(256), 0, stream>>>(
      P.W1, P.W2, P.W3, P.W4, P.W5, P.W6,
      (unsigned short*)wf, (unsigned short*)(wf + 327680),
      (unsigned short*)(wf + 655360), (unsigned short*)(wf + 659456));
  fused_kernel<<<dim3(nbP + nbBC), dim3(512), 0, stream>>>(P, nbP);
  reduce_kernel<<<dim3(1), dim3(256), 0, stream>>>(P.wsBC, P.wsDA, P.wsF,
                                                   (float*)d_out, nbBC, nbP);
}

// Round 13
// 155.833 us; speedup vs baseline: 3.1447x; 1.1096x over previous
//
#include <hip/hip_runtime.h>

#define NUC 8.0e-4f   // MIU/(U*L)

typedef _Float16 __attribute__((ext_vector_type(8))) f16x8;
typedef __attribute__((ext_vector_type(8))) unsigned short u16x8;
typedef __attribute__((ext_vector_type(4))) float   f32x4;

struct KP {
  const float *W0,*b0,*W1,*b1,*W2,*b2,*W3,*b3,*W4,*b4,*W5,*b5,*W6,*b6;
  const float *bc1,*bc2,*bc3,*bc4,*bc5,*f1,*inp,*real;
  const unsigned short *Wfh,*Wfl;     // frag-ordered fp16 hi/lo W1..W5
  const unsigned short *W6fh,*W6fl;   // frag-ordered fp16 hi/lo W6 (N padded to 16)
  float *wsBC,*wsDA,*wsF;
};

// fast tanh: t = 1 - 2*rcp(exp2(a*2log2e)+1); a=+inf->1, a=-inf->-1
__device__ __forceinline__ float ftanh(float a){
  float e = __builtin_amdgcn_exp2f(a * 2.88539008177792681472f);
  return 1.0f - 2.0f*__builtin_amdgcn_rcpf(e + 1.0f);
}
// fp16 split: hi = rne(v), lo = rne(v - hi)
__device__ __forceinline__ void splith(float v, unsigned short& h, unsigned short& l){
  _Float16 hh = (_Float16)v;
  float rem = v - (float)hh;
  _Float16 ll = (_Float16)rem;
  h = __builtin_bit_cast(unsigned short, hh);
  l = __builtin_bit_cast(unsigned short, ll);
}
__device__ __forceinline__ unsigned short cvth(float v){
  _Float16 hh = (_Float16)v;
  return __builtin_bit_cast(unsigned short, hh);
}
// A byte addr in [80][256] fp16 (row stride 512B), bank-swizzled
__device__ __forceinline__ int aswz(int row, int kbyte){
  int f = ((row & 7) ^ ((row & 8) >> 2)) << 4;
  return (row*512 + kbyte) ^ f;
}

// ---------------- prep: split W1..W5 (+W6 padded) into frag-ordered fp16 hi/lo ----------------
// frag order: [ks(8)][ntile][lane(64)][e(8)]; lane=((k&31)>>3)*16+(col&15), e=k&7
__global__ void prep_kernel(const float* W1, const float* W2, const float* W3,
                            const float* W4, const float* W5, const float* W6,
                            unsigned short* Wfh, unsigned short* Wfl,
                            unsigned short* W6fh, unsigned short* W6fl){
  int idx = blockIdx.x*256 + threadIdx.x;      // 0..331775
  if (idx < 327680){
    int li  = idx >> 16;
    int rem = idx & 65535;
    int k   = rem >> 8;
    int col = rem & 255;
    const float* Ws[5] = {W1,W2,W3,W4,W5};
    float v = Ws[li][k*256 + col];
    unsigned short hi, lo;
    splith(v, hi, lo);
    int ks = k >> 5, kr = k & 31, qq = kr >> 3, e = kr & 7;
    int lane = qq*16 + (col & 15), nt = col >> 4;
    int pos = li*65536 + (ks*16 + nt)*512 + lane*8 + e;
    Wfh[pos] = hi; Wfl[pos] = lo;
  } else {
    int t = idx - 327680;            // 0..4095: [ks(8)][lane(64)][e(8)]
    int ks = t >> 9, lane = (t & 511) >> 3, e = t & 7;
    int k = ks*32 + (lane >> 4)*8 + e;
    int col = lane & 15;
    float v = (col < 4) ? W6[k*4 + col] : 0.f;
    unsigned short hi, lo;
    splith(v, hi, lo);
    W6fh[t] = hi; W6fl[t] = lo;
  }
}

// ---------------- fused main kernel: 512 thr = 8 waves, M=80, N=256 ----------------
// fp16 selective precision + ping-pong A double-buffer (1 barrier/layer).
// layer li reads buf[li&1], writes buf[(li+1)&1]; layer0 -> buf0; layer6 reads buf1.
__global__ __launch_bounds__(512,4) void fused_kernel(KP P, int nbP){
  __shared__ unsigned char Abuf[81920];   // 2 x 40960 fp16 A [80][256]
  const int tid  = threadIdx.x;
  const int lane = tid & 63;
  const int wv   = tid >> 6;          // 0..7
  const int q    = lane >> 4;         // 0..3
  const int lrow = lane & 15;
  const bool isP = (int)blockIdx.x < nbP;
  const int bid  = isP ? (int)blockIdx.x : (int)blockIdx.x - nbP;

  // ---- layer 0 (2 -> 256), write A into buf0 ----
  {
    const int pt = tid >> 5;      // 0..15
    const int jg = tid & 31;      // 8-col group
    const int j0 = jg*8;
    float wz[8], wr[8], bb[8];
    #pragma unroll
    for (int jj=0;jj<8;++jj){ wz[jj]=P.W0[j0+jj]; wr[jj]=P.W0[256+j0+jj]; bb[jj]=P.b0[j0+jj]; }
    if (isP){
      int g = bid*16 + pt;
      float x0 = P.f1[2*g], x1 = P.f1[2*g+1];
      u16x8 hv[5];
      #pragma unroll
      for (int jj=0;jj<8;++jj){
        float a = x0*wz[jj] + x1*wr[jj] + bb[jj];
        float t = ftanh(a), s = 1.f - t*t, cc = -2.f*t*s;
        float o[5] = {t, s*wz[jj], s*wr[jj], cc*wz[jj]*wz[jj], cc*wr[jj]*wr[jj]};
        #pragma unroll
        for (int s_=0;s_<5;++s_) hv[s_][jj] = cvth(o[s_]);
      }
      #pragma unroll
      for (int s_=0;s_<5;++s_){
        int byte = aswz(s_*16 + pt, jg*16);
        *(u16x8*)(Abuf + byte) = hv[s_];
      }
    } else {
      #pragma unroll
      for (int pp=0;pp<5;++pp){
        int row = pt + 16*pp;
        int g = bid*80 + row;
        float x0 = 0.f, x1 = 0.f;
        if (g < 37000){
          const float* src; int li2;
          if      (g <  1000){ src=P.bc1; li2=g; }
          else if (g <  2000){ src=P.bc2; li2=g-1000; }
          else if (g <  7000){ src=P.bc3; li2=g-2000; }
          else if (g < 12000){ src=P.bc4; li2=g-7000; }
          else if (g < 17000){ src=P.bc5; li2=g-12000; }
          else               { src=P.inp; li2=g-17000; }
          x0 = src[2*li2]; x1 = src[2*li2+1];
        }
        u16x8 hv;
        #pragma unroll
        for (int jj=0;jj<8;++jj)
          hv[jj] = cvth(ftanh(x0*wz[jj] + x1*wr[jj] + bb[jj]));
        int byte = aswz(row, jg*16);
        *(u16x8*)(Abuf + byte) = hv;
      }
    }
  }

  // ---- layers 1..5: read buf[li&1], write buf[(li+1)&1]; ONE barrier/layer ----
  for (int li=0; li<5; ++li){
    const float* bl = (li==0)?P.b1:(li==1)?P.b2:(li==2)?P.b3:(li==3)?P.b4:P.b5;
    const unsigned short* WH = P.Wfh + li*65536;
    const unsigned short* WL = P.Wfl + li*65536;
    unsigned char* rb = Abuf + (li&1)*40960;
    unsigned char* wb = Abuf + ((li+1)&1)*40960;
    f32x4 acc[5][2];
    #pragma unroll
    for (int m=0;m<5;++m)
      #pragma unroll
      for (int n=0;n<2;++n){ acc[m][n][0]=0.f; acc[m][n][1]=0.f; acc[m][n][2]=0.f; acc[m][n][3]=0.f; }
    __syncthreads();   // prior writes to rb visible; prior reads of wb done
    #pragma unroll 1
    for (int ks=0; ks<8; ++ks){
      f16x8 bh0, bh1, bo0, bo1;
      {
        int idx = (ks*16 + wv*2)*512 + lane*8;
        bh0 = *(const f16x8*)(WH + idx);
        bh1 = *(const f16x8*)(WH + idx + 512);
        if (isP){
          bo0 = *(const f16x8*)(WL + idx);
          bo1 = *(const f16x8*)(WL + idx + 512);
        }
      }
      __builtin_amdgcn_s_setprio(1);
      #pragma unroll
      for (int m=0;m<5;++m){
        int byte = aswz(m*16 + lrow, ks*64 + q*16);
        f16x8 ah = *(const f16x8*)(rb + byte);
        acc[m][0] = __builtin_amdgcn_mfma_f32_16x16x32_f16(ah, bh0, acc[m][0], 0,0,0);
        acc[m][1] = __builtin_amdgcn_mfma_f32_16x16x32_f16(ah, bh1, acc[m][1], 0,0,0);
        if (m == 0 && isP){
          acc[0][0] = __builtin_amdgcn_mfma_f32_16x16x32_f16(ah, bo0, acc[0][0], 0,0,0);
          acc[0][1] = __builtin_amdgcn_mfma_f32_16x16x32_f16(ah, bo1, acc[0][1], 0,0,0);
        }
      }
      __builtin_amdgcn_s_setprio(0);
    }
    // epilogue writes to wb while laggards may still read rb — safe (disjoint)
    #pragma unroll
    for (int n=0;n<2;++n){
      int col = (wv*2+n)*16 + lrow;
      float bias = bl[col];
      #pragma unroll
      for (int r=0;r<4;++r){
        int rw = q*4 + r;
        if (isP){
          float a  = acc[0][n][r] + bias;
          float Dz = acc[1][n][r], Dr = acc[2][n][r];
          float Dzz= acc[3][n][r], Drr= acc[4][n][r];
          float t = ftanh(a), s = 1.f - t*t, cc = -2.f*t*s;
          float o[5] = {t, s*Dz, s*Dr, s*Dzz + cc*Dz*Dz, s*Drr + cc*Dr*Dr};
          #pragma unroll
          for (int s_=0;s_<5;++s_){
            int row = s_*16 + rw;
            *(unsigned short*)(wb + aswz(row, col*2)) = cvth(o[s_]);
          }
        } else {
          #pragma unroll
          for (int m=0;m<5;++m){
            int row = m*16 + rw;
            float t = ftanh(acc[m][n][r] + bias);
            *(unsigned short*)(wb + aswz(row, col*2)) = cvth(t);
          }
        }
      }
    }
  }
  __syncthreads();   // layer-5 A (buf1) visible

  // ---- layer 6 via MFMA: wave m (0..4) owns M-tile m; reads buf1 ----
  const unsigned char* fb = Abuf + 40960;
  f32x4 a6; a6[0]=0.f; a6[1]=0.f; a6[2]=0.f; a6[3]=0.f;
  if (wv < 5){
    #pragma unroll 1
    for (int ks=0; ks<8; ++ks){
      f16x8 bh = *(const f16x8*)(P.W6fh + ks*512 + lane*8);
      f16x8 bo = *(const f16x8*)(P.W6fl + ks*512 + lane*8);
      int byte = aswz(wv*16 + lrow, ks*64 + q*16);
      f16x8 ah = *(const f16x8*)(fb + byte);
      a6 = __builtin_amdgcn_mfma_f32_16x16x32_f16(ah, bh, a6, 0,0,0);
      a6 = __builtin_amdgcn_mfma_f32_16x16x32_f16(ah, bo, a6, 0,0,0);
    }
  }

  float* fin  = (float*)Abuf;            // buf0 region: pde [16][20]; fwd [80][4]
  float* red  = (float*)(Abuf + 4096);
  float* redB = (float*)(Abuf + 6144);

  // fin writes go to buf0 while layer-6 reads buf1 — disjoint, but we need
  // all waves' layer-5 epilogue reads of buf0 done: they were (last use of
  // buf0 was li=3 reads; li=4 wrote buf1; barrier above covers it).
  if (wv < 5 && lrow < 4){
    #pragma unroll
    for (int r=0;r<4;++r){
      if (isP){
        int pt = q*4 + r;
        float v = a6[r] + ((wv==0) ? P.b6[lrow] : 0.f);
        fin[pt*20 + wv*4 + lrow] = v;
      } else {
        int row = wv*16 + q*4 + r;
        fin[row*4 + lrow] = a6[r] + P.b6[lrow];
      }
    }
  }
  __syncthreads();

  // ---- loss terms ----
  if (isP){
    if (tid < 16){
      const float* F = &fin[tid*20];
      float r = P.f1[2*(bid*16 + tid) + 1];
      float uz=F[0],  us=F[1],  ur=F[2];
      float uz_z=F[4],us_z=F[5],ur_z=F[6],p_z=F[7];
      float uz_r=F[8],us_r=F[9],ur_r=F[10],p_r=F[11];
      float uz_zz=F[12],us_zz=F[13],ur_zz=F[14];
      float uz_rr=F[16],us_rr=F[17],ur_rr=F[18];
      float invr = 1.f/r;
      float eq1 = ur*ur_r + uz*ur_z - us*us*invr + p_r
                - NUC*invr*ur_r - NUC*ur_rr - NUC*ur_zz + NUC*ur*invr*invr;
      float eq2 = ur*us_r + uz*us_z + ur*us*invr
                - NUC*invr*us_r - NUC*us_rr - NUC*us_zz + NUC*us*invr*invr;
      float eq3 = ur*uz_r + uz*uz_z + p_z
                - NUC*invr*uz_r - NUC*uz_rr - NUC*uz_zz;
      float eq4 = ur + r*ur_r + r*uz_z;
      red[tid] = (eq1*eq1 + eq2*eq2 + eq3*eq3 + eq4*eq4) * (1.0f/80000.f);
    }
    __syncthreads();
    if (tid == 0){
      float s = 0.f;
      #pragma unroll
      for (int i=0;i<16;++i) s += red[i];
      P.wsF[bid] = s;
    }
  } else {
    if (tid < 80){
      float dj0 = fin[tid*4+0], dj1 = fin[tid*4+1];
      float dj2 = fin[tid*4+2], dj3 = fin[tid*4+3];
      float bcp = 0.f, dap = 0.f;
      int g = bid*80 + tid;
      if (g < 37000){
        if      (g <  2000){ bcp = (dj0*dj0 + dj1*dj1 + dj2*dj2)*(1.0f/1000.f); }
        else if (g <  7000){ float d1 = dj1 - 1.f;
                             bcp = (dj0*dj0 + d1*d1 + dj2*dj2)*(1.0f/5000.f); }
        else if (g < 12000){ bcp = (dj0*dj0 + dj1*dj1 + dj2*dj2)*(1.0f/5000.f); }
        else if (g < 17000){ bcp = dj3*dj3*(1.0f/5000.f); }
        else { const float* rr = P.real + (g-17000)*4;
               float e0=dj0-rr[0], e1=dj1-rr[1], e2=dj2-rr[2], e3=dj3-rr[3];
               dap = (e0*e0 + e1*e1 + e2*e2 + e3*e3)*(1.0f/80000.f); }
      }
      red[tid] = bcp; redB[tid] = dap;
    }
    __syncthreads();
    if (tid == 0){
      float sA=0.f, sB=0.f;
      #pragma unroll
      for (int i=0;i<80;++i){ sA += red[i]; sB += redB[i]; }
      P.wsBC[bid] = sA; P.wsDA[bid] = sB;
    }
  }
}

// ---------------- final deterministic reduction ----------------
__global__ void reduce_kernel(const float* wsBC, const float* wsDA, const float* wsF,
                              float* out, int nbBC, int nbP){
  __shared__ float sm[256];
  const int tid = threadIdx.x;
  float a;

  a = 0.f; for (int i=tid;i<nbBC;i+=256) a += wsBC[i];
  sm[tid]=a; __syncthreads();
  for (int off=128; off>0; off>>=1){ if (tid<off) sm[tid]+=sm[tid+off]; __syncthreads(); }
  if (tid==0) out[0]=sm[0];
  __syncthreads();

  a = 0.f; for (int i=tid;i<nbBC;i+=256) a += wsDA[i];
  sm[tid]=a; __syncthreads();
  for (int off=128; off>0; off>>=1){ if (tid<off) sm[tid]+=sm[tid+off]; __syncthreads(); }
  if (tid==0) out[1]=sm[0];
  __syncthreads();

  a = 0.f; for (int i=tid;i<nbP;i+=256) a += wsF[i];
  sm[tid]=a; __syncthreads();
  for (int off=128; off>0; off>>=1){ if (tid<off) sm[tid]+=sm[tid+off]; __syncthreads(); }
  if (tid==0) out[2]=sm[0];
}

extern "C" void kernel_launch(void* const* d_in, const int* in_sizes, int n_in,
                              void* d_out, int out_size, void* d_ws, size_t ws_size,
                              hipStream_t stream){
  KP P;
  P.W0=(const float*)d_in[0];  P.b0=(const float*)d_in[1];
  P.W1=(const float*)d_in[2];  P.b1=(const float*)d_in[3];
  P.W2=(const float*)d_in[4];  P.b2=(const float*)d_in[5];
  P.W3=(const float*)d_in[6];  P.b3=(const float*)d_in[7];
  P.W4=(const float*)d_in[8];  P.b4=(const float*)d_in[9];
  P.W5=(const float*)d_in[10]; P.b5=(const float*)d_in[11];
  P.W6=(const float*)d_in[12]; P.b6=(const float*)d_in[13];
  P.bc1=(const float*)d_in[14]; P.bc2=(const float*)d_in[15];
  P.bc3=(const float*)d_in[16]; P.bc4=(const float*)d_in[17];
  P.bc5=(const float*)d_in[18]; P.f1=(const float*)d_in[19];
  P.inp=(const float*)d_in[20]; P.real=(const float*)d_in[21];

  unsigned short* wf = (unsigned short*)d_ws;
  P.Wfh  = wf;                  // 327680 ush
  P.Wfl  = wf + 327680;         // 327680 ush
  P.W6fh = wf + 655360;         // 4096 ush
  P.W6fl = wf + 659456;         // 4096 ush
  float* pb = (float*)((char*)d_ws + 1327104);
  P.wsBC = pb; P.wsDA = pb + 512; P.wsF = pb + 1024;   // 463,463,1250 used

  const int nbP  = 20000 / 16;           // 1250 pde blocks (16 pts)
  const int nbBC = (37000 + 79) / 80;    // 463 fwd blocks (80 pts)

  prep_kernel<<<dim3(1296), dim3(256), 0, stream>>>(
      P.W1, P.W2, P.W3, P.W4, P.W5, P.W6,
      (unsigned short*)wf, (unsigned short*)(wf + 327680),
      (unsigned short*)(wf + 655360), (unsigned short*)(wf + 659456));
  fused_kernel<<<dim3(nbP + nbBC), dim3(512), 0, stream>>>(P, nbP);
  reduce_kernel<<<dim3(1), dim3(256), 0, stream>>>(P.wsBC, P.wsDA, P.wsF,
                                                   (float*)d_out, nbBC, nbP);
}

// Round 14
// 147.696 us; speedup vs baseline: 3.3180x; 1.0551x over previous
//
#include <hip/hip_runtime.h>

#define NUC 8.0e-4f   // MIU/(U*L)

typedef _Float16 __attribute__((ext_vector_type(8))) f16x8;
typedef __attribute__((ext_vector_type(8))) unsigned short u16x8;
typedef __attribute__((ext_vector_type(4))) float   f32x4;

struct KP {
  const float *W0,*b0,*W1,*b1,*W2,*b2,*W3,*b3,*W4,*b4,*W5,*b5,*W6,*b6;
  const float *bc1,*bc2,*bc3,*bc4,*bc5,*f1,*inp,*real;
  const unsigned short *Wfh,*Wfl;     // frag-ordered fp16 hi/lo W1..W5
  const unsigned short *W6fh,*W6fl;   // frag-ordered fp16 hi/lo W6 (N padded to 16)
  float *wsBC,*wsDA,*wsF;
};

// fast tanh: t = 1 - 2*rcp(exp2(a*2log2e)+1); a=+inf->1, a=-inf->-1
__device__ __forceinline__ float ftanh(float a){
  float e = __builtin_amdgcn_exp2f(a * 2.88539008177792681472f);
  return 1.0f - 2.0f*__builtin_amdgcn_rcpf(e + 1.0f);
}
// fp16 split: hi = rne(v), lo = rne(v - hi)
__device__ __forceinline__ void splith(float v, unsigned short& h, unsigned short& l){
  _Float16 hh = (_Float16)v;
  float rem = v - (float)hh;
  _Float16 ll = (_Float16)rem;
  h = __builtin_bit_cast(unsigned short, hh);
  l = __builtin_bit_cast(unsigned short, ll);
}
__device__ __forceinline__ unsigned short cvth(float v){
  _Float16 hh = (_Float16)v;
  return __builtin_bit_cast(unsigned short, hh);
}
// A byte addr in [80][256] fp16 (row stride 512B), bank-swizzled.
// NOTE: hot paths use the hoisted-identity form; this helper remains for prep/L0.
__device__ __forceinline__ int aswz(int row, int kbyte){
  int f = ((row & 7) ^ ((row & 8) >> 2)) << 4;
  return (row*512 + kbyte) ^ f;
}

// ---------------- prep: split W1..W5 (+W6 padded) into frag-ordered fp16 hi/lo ----------------
// frag order: [ks(8)][ntile][lane(64)][e(8)]; lane=((k&31)>>3)*16+(col&15), e=k&7
__global__ void prep_kernel(const float* W1, const float* W2, const float* W3,
                            const float* W4, const float* W5, const float* W6,
                            unsigned short* Wfh, unsigned short* Wfl,
                            unsigned short* W6fh, unsigned short* W6fl){
  int idx = blockIdx.x*256 + threadIdx.x;      // 0..331775
  if (idx < 327680){
    int li  = idx >> 16;
    int rem = idx & 65535;
    int k   = rem >> 8;
    int col = rem & 255;
    const float* Ws[5] = {W1,W2,W3,W4,W5};
    float v = Ws[li][k*256 + col];
    unsigned short hi, lo;
    splith(v, hi, lo);
    int ks = k >> 5, kr = k & 31, qq = kr >> 3, e = kr & 7;
    int lane = qq*16 + (col & 15), nt = col >> 4;
    int pos = li*65536 + (ks*16 + nt)*512 + lane*8 + e;
    Wfh[pos] = hi; Wfl[pos] = lo;
  } else {
    int t = idx - 327680;            // 0..4095: [ks(8)][lane(64)][e(8)]
    int ks = t >> 9, lane = (t & 511) >> 3, e = t & 7;
    int k = ks*32 + (lane >> 4)*8 + e;
    int col = lane & 15;
    float v = (col < 4) ? W6[k*4 + col] : 0.f;
    unsigned short hi, lo;
    splith(v, hi, lo);
    W6fh[t] = hi; W6fl[t] = lo;
  }
}

// ---------------- fused main kernel: 512 thr = 8 waves, M=80, N=256 ----------------
// fp16 selective precision + ping-pong A double-buffer + hoisted swizzle addressing.
__global__ __launch_bounds__(512,4) void fused_kernel(KP P, int nbP){
  __shared__ unsigned char Abuf[81920];   // 2 x 40960 fp16 A [80][256]
  const int tid  = threadIdx.x;
  const int lane = tid & 63;
  const int wv   = tid >> 6;          // 0..7
  const int q    = lane >> 4;         // 0..3
  const int lrow = lane & 15;
  const bool isP = (int)blockIdx.x < nbP;
  const int bid  = isP ? (int)blockIdx.x : (int)blockIdx.x - nbP;

  // hoisted swizzle pieces (identical address mapping; bit-fields disjoint)
  const int fr    = ((lrow & 7) ^ ((lrow & 8) >> 2)) << 4;   // f(row) for row&15==lrow
  const int abase = lrow*512 + q*16;                          // + ks*64, ^fr, + m*8192
  const int qa = (q & 1) * 4, qb = (q >> 1) * 2;              // f pieces for rw=q*4+r

  // ---- layer 0 (2 -> 256), write A into buf0 ----
  {
    const int pt = tid >> 5;      // 0..15
    const int jg = tid & 31;      // 8-col group
    const int j0 = jg*8;
    const int f0 = ((pt & 7) ^ ((pt & 8) >> 2)) << 4;
    const int b0 = (pt*512 + jg*16) ^ f0;     // + s_*8192 (or pp*8192)
    float wz[8], wr[8], bb[8];
    #pragma unroll
    for (int jj=0;jj<8;++jj){ wz[jj]=P.W0[j0+jj]; wr[jj]=P.W0[256+j0+jj]; bb[jj]=P.b0[j0+jj]; }
    if (isP){
      int g = bid*16 + pt;
      float x0 = P.f1[2*g], x1 = P.f1[2*g+1];
      u16x8 hv[5];
      #pragma unroll
      for (int jj=0;jj<8;++jj){
        float a = x0*wz[jj] + x1*wr[jj] + bb[jj];
        float t = ftanh(a), s = 1.f - t*t, cc = -2.f*t*s;
        float o[5] = {t, s*wz[jj], s*wr[jj], cc*wz[jj]*wz[jj], cc*wr[jj]*wr[jj]};
        #pragma unroll
        for (int s_=0;s_<5;++s_) hv[s_][jj] = cvth(o[s_]);
      }
      #pragma unroll
      for (int s_=0;s_<5;++s_)
        *(u16x8*)(Abuf + b0 + s_*8192) = hv[s_];
    } else {
      #pragma unroll
      for (int pp=0;pp<5;++pp){
        int g = bid*80 + pt + 16*pp;
        float x0 = 0.f, x1 = 0.f;
        if (g < 37000){
          const float* src; int li2;
          if      (g <  1000){ src=P.bc1; li2=g; }
          else if (g <  2000){ src=P.bc2; li2=g-1000; }
          else if (g <  7000){ src=P.bc3; li2=g-2000; }
          else if (g < 12000){ src=P.bc4; li2=g-7000; }
          else if (g < 17000){ src=P.bc5; li2=g-12000; }
          else               { src=P.inp; li2=g-17000; }
          x0 = src[2*li2]; x1 = src[2*li2+1];
        }
        u16x8 hv;
        #pragma unroll
        for (int jj=0;jj<8;++jj)
          hv[jj] = cvth(ftanh(x0*wz[jj] + x1*wr[jj] + bb[jj]));
        *(u16x8*)(Abuf + b0 + pp*8192) = hv;
      }
    }
  }

  // ---- layers 1..5: read buf[li&1], write buf[(li+1)&1]; ONE barrier/layer ----
  for (int li=0; li<5; ++li){
    const float* bl = (li==0)?P.b1:(li==1)?P.b2:(li==2)?P.b3:(li==3)?P.b4:P.b5;
    const unsigned short* WH = P.Wfh + li*65536;
    const unsigned short* WL = P.Wfl + li*65536;
    unsigned char* rb = Abuf + (li&1)*40960;
    unsigned char* wb = Abuf + ((li+1)&1)*40960;
    f32x4 acc[5][2];
    #pragma unroll
    for (int m=0;m<5;++m)
      #pragma unroll
      for (int n=0;n<2;++n){ acc[m][n][0]=0.f; acc[m][n][1]=0.f; acc[m][n][2]=0.f; acc[m][n][3]=0.f; }
    __syncthreads();   // prior writes to rb visible; prior reads of wb done
    #pragma unroll 1
    for (int ks=0; ks<8; ++ks){
      f16x8 bh0, bh1, bo0, bo1;
      {
        int idx = (ks*16 + wv*2)*512 + lane*8;
        bh0 = *(const f16x8*)(WH + idx);
        bh1 = *(const f16x8*)(WH + idx + 512);
        if (isP){
          bo0 = *(const f16x8*)(WL + idx);
          bo1 = *(const f16x8*)(WL + idx + 512);
        }
      }
      const int aaddr = (abase + ks*64) ^ fr;     // shared base; +m*8192 folds to offset
      __builtin_amdgcn_s_setprio(1);
      #pragma unroll
      for (int m=0;m<5;++m){
        f16x8 ah = *(const f16x8*)(rb + aaddr + m*8192);
        acc[m][0] = __builtin_amdgcn_mfma_f32_16x16x32_f16(ah, bh0, acc[m][0], 0,0,0);
        acc[m][1] = __builtin_amdgcn_mfma_f32_16x16x32_f16(ah, bh1, acc[m][1], 0,0,0);
        if (m == 0 && isP){
          acc[0][0] = __builtin_amdgcn_mfma_f32_16x16x32_f16(ah, bo0, acc[0][0], 0,0,0);
          acc[0][1] = __builtin_amdgcn_mfma_f32_16x16x32_f16(ah, bo1, acc[0][1], 0,0,0);
        }
      }
      __builtin_amdgcn_s_setprio(0);
    }
    // epilogue writes to wb while laggards may still read rb — safe (disjoint)
    #pragma unroll
    for (int n=0;n<2;++n){
      const int col  = (wv*2+n)*16 + lrow;
      const int col2 = col*2;
      const float bias = bl[col];
      #pragma unroll
      for (int r=0;r<4;++r){
        const int fe  = ((qa + r) ^ qb) << 4;
        const int snr = q*2048 + r*512 + (col2 ^ fe);   // + s_*8192 (or m*8192)
        if (isP){
          float a  = acc[0][n][r] + bias;
          float Dz = acc[1][n][r], Dr = acc[2][n][r];
          float Dzz= acc[3][n][r], Drr= acc[4][n][r];
          float t = ftanh(a), s = 1.f - t*t, cc = -2.f*t*s;
          float o[5] = {t, s*Dz, s*Dr, s*Dzz + cc*Dz*Dz, s*Drr + cc*Dr*Dr};
          #pragma unroll
          for (int s_=0;s_<5;++s_)
            *(unsigned short*)(wb + snr + s_*8192) = cvth(o[s_]);
        } else {
          #pragma unroll
          for (int m=0;m<5;++m){
            float t = ftanh(acc[m][n][r] + bias);
            *(unsigned short*)(wb + snr + m*8192) = cvth(t);
          }
        }
      }
    }
  }
  __syncthreads();   // layer-5 A (buf1) visible

  // ---- layer 6 via MFMA: wave m (0..4) owns M-tile m; reads buf1 ----
  const unsigned char* fb = Abuf + 40960;
  f32x4 a6; a6[0]=0.f; a6[1]=0.f; a6[2]=0.f; a6[3]=0.f;
  if (wv < 5){
    const int b6 = wv*8192;
    #pragma unroll 1
    for (int ks=0; ks<8; ++ks){
      f16x8 bh = *(const f16x8*)(P.W6fh + ks*512 + lane*8);
      f16x8 bo = *(const f16x8*)(P.W6fl + ks*512 + lane*8);
      f16x8 ah = *(const f16x8*)(fb + (((abase + ks*64) ^ fr) + b6));
      a6 = __builtin_amdgcn_mfma_f32_16x16x32_f16(ah, bh, a6, 0,0,0);
      a6 = __builtin_amdgcn_mfma_f32_16x16x32_f16(ah, bo, a6, 0,0,0);
    }
  }

  float* fin  = (float*)Abuf;            // buf0 region: pde [16][20]; fwd [80][4]
  float* red  = (float*)(Abuf + 4096);
  float* redB = (float*)(Abuf + 6144);

  if (wv < 5 && lrow < 4){
    #pragma unroll
    for (int r=0;r<4;++r){
      if (isP){
        int pt = q*4 + r;
        float v = a6[r] + ((wv==0) ? P.b6[lrow] : 0.f);
        fin[pt*20 + wv*4 + lrow] = v;
      } else {
        int row = wv*16 + q*4 + r;
        fin[row*4 + lrow] = a6[r] + P.b6[lrow];
      }
    }
  }
  __syncthreads();

  // ---- loss terms ----
  if (isP){
    if (tid < 16){
      const float* F = &fin[tid*20];
      float r = P.f1[2*(bid*16 + tid) + 1];
      float uz=F[0],  us=F[1],  ur=F[2];
      float uz_z=F[4],us_z=F[5],ur_z=F[6],p_z=F[7];
      float uz_r=F[8],us_r=F[9],ur_r=F[10],p_r=F[11];
      float uz_zz=F[12],us_zz=F[13],ur_zz=F[14];
      float uz_rr=F[16],us_rr=F[17],ur_rr=F[18];
      float invr = 1.f/r;
      float eq1 = ur*ur_r + uz*ur_z - us*us*invr + p_r
                - NUC*invr*ur_r - NUC*ur_rr - NUC*ur_zz + NUC*ur*invr*invr;
      float eq2 = ur*us_r + uz*us_z + ur*us*invr
                - NUC*invr*us_r - NUC*us_rr - NUC*us_zz + NUC*us*invr*invr;
      float eq3 = ur*uz_r + uz*uz_z + p_z
                - NUC*invr*uz_r - NUC*uz_rr - NUC*uz_zz;
      float eq4 = ur + r*ur_r + r*uz_z;
      red[tid] = (eq1*eq1 + eq2*eq2 + eq3*eq3 + eq4*eq4) * (1.0f/80000.f);
    }
    __syncthreads();
    if (tid == 0){
      float s = 0.f;
      #pragma unroll
      for (int i=0;i<16;++i) s += red[i];
      P.wsF[bid] = s;
    }
  } else {
    if (tid < 80){
      float dj0 = fin[tid*4+0], dj1 = fin[tid*4+1];
      float dj2 = fin[tid*4+2], dj3 = fin[tid*4+3];
      float bcp = 0.f, dap = 0.f;
      int g = bid*80 + tid;
      if (g < 37000){
        if      (g <  2000){ bcp = (dj0*dj0 + dj1*dj1 + dj2*dj2)*(1.0f/1000.f); }
        else if (g <  7000){ float d1 = dj1 - 1.f;
                             bcp = (dj0*dj0 + d1*d1 + dj2*dj2)*(1.0f/5000.f); }
        else if (g < 12000){ bcp = (dj0*dj0 + dj1*dj1 + dj2*dj2)*(1.0f/5000.f); }
        else if (g < 17000){ bcp = dj3*dj3*(1.0f/5000.f); }
        else { const float* rr = P.real + (g-17000)*4;
               float e0=dj0-rr[0], e1=dj1-rr[1], e2=dj2-rr[2], e3=dj3-rr[3];
               dap = (e0*e0 + e1*e1 + e2*e2 + e3*e3)*(1.0f/80000.f); }
      }
      red[tid] = bcp; redB[tid] = dap;
    }
    __syncthreads();
    if (tid == 0){
      float sA=0.f, sB=0.f;
      #pragma unroll
      for (int i=0;i<80;++i){ sA += red[i]; sB += redB[i]; }
      P.wsBC[bid] = sA; P.wsDA[bid] = sB;
    }
  }
}

// ---------------- final deterministic reduction ----------------
__global__ void reduce_kernel(const float* wsBC, const float* wsDA, const float* wsF,
                              float* out, int nbBC, int nbP){
  __shared__ float sm[256];
  const int tid = threadIdx.x;
  float a;

  a = 0.f; for (int i=tid;i<nbBC;i+=256) a += wsBC[i];
  sm[tid]=a; __syncthreads();
  for (int off=128; off>0; off>>=1){ if (tid<off) sm[tid]+=sm[tid+off]; __syncthreads(); }
  if (tid==0) out[0]=sm[0];
  __syncthreads();

  a = 0.f; for (int i=tid;i<nbBC;i+=256) a += wsDA[i];
  sm[tid]=a; __syncthreads();
  for (int off=128; off>0; off>>=1){ if (tid<off) sm[tid]+=sm[tid+off]; __syncthreads(); }
  if (tid==0) out[1]=sm[0];
  __syncthreads();

  a = 0.f; for (int i=tid;i<nbP;i+=256) a += wsF[i];
  sm[tid]=a; __syncthreads();
  for (int off=128; off>0; off>>=1){ if (tid<off) sm[tid]+=sm[tid+off]; __syncthreads(); }
  if (tid==0) out[2]=sm[0];
}

extern "C" void kernel_launch(void* const* d_in, const int* in_sizes, int n_in,
                              void* d_out, int out_size, void* d_ws, size_t ws_size,
                              hipStream_t stream){
  KP P;
  P.W0=(const float*)d_in[0];  P.b0=(const float*)d_in[1];
  P.W1=(const float*)d_in[2];  P.b1=(const float*)d_in[3];
  P.W2=(const float*)d_in[4];  P.b2=(const float*)d_in[5];
  P.W3=(const float*)d_in[6];  P.b3=(const float*)d_in[7];
  P.W4=(const float*)d_in[8];  P.b4=(const float*)d_in[9];
  P.W5=(const float*)d_in[10]; P.b5=(const float*)d_in[11];
  P.W6=(const float*)d_in[12]; P.b6=(const float*)d_in[13];
  P.bc1=(const float*)d_in[14]; P.bc2=(const float*)d_in[15];
  P.bc3=(const float*)d_in[16]; P.bc4=(const float*)d_in[17];
  P.bc5=(const float*)d_in[18]; P.f1=(const float*)d_in[19];
  P.inp=(const float*)d_in[20]; P.real=(const float*)d_in[21];

  unsigned short* wf = (unsigned short*)d_ws;
  P.Wfh  = wf;                  // 327680 ush
  P.Wfl  = wf + 327680;         // 327680 ush
  P.W6fh = wf + 655360;         // 4096 ush
  P.W6fl = wf + 659456;         // 4096 ush
  float* pb = (float*)((char*)d_ws + 1327104);
  P.wsBC = pb; P.wsDA = pb + 512; P.wsF = pb + 1024;   // 463,463,1250 used

  const int nbP  = 20000 / 16;           // 1250 pde blocks (16 pts)
  const int nbBC = (37000 + 79) / 80;    // 463 fwd blocks (80 pts)

  prep_kernel<<<dim3(1296), dim3(256), 0, stream>>>(
      P.W1, P.W2, P.W3, P.W4, P.W5, P.W6,
      (unsigned short*)wf, (unsigned short*)(wf + 327680),
      (unsigned short*)(wf + 655360), (unsigned short*)(wf + 659456));
  fused_kernel<<<dim3(nbP + nbBC), dim3(512), 0, stream>>>(P, nbP);
  reduce_kernel<<<dim3(1), dim3(256), 0, stream>>>(P.wsBC, P.wsDA, P.wsF,
                                                   (float*)d_out, nbBC, nbP);
}

// Round 15
// 146.177 us; speedup vs baseline: 3.3525x; 1.0104x over previous
//
#include <hip/hip_runtime.h>

#define NUC 8.0e-4f   // MIU/(U*L)

typedef _Float16 __attribute__((ext_vector_type(8))) f16x8;
typedef __attribute__((ext_vector_type(8))) unsigned short u16x8;
typedef __attribute__((ext_vector_type(4))) float   f32x4;

struct KP {
  const float *W0,*b0,*W1,*b1,*W2,*b2,*W3,*b3,*W4,*b4,*W5,*b5,*W6,*b6;
  const float *bc1,*bc2,*bc3,*bc4,*bc5,*f1,*inp,*real;
  const unsigned short *Wfh,*Wfl;     // frag-ordered fp16 hi/lo W1..W5
  const unsigned short *W6fh,*W6fl;   // frag-ordered fp16 hi/lo W6 (N padded to 16)
  float *wsBC,*wsDA,*wsF;
};

// fast tanh: t = 1 - 2*rcp(exp2(a*2log2e)+1); a=+inf->1, a=-inf->-1
__device__ __forceinline__ float ftanh(float a){
  float e = __builtin_amdgcn_exp2f(a * 2.88539008177792681472f);
  return 1.0f - 2.0f*__builtin_amdgcn_rcpf(e + 1.0f);
}
// fp16 split: hi = rne(v), lo = rne(v - hi)
__device__ __forceinline__ void splith(float v, unsigned short& h, unsigned short& l){
  _Float16 hh = (_Float16)v;
  float rem = v - (float)hh;
  _Float16 ll = (_Float16)rem;
  h = __builtin_bit_cast(unsigned short, hh);
  l = __builtin_bit_cast(unsigned short, ll);
}
__device__ __forceinline__ unsigned short cvth(float v){
  _Float16 hh = (_Float16)v;
  return __builtin_bit_cast(unsigned short, hh);
}
// A byte addr in [80][256] fp16 (row stride 512B), bank-swizzled (prep/L0 helper)
__device__ __forceinline__ int aswz(int row, int kbyte){
  int f = ((row & 7) ^ ((row & 8) >> 2)) << 4;
  return (row*512 + kbyte) ^ f;
}

// ---------------- prep: split W1..W5 (+W6 padded) into frag-ordered fp16 hi/lo ----------------
// frag order: [ks(8)][ntile][lane(64)][e(8)]; lane=((k&31)>>3)*16+(col&15), e=k&7
__global__ void prep_kernel(const float* W1, const float* W2, const float* W3,
                            const float* W4, const float* W5, const float* W6,
                            unsigned short* Wfh, unsigned short* Wfl,
                            unsigned short* W6fh, unsigned short* W6fl){
  int idx = blockIdx.x*256 + threadIdx.x;      // 0..331775
  if (idx < 327680){
    int li  = idx >> 16;
    int rem = idx & 65535;
    int k   = rem >> 8;
    int col = rem & 255;
    const float* Ws[5] = {W1,W2,W3,W4,W5};
    float v = Ws[li][k*256 + col];
    unsigned short hi, lo;
    splith(v, hi, lo);
    int ks = k >> 5, kr = k & 31, qq = kr >> 3, e = kr & 7;
    int lane = qq*16 + (col & 15), nt = col >> 4;
    int pos = li*65536 + (ks*16 + nt)*512 + lane*8 + e;
    Wfh[pos] = hi; Wfl[pos] = lo;
  } else {
    int t = idx - 327680;            // 0..4095: [ks(8)][lane(64)][e(8)]
    int ks = t >> 9, lane = (t & 511) >> 3, e = t & 7;
    int k = ks*32 + (lane >> 4)*8 + e;
    int col = lane & 15;
    float v = (col < 4) ? W6[k*4 + col] : 0.f;
    unsigned short hi, lo;
    splith(v, hi, lo);
    W6fh[t] = hi; W6fl[t] = lo;
  }
}

// ---------------- fused main kernel: 512 thr = 8 waves, M=80, N=256 ----------------
// fp16 selective precision + ping-pong A dbuf + hoisted swizzle + B software pipeline.
__global__ __launch_bounds__(512,4) void fused_kernel(KP P, int nbP){
  __shared__ unsigned char Abuf[81920];   // 2 x 40960 fp16 A [80][256]
  const int tid  = threadIdx.x;
  const int lane = tid & 63;
  const int wv   = tid >> 6;          // 0..7
  const int q    = lane >> 4;         // 0..3
  const int lrow = lane & 15;
  const bool isP = (int)blockIdx.x < nbP;
  const int bid  = isP ? (int)blockIdx.x : (int)blockIdx.x - nbP;

  // hoisted swizzle pieces (identical address mapping; bit-fields disjoint)
  const int fr    = ((lrow & 7) ^ ((lrow & 8) >> 2)) << 4;   // f(row) for row&15==lrow
  const int abase = lrow*512 + q*16;                          // + ks*64, ^fr, + m*8192
  const int qa = (q & 1) * 4, qb = (q >> 1) * 2;              // f pieces for rw=q*4+r

  // ---- layer 0 (2 -> 256), write A into buf0 ----
  {
    const int pt = tid >> 5;      // 0..15
    const int jg = tid & 31;      // 8-col group
    const int j0 = jg*8;
    const int f0 = ((pt & 7) ^ ((pt & 8) >> 2)) << 4;
    const int b0 = (pt*512 + jg*16) ^ f0;     // + s_*8192 (or pp*8192)
    float wz[8], wr[8], bb[8];
    #pragma unroll
    for (int jj=0;jj<8;++jj){ wz[jj]=P.W0[j0+jj]; wr[jj]=P.W0[256+j0+jj]; bb[jj]=P.b0[j0+jj]; }
    if (isP){
      int g = bid*16 + pt;
      float x0 = P.f1[2*g], x1 = P.f1[2*g+1];
      u16x8 hv[5];
      #pragma unroll
      for (int jj=0;jj<8;++jj){
        float a = x0*wz[jj] + x1*wr[jj] + bb[jj];
        float t = ftanh(a), s = 1.f - t*t, cc = -2.f*t*s;
        float o[5] = {t, s*wz[jj], s*wr[jj], cc*wz[jj]*wz[jj], cc*wr[jj]*wr[jj]};
        #pragma unroll
        for (int s_=0;s_<5;++s_) hv[s_][jj] = cvth(o[s_]);
      }
      #pragma unroll
      for (int s_=0;s_<5;++s_)
        *(u16x8*)(Abuf + b0 + s_*8192) = hv[s_];
    } else {
      #pragma unroll
      for (int pp=0;pp<5;++pp){
        int g = bid*80 + pt + 16*pp;
        float x0 = 0.f, x1 = 0.f;
        if (g < 37000){
          const float* src; int li2;
          if      (g <  1000){ src=P.bc1; li2=g; }
          else if (g <  2000){ src=P.bc2; li2=g-1000; }
          else if (g <  7000){ src=P.bc3; li2=g-2000; }
          else if (g < 12000){ src=P.bc4; li2=g-7000; }
          else if (g < 17000){ src=P.bc5; li2=g-12000; }
          else               { src=P.inp; li2=g-17000; }
          x0 = src[2*li2]; x1 = src[2*li2+1];
        }
        u16x8 hv;
        #pragma unroll
        for (int jj=0;jj<8;++jj)
          hv[jj] = cvth(ftanh(x0*wz[jj] + x1*wr[jj] + bb[jj]));
        *(u16x8*)(Abuf + b0 + pp*8192) = hv;
      }
    }
  }

  // ---- layers 1..5: read buf[li&1], write buf[(li+1)&1]; ONE barrier/layer ----
  for (int li=0; li<5; ++li){
    const float* bl = (li==0)?P.b1:(li==1)?P.b2:(li==2)?P.b3:(li==3)?P.b4:P.b5;
    const unsigned short* WH = P.Wfh + li*65536;
    const unsigned short* WL = P.Wfl + li*65536;
    unsigned char* rb = Abuf + (li&1)*40960;
    unsigned char* wb = Abuf + ((li+1)&1)*40960;
    f32x4 acc[5][2];
    #pragma unroll
    for (int m=0;m<5;++m)
      #pragma unroll
      for (int n=0;n<2;++n){ acc[m][n][0]=0.f; acc[m][n][1]=0.f; acc[m][n][2]=0.f; acc[m][n][3]=0.f; }

    auto loadB = [&](int ks, f16x8& h0, f16x8& h1, f16x8& o0, f16x8& o1){
      int idx = (ks*16 + wv*2)*512 + lane*8;
      h0 = *(const f16x8*)(WH + idx);
      h1 = *(const f16x8*)(WH + idx + 512);
      if (isP){
        o0 = *(const f16x8*)(WL + idx);
        o1 = *(const f16x8*)(WL + idx + 512);
      }
    };
    auto mm = [&](int ks, f16x8& h0, f16x8& h1, f16x8& o0, f16x8& o1){
      const int aaddr = (abase + ks*64) ^ fr;     // shared base; +m*8192 folds to offset
      __builtin_amdgcn_s_setprio(1);
      #pragma unroll
      for (int m=0;m<5;++m){
        f16x8 ah = *(const f16x8*)(rb + aaddr + m*8192);
        acc[m][0] = __builtin_amdgcn_mfma_f32_16x16x32_f16(ah, h0, acc[m][0], 0,0,0);
        acc[m][1] = __builtin_amdgcn_mfma_f32_16x16x32_f16(ah, h1, acc[m][1], 0,0,0);
        if (m == 0 && isP){
          acc[0][0] = __builtin_amdgcn_mfma_f32_16x16x32_f16(ah, o0, acc[0][0], 0,0,0);
          acc[0][1] = __builtin_amdgcn_mfma_f32_16x16x32_f16(ah, o1, acc[0][1], 0,0,0);
        }
      }
      __builtin_amdgcn_s_setprio(0);
    };

    __syncthreads();   // prior writes to rb visible; prior reads of wb done

    // B software pipeline, depth 1, unroll-by-2 register rotation (no copies)
    f16x8 Ah0{}, Ah1{}, Ao0{}, Ao1{}, Bh0{}, Bh1{}, Bo0{}, Bo1{};
    loadB(0, Ah0, Ah1, Ao0, Ao1);
    #pragma unroll 1
    for (int ks=0; ks<8; ks+=2){
      loadB(ks+1, Bh0, Bh1, Bo0, Bo1);
      mm(ks, Ah0, Ah1, Ao0, Ao1);
      if (ks+2 < 8) loadB(ks+2, Ah0, Ah1, Ao0, Ao1);
      mm(ks+1, Bh0, Bh1, Bo0, Bo1);
    }

    // epilogue writes to wb while laggards may still read rb — safe (disjoint)
    #pragma unroll
    for (int n=0;n<2;++n){
      const int col  = (wv*2+n)*16 + lrow;
      const int col2 = col*2;
      const float bias = bl[col];
      #pragma unroll
      for (int r=0;r<4;++r){
        const int fe  = ((qa + r) ^ qb) << 4;
        const int snr = q*2048 + r*512 + (col2 ^ fe);   // + s_*8192 (or m*8192)
        if (isP){
          float a  = acc[0][n][r] + bias;
          float Dz = acc[1][n][r], Dr = acc[2][n][r];
          float Dzz= acc[3][n][r], Drr= acc[4][n][r];
          float t = ftanh(a), s = 1.f - t*t, cc = -2.f*t*s;
          float o[5] = {t, s*Dz, s*Dr, s*Dzz + cc*Dz*Dz, s*Drr + cc*Dr*Dr};
          #pragma unroll
          for (int s_=0;s_<5;++s_)
            *(unsigned short*)(wb + snr + s_*8192) = cvth(o[s_]);
        } else {
          #pragma unroll
          for (int m=0;m<5;++m){
            float t = ftanh(acc[m][n][r] + bias);
            *(unsigned short*)(wb + snr + m*8192) = cvth(t);
          }
        }
      }
    }
  }
  __syncthreads();   // layer-5 A (buf1) visible

  // ---- layer 6 via MFMA: wave m (0..4) owns M-tile m; reads buf1 ----
  const unsigned char* fb = Abuf + 40960;
  f32x4 a6; a6[0]=0.f; a6[1]=0.f; a6[2]=0.f; a6[3]=0.f;
  if (wv < 5){
    const int b6 = wv*8192;
    #pragma unroll 1
    for (int ks=0; ks<8; ++ks){
      f16x8 bh = *(const f16x8*)(P.W6fh + ks*512 + lane*8);
      f16x8 bo = *(const f16x8*)(P.W6fl + ks*512 + lane*8);
      f16x8 ah = *(const f16x8*)(fb + (((abase + ks*64) ^ fr) + b6));
      a6 = __builtin_amdgcn_mfma_f32_16x16x32_f16(ah, bh, a6, 0,0,0);
      a6 = __builtin_amdgcn_mfma_f32_16x16x32_f16(ah, bo, a6, 0,0,0);
    }
  }

  float* fin  = (float*)Abuf;            // buf0 region: pde [16][20]; fwd [80][4]
  float* red  = (float*)(Abuf + 4096);
  float* redB = (float*)(Abuf + 6144);

  if (wv < 5 && lrow < 4){
    #pragma unroll
    for (int r=0;r<4;++r){
      if (isP){
        int pt = q*4 + r;
        float v = a6[r] + ((wv==0) ? P.b6[lrow] : 0.f);
        fin[pt*20 + wv*4 + lrow] = v;
      } else {
        int row = wv*16 + q*4 + r;
        fin[row*4 + lrow] = a6[r] + P.b6[lrow];
      }
    }
  }
  __syncthreads();

  // ---- loss terms ----
  if (isP){
    if (tid < 16){
      const float* F = &fin[tid*20];
      float r = P.f1[2*(bid*16 + tid) + 1];
      float uz=F[0],  us=F[1],  ur=F[2];
      float uz_z=F[4],us_z=F[5],ur_z=F[6],p_z=F[7];
      float uz_r=F[8],us_r=F[9],ur_r=F[10],p_r=F[11];
      float uz_zz=F[12],us_zz=F[13],ur_zz=F[14];
      float uz_rr=F[16],us_rr=F[17],ur_rr=F[18];
      float invr = 1.f/r;
      float eq1 = ur*ur_r + uz*ur_z - us*us*invr + p_r
                - NUC*invr*ur_r - NUC*ur_rr - NUC*ur_zz + NUC*ur*invr*invr;
      float eq2 = ur*us_r + uz*us_z + ur*us*invr
                - NUC*invr*us_r - NUC*us_rr - NUC*us_zz + NUC*us*invr*invr;
      float eq3 = ur*uz_r + uz*uz_z + p_z
                - NUC*invr*uz_r - NUC*uz_rr - NUC*uz_zz;
      float eq4 = ur + r*ur_r + r*uz_z;
      red[tid] = (eq1*eq1 + eq2*eq2 + eq3*eq3 + eq4*eq4) * (1.0f/80000.f);
    }
    __syncthreads();
    if (tid == 0){
      float s = 0.f;
      #pragma unroll
      for (int i=0;i<16;++i) s += red[i];
      P.wsF[bid] = s;
    }
  } else {
    if (tid < 80){
      float dj0 = fin[tid*4+0], dj1 = fin[tid*4+1];
      float dj2 = fin[tid*4+2], dj3 = fin[tid*4+3];
      float bcp = 0.f, dap = 0.f;
      int g = bid*80 + tid;
      if (g < 37000){
        if      (g <  2000){ bcp = (dj0*dj0 + dj1*dj1 + dj2*dj2)*(1.0f/1000.f); }
        else if (g <  7000){ float d1 = dj1 - 1.f;
                             bcp = (dj0*dj0 + d1*d1 + dj2*dj2)*(1.0f/5000.f); }
        else if (g < 12000){ bcp = (dj0*dj0 + dj1*dj1 + dj2*dj2)*(1.0f/5000.f); }
        else if (g < 17000){ bcp = dj3*dj3*(1.0f/5000.f); }
        else { const float* rr = P.real + (g-17000)*4;
               float e0=dj0-rr[0], e1=dj1-rr[1], e2=dj2-rr[2], e3=dj3-rr[3];
               dap = (e0*e0 + e1*e1 + e2*e2 + e3*e3)*(1.0f/80000.f); }
      }
      red[tid] = bcp; redB[tid] = dap;
    }
    __syncthreads();
    if (tid == 0){
      float sA=0.f, sB=0.f;
      #pragma unroll
      for (int i=0;i<80;++i){ sA += red[i]; sB += redB[i]; }
      P.wsBC[bid] = sA; P.wsDA[bid] = sB;
    }
  }
}

// ---------------- final deterministic reduction ----------------
__global__ void reduce_kernel(const float* wsBC, const float* wsDA, const float* wsF,
                              float* out, int nbBC, int nbP){
  __shared__ float sm[256];
  const int tid = threadIdx.x;
  float a;

  a = 0.f; for (int i=tid;i<nbBC;i+=256) a += wsBC[i];
  sm[tid]=a; __syncthreads();
  for (int off=128; off>0; off>>=1){ if (tid<off) sm[tid]+=sm[tid+off]; __syncthreads(); }
  if (tid==0) out[0]=sm[0];
  __syncthreads();

  a = 0.f; for (int i=tid;i<nbBC;i+=256) a += wsDA[i];
  sm[tid]=a; __syncthreads();
  for (int off=128; off>0; off>>=1){ if (tid<off) sm[tid]+=sm[tid+off]; __syncthreads(); }
  if (tid==0) out[1]=sm[0];
  __syncthreads();

  a = 0.f; for (int i=tid;i<nbP;i+=256) a += wsF[i];
  sm[tid]=a; __syncthreads();
  for (int off=128; off>0; off>>=1){ if (tid<off) sm[tid]+=sm[tid+off]; __syncthreads(); }
  if (tid==0) out[2]=sm[0];
}

extern "C" void kernel_launch(void* const* d_in, const int* in_sizes, int n_in,
                              void* d_out, int out_size, void* d_ws, size_t ws_size,
                              hipStream_t stream){
  KP P;
  P.W0=(const float*)d_in[0];  P.b0=(const float*)d_in[1];
  P.W1=(const float*)d_in[2];  P.b1=(const float*)d_in[3];
  P.W2=(const float*)d_in[4];  P.b2=(const float*)d_in[5];
  P.W3=(const float*)d_in[6];  P.b3=(const float*)d_in[7];
  P.W4=(const float*)d_in[8];  P.b4=(const float*)d_in[9];
  P.W5=(const float*)d_in[10]; P.b5=(const float*)d_in[11];
  P.W6=(const float*)d_in[12]; P.b6=(const float*)d_in[13];
  P.bc1=(const float*)d_in[14]; P.bc2=(const float*)d_in[15];
  P.bc3=(const float*)d_in[16]; P.bc4=(const float*)d_in[17];
  P.bc5=(const float*)d_in[18]; P.f1=(const float*)d_in[19];
  P.inp=(const float*)d_in[20]; P.real=(const float*)d_in[21];

  unsigned short* wf = (unsigned short*)d_ws;
  P.Wfh  = wf;                  // 327680 ush
  P.Wfl  = wf + 327680;         // 327680 ush
  P.W6fh = wf + 655360;         // 4096 ush
  P.W6fl = wf + 659456;         // 4096 ush
  float* pb = (float*)((char*)d_ws + 1327104);
  P.wsBC = pb; P.wsDA = pb + 512; P.wsF = pb + 1024;   // 463,463,1250 used

  const int nbP  = 20000 / 16;           // 1250 pde blocks (16 pts)
  const int nbBC = (37000 + 79) / 80;    // 463 fwd blocks (80 pts)

  prep_kernel<<<dim3(1296), dim3(256), 0, stream>>>(
      P.W1, P.W2, P.W3, P.W4, P.W5, P.W6,
      (unsigned short*)wf, (unsigned short*)(wf + 327680),
      (unsigned short*)(wf + 655360), (unsigned short*)(wf + 659456));
  fused_kernel<<<dim3(nbP + nbBC), dim3(512), 0, stream>>>(P, nbP);
  reduce_kernel<<<dim3(1), dim3(256), 0, stream>>>(P.wsBC, P.wsDA, P.wsF,
                                                   (float*)d_out, nbBC, nbP);
}

// Round 16
// 121.370 us; speedup vs baseline: 4.0377x; 1.2044x over previous
//
#include <hip/hip_runtime.h>

#define NUC 8.0e-4f   // MIU/(U*L)

typedef _Float16 __attribute__((ext_vector_type(8))) f16x8;
typedef __attribute__((ext_vector_type(8))) unsigned short u16x8;
typedef __attribute__((ext_vector_type(4))) float   f32x4;

struct KP {
  const float *W0,*b0,*W1,*b1,*W2,*b2,*W3,*b3,*W4,*b4,*W5,*b5,*W6,*b6;
  const float *bc1,*bc2,*bc3,*bc4,*bc5,*f1,*inp,*real;
  const unsigned short *Wfh;     // frag-ordered fp16 W1..W5 (1-term)
  const unsigned short *W6fh;    // frag-ordered fp16 W6 (N padded to 16)
  float *wsBC,*wsDA,*wsF;
};

// fast tanh: t = 1 - 2*rcp(exp2(a*2log2e)+1); a=+inf->1, a=-inf->-1
__device__ __forceinline__ float ftanh(float a){
  float e = __builtin_amdgcn_exp2f(a * 2.88539008177792681472f);
  return 1.0f - 2.0f*__builtin_amdgcn_rcpf(e + 1.0f);
}
__device__ __forceinline__ unsigned short cvth(float v){
  _Float16 hh = (_Float16)v;
  return __builtin_bit_cast(unsigned short, hh);
}
// A byte addr in [80][256] fp16 (row stride 512B), bank-swizzled (prep/L0 helper)
__device__ __forceinline__ int aswz(int row, int kbyte){
  int f = ((row & 7) ^ ((row & 8) >> 2)) << 4;
  return (row*512 + kbyte) ^ f;
}

// ---------------- prep: W1..W5 (+W6 padded) into frag-ordered fp16 (1-term) ----------------
// frag order: [ks(8)][ntile][lane(64)][e(8)]; lane=((k&31)>>3)*16+(col&15), e=k&7
__global__ void prep_kernel(const float* W1, const float* W2, const float* W3,
                            const float* W4, const float* W5, const float* W6,
                            unsigned short* Wfh, unsigned short* W6fh){
  int idx = blockIdx.x*256 + threadIdx.x;      // 0..331775
  if (idx < 327680){
    int li  = idx >> 16;
    int rem = idx & 65535;
    int k   = rem >> 8;
    int col = rem & 255;
    const float* Ws[5] = {W1,W2,W3,W4,W5};
    float v = Ws[li][k*256 + col];
    int ks = k >> 5, kr = k & 31, qq = kr >> 3, e = kr & 7;
    int lane = qq*16 + (col & 15), nt = col >> 4;
    int pos = li*65536 + (ks*16 + nt)*512 + lane*8 + e;
    Wfh[pos] = cvth(v);
  } else {
    int t = idx - 327680;            // 0..4095: [ks(8)][lane(64)][e(8)]
    int ks = t >> 9, lane = (t & 511) >> 3, e = t & 7;
    int k = ks*32 + (lane >> 4)*8 + e;
    int col = lane & 15;
    float v = (col < 4) ? W6[k*4 + col] : 0.f;
    W6fh[t] = cvth(v);
  }
}

// ---------------- fused main kernel: 512 thr = 8 waves, M=80, N=256 ----------------
// full 1-term fp16 + ping-pong A dbuf + hoisted swizzle + B software pipeline.
__global__ __launch_bounds__(512,4) void fused_kernel(KP P, int nbP){
  __shared__ unsigned char Abuf[81920];   // 2 x 40960 fp16 A [80][256]
  const int tid  = threadIdx.x;
  const int lane = tid & 63;
  const int wv   = tid >> 6;          // 0..7
  const int q    = lane >> 4;         // 0..3
  const int lrow = lane & 15;
  const bool isP = (int)blockIdx.x < nbP;
  const int bid  = isP ? (int)blockIdx.x : (int)blockIdx.x - nbP;

  // hoisted swizzle pieces (identical address mapping; bit-fields disjoint)
  const int fr    = ((lrow & 7) ^ ((lrow & 8) >> 2)) << 4;   // f(row) for row&15==lrow
  const int abase = lrow*512 + q*16;                          // + ks*64, ^fr, + m*8192
  const int qa = (q & 1) * 4, qb = (q >> 1) * 2;              // f pieces for rw=q*4+r

  // ---- layer 0 (2 -> 256), write A into buf0 ----
  {
    const int pt = tid >> 5;      // 0..15
    const int jg = tid & 31;      // 8-col group
    const int j0 = jg*8;
    const int f0 = ((pt & 7) ^ ((pt & 8) >> 2)) << 4;
    const int b0 = (pt*512 + jg*16) ^ f0;     // + s_*8192 (or pp*8192)
    float wz[8], wr[8], bb[8];
    #pragma unroll
    for (int jj=0;jj<8;++jj){ wz[jj]=P.W0[j0+jj]; wr[jj]=P.W0[256+j0+jj]; bb[jj]=P.b0[j0+jj]; }
    if (isP){
      int g = bid*16 + pt;
      float x0 = P.f1[2*g], x1 = P.f1[2*g+1];
      u16x8 hv[5];
      #pragma unroll
      for (int jj=0;jj<8;++jj){
        float a = x0*wz[jj] + x1*wr[jj] + bb[jj];
        float t = ftanh(a), s = 1.f - t*t, cc = -2.f*t*s;
        float o[5] = {t, s*wz[jj], s*wr[jj], cc*wz[jj]*wz[jj], cc*wr[jj]*wr[jj]};
        #pragma unroll
        for (int s_=0;s_<5;++s_) hv[s_][jj] = cvth(o[s_]);
      }
      #pragma unroll
      for (int s_=0;s_<5;++s_)
        *(u16x8*)(Abuf + b0 + s_*8192) = hv[s_];
    } else {
      #pragma unroll
      for (int pp=0;pp<5;++pp){
        int g = bid*80 + pt + 16*pp;
        float x0 = 0.f, x1 = 0.f;
        if (g < 37000){
          const float* src; int li2;
          if      (g <  1000){ src=P.bc1; li2=g; }
          else if (g <  2000){ src=P.bc2; li2=g-1000; }
          else if (g <  7000){ src=P.bc3; li2=g-2000; }
          else if (g < 12000){ src=P.bc4; li2=g-7000; }
          else if (g < 17000){ src=P.bc5; li2=g-12000; }
          else               { src=P.inp; li2=g-17000; }
          x0 = src[2*li2]; x1 = src[2*li2+1];
        }
        u16x8 hv;
        #pragma unroll
        for (int jj=0;jj<8;++jj)
          hv[jj] = cvth(ftanh(x0*wz[jj] + x1*wr[jj] + bb[jj]));
        *(u16x8*)(Abuf + b0 + pp*8192) = hv;
      }
    }
  }

  // ---- layers 1..5: read buf[li&1], write buf[(li+1)&1]; ONE barrier/layer ----
  for (int li=0; li<5; ++li){
    const float* bl = (li==0)?P.b1:(li==1)?P.b2:(li==2)?P.b3:(li==3)?P.b4:P.b5;
    const unsigned short* WH = P.Wfh + li*65536;
    unsigned char* rb = Abuf + (li&1)*40960;
    unsigned char* wb = Abuf + ((li+1)&1)*40960;
    f32x4 acc[5][2];
    #pragma unroll
    for (int m=0;m<5;++m)
      #pragma unroll
      for (int n=0;n<2;++n){ acc[m][n][0]=0.f; acc[m][n][1]=0.f; acc[m][n][2]=0.f; acc[m][n][3]=0.f; }

    auto loadB = [&](int ks, f16x8& h0, f16x8& h1){
      int idx = (ks*16 + wv*2)*512 + lane*8;
      h0 = *(const f16x8*)(WH + idx);
      h1 = *(const f16x8*)(WH + idx + 512);
    };
    auto mm = [&](int ks, f16x8& h0, f16x8& h1){
      const int aaddr = (abase + ks*64) ^ fr;     // shared base; +m*8192 folds to offset
      __builtin_amdgcn_s_setprio(1);
      #pragma unroll
      for (int m=0;m<5;++m){
        f16x8 ah = *(const f16x8*)(rb + aaddr + m*8192);
        acc[m][0] = __builtin_amdgcn_mfma_f32_16x16x32_f16(ah, h0, acc[m][0], 0,0,0);
        acc[m][1] = __builtin_amdgcn_mfma_f32_16x16x32_f16(ah, h1, acc[m][1], 0,0,0);
      }
      __builtin_amdgcn_s_setprio(0);
    };

    __syncthreads();   // prior writes to rb visible; prior reads of wb done

    // B software pipeline, depth 1, unroll-by-2 register rotation
    f16x8 Ah0{}, Ah1{}, Bh0{}, Bh1{};
    loadB(0, Ah0, Ah1);
    #pragma unroll 1
    for (int ks=0; ks<8; ks+=2){
      loadB(ks+1, Bh0, Bh1);
      mm(ks, Ah0, Ah1);
      if (ks+2 < 8) loadB(ks+2, Ah0, Ah1);
      mm(ks+1, Bh0, Bh1);
    }

    // epilogue writes to wb while laggards may still read rb — safe (disjoint)
    #pragma unroll
    for (int n=0;n<2;++n){
      const int col  = (wv*2+n)*16 + lrow;
      const int col2 = col*2;
      const float bias = bl[col];
      #pragma unroll
      for (int r=0;r<4;++r){
        const int fe  = ((qa + r) ^ qb) << 4;
        const int snr = q*2048 + r*512 + (col2 ^ fe);   // + s_*8192 (or m*8192)
        if (isP){
          float a  = acc[0][n][r] + bias;
          float Dz = acc[1][n][r], Dr = acc[2][n][r];
          float Dzz= acc[3][n][r], Drr= acc[4][n][r];
          float t = ftanh(a), s = 1.f - t*t, cc = -2.f*t*s;
          float o[5] = {t, s*Dz, s*Dr, s*Dzz + cc*Dz*Dz, s*Drr + cc*Dr*Dr};
          #pragma unroll
          for (int s_=0;s_<5;++s_)
            *(unsigned short*)(wb + snr + s_*8192) = cvth(o[s_]);
        } else {
          #pragma unroll
          for (int m=0;m<5;++m){
            float t = ftanh(acc[m][n][r] + bias);
            *(unsigned short*)(wb + snr + m*8192) = cvth(t);
          }
        }
      }
    }
  }
  __syncthreads();   // layer-5 A (buf1) visible

  // ---- layer 6 via MFMA: wave m (0..4) owns M-tile m; reads buf1 ----
  const unsigned char* fb = Abuf + 40960;
  f32x4 a6; a6[0]=0.f; a6[1]=0.f; a6[2]=0.f; a6[3]=0.f;
  if (wv < 5){
    const int b6 = wv*8192;
    #pragma unroll 1
    for (int ks=0; ks<8; ++ks){
      f16x8 bh = *(const f16x8*)(P.W6fh + ks*512 + lane*8);
      f16x8 ah = *(const f16x8*)(fb + (((abase + ks*64) ^ fr) + b6));
      a6 = __builtin_amdgcn_mfma_f32_16x16x32_f16(ah, bh, a6, 0,0,0);
    }
  }

  float* fin  = (float*)Abuf;            // buf0 region: pde [16][20]; fwd [80][4]
  float* red  = (float*)(Abuf + 4096);
  float* redB = (float*)(Abuf + 6144);

  if (wv < 5 && lrow < 4){
    #pragma unroll
    for (int r=0;r<4;++r){
      if (isP){
        int pt = q*4 + r;
        float v = a6[r] + ((wv==0) ? P.b6[lrow] : 0.f);
        fin[pt*20 + wv*4 + lrow] = v;
      } else {
        int row = wv*16 + q*4 + r;
        fin[row*4 + lrow] = a6[r] + P.b6[lrow];
      }
    }
  }
  __syncthreads();

  // ---- loss terms ----
  if (isP){
    if (tid < 16){
      const float* F = &fin[tid*20];
      float r = P.f1[2*(bid*16 + tid) + 1];
      float uz=F[0],  us=F[1],  ur=F[2];
      float uz_z=F[4],us_z=F[5],ur_z=F[6],p_z=F[7];
      float uz_r=F[8],us_r=F[9],ur_r=F[10],p_r=F[11];
      float uz_zz=F[12],us_zz=F[13],ur_zz=F[14];
      float uz_rr=F[16],us_rr=F[17],ur_rr=F[18];
      float invr = 1.f/r;
      float eq1 = ur*ur_r + uz*ur_z - us*us*invr + p_r
                - NUC*invr*ur_r - NUC*ur_rr - NUC*ur_zz + NUC*ur*invr*invr;
      float eq2 = ur*us_r + uz*us_z + ur*us*invr
                - NUC*invr*us_r - NUC*us_rr - NUC*us_zz + NUC*us*invr*invr;
      float eq3 = ur*uz_r + uz*uz_z + p_z
                - NUC*invr*uz_r - NUC*uz_rr - NUC*uz_zz;
      float eq4 = ur + r*ur_r + r*uz_z;
      red[tid] = (eq1*eq1 + eq2*eq2 + eq3*eq3 + eq4*eq4) * (1.0f/80000.f);
    }
    __syncthreads();
    if (tid == 0){
      float s = 0.f;
      #pragma unroll
      for (int i=0;i<16;++i) s += red[i];
      P.wsF[bid] = s;
    }
  } else {
    if (tid < 80){
      float dj0 = fin[tid*4+0], dj1 = fin[tid*4+1];
      float dj2 = fin[tid*4+2], dj3 = fin[tid*4+3];
      float bcp = 0.f, dap = 0.f;
      int g = bid*80 + tid;
      if (g < 37000){
        if      (g <  2000){ bcp = (dj0*dj0 + dj1*dj1 + dj2*dj2)*(1.0f/1000.f); }
        else if (g <  7000){ float d1 = dj1 - 1.f;
                             bcp = (dj0*dj0 + d1*d1 + dj2*dj2)*(1.0f/5000.f); }
        else if (g < 12000){ bcp = (dj0*dj0 + dj1*dj1 + dj2*dj2)*(1.0f/5000.f); }
        else if (g < 17000){ bcp = dj3*dj3*(1.0f/5000.f); }
        else { const float* rr = P.real + (g-17000)*4;
               float e0=dj0-rr[0], e1=dj1-rr[1], e2=dj2-rr[2], e3=dj3-rr[3];
               dap = (e0*e0 + e1*e1 + e2*e2 + e3*e3)*(1.0f/80000.f); }
      }
      red[tid] = bcp; redB[tid] = dap;
    }
    __syncthreads();
    if (tid == 0){
      float sA=0.f, sB=0.f;
      #pragma unroll
      for (int i=0;i<80;++i){ sA += red[i]; sB += redB[i]; }
      P.wsBC[bid] = sA; P.wsDA[bid] = sB;
    }
  }
}

// ---------------- final deterministic reduction ----------------
__global__ void reduce_kernel(const float* wsBC, const float* wsDA, const float* wsF,
                              float* out, int nbBC, int nbP){
  __shared__ float sm[256];
  const int tid = threadIdx.x;
  float a;

  a = 0.f; for (int i=tid;i<nbBC;i+=256) a += wsBC[i];
  sm[tid]=a; __syncthreads();
  for (int off=128; off>0; off>>=1){ if (tid<off) sm[tid]+=sm[tid+off]; __syncthreads(); }
  if (tid==0) out[0]=sm[0];
  __syncthreads();

  a = 0.f; for (int i=tid;i<nbBC;i+=256) a += wsDA[i];
  sm[tid]=a; __syncthreads();
  for (int off=128; off>0; off>>=1){ if (tid<off) sm[tid]+=sm[tid+off]; __syncthreads(); }
  if (tid==0) out[1]=sm[0];
  __syncthreads();

  a = 0.f; for (int i=tid;i<nbP;i+=256) a += wsF[i];
  sm[tid]=a; __syncthreads();
  for (int off=128; off>0; off>>=1){ if (tid<off) sm[tid]+=sm[tid+off]; __syncthreads(); }
  if (tid==0) out[2]=sm[0];
}

extern "C" void kernel_launch(void* const* d_in, const int* in_sizes, int n_in,
                              void* d_out, int out_size, void* d_ws, size_t ws_size,
                              hipStream_t stream){
  KP P;
  P.W0=(const float*)d_in[0];  P.b0=(const float*)d_in[1];
  P.W1=(const float*)d_in[2];  P.b1=(const float*)d_in[3];
  P.W2=(const float*)d_in[4];  P.b2=(const float*)d_in[5];
  P.W3=(const float*)d_in[6];  P.b3=(const float*)d_in[7];
  P.W4=(const float*)d_in[8];  P.b4=(const float*)d_in[9];
  P.W5=(const float*)d_in[10]; P.b5=(const float*)d_in[11];
  P.W6=(const float*)d_in[12]; P.b6=(const float*)d_in[13];
  P.bc1=(const float*)d_in[14]; P.bc2=(const float*)d_in[15];
  P.bc3=(const float*)d_in[16]; P.bc4=(const float*)d_in[17];
  P.bc5=(const float*)d_in[18]; P.f1=(const float*)d_in[19];
  P.inp=(const float*)d_in[20]; P.real=(const float*)d_in[21];

  unsigned short* wf = (unsigned short*)d_ws;
  P.Wfh  = wf;                  // 327680 ush
  P.W6fh = wf + 327680;         // 4096 ush
  float* pb = (float*)((char*)d_ws + 663552);
  P.wsBC = pb; P.wsDA = pb + 512; P.wsF = pb + 1024;   // 463,463,1250 used

  const int nbP  = 20000 / 16;           // 1250 pde blocks (16 pts)
  const int nbBC = (37000 + 79) / 80;    // 463 fwd blocks (80 pts)

  prep_kernel<<<dim3(1296), dim3(256), 0, stream>>>(
      P.W1, P.W2, P.W3, P.W4, P.W5, P.W6,
      (unsigned short*)wf, (unsigned short*)(wf + 327680));
  fused_kernel<<<dim3(nbP + nbBC), dim3(512), 0, stream>>>(P, nbP);
  reduce_kernel<<<dim3(1), dim3(256), 0, stream>>>(P.wsBC, P.wsDA, P.wsF,
                                                   (float*)d_out, nbBC, nbP);
}

// Round 17
// 118.528 us; speedup vs baseline: 4.1345x; 1.0240x over previous
//
#include <hip/hip_runtime.h>

#define NUC 8.0e-4f   // MIU/(U*L)

typedef _Float16 __attribute__((ext_vector_type(8))) f16x8;
typedef __attribute__((ext_vector_type(8))) unsigned short u16x8;
typedef __attribute__((ext_vector_type(4))) float   f32x4;

struct KP {
  const float *W0,*b0,*W1,*b1,*W2,*b2,*W3,*b3,*W4,*b4,*W5,*b5,*W6,*b6;
  const float *bc1,*bc2,*bc3,*bc4,*bc5,*f1,*inp,*real;
  const unsigned short *Wfh;     // frag-ordered fp16 W1..W5 (1-term)
  const unsigned short *W6fh;    // frag-ordered fp16 W6 (N padded to 16)
  float *wsBC,*wsDA,*wsF;
};

// fast tanh: t = 1 - 2*rcp(exp2(a*2log2e)+1); a=+inf->1, a=-inf->-1
__device__ __forceinline__ float ftanh(float a){
  float e = __builtin_amdgcn_exp2f(a * 2.88539008177792681472f);
  return 1.0f - 2.0f*__builtin_amdgcn_rcpf(e + 1.0f);
}
__device__ __forceinline__ unsigned short cvth(float v){
  _Float16 hh = (_Float16)v;
  return __builtin_bit_cast(unsigned short, hh);
}

// ---------------- prep: W1..W5 (+W6 padded) into frag-ordered fp16 (1-term) ----------------
// frag order: [ks(8)][ntile][lane(64)][e(8)]; lane=((k&31)>>3)*16+(col&15), e=k&7
__global__ void prep_kernel(const float* W1, const float* W2, const float* W3,
                            const float* W4, const float* W5, const float* W6,
                            unsigned short* Wfh, unsigned short* W6fh){
  int idx = blockIdx.x*256 + threadIdx.x;      // 0..331775
  if (idx < 327680){
    int li  = idx >> 16;
    int rem = idx & 65535;
    int k   = rem >> 8;
    int col = rem & 255;
    const float* Ws[5] = {W1,W2,W3,W4,W5};
    float v = Ws[li][k*256 + col];
    int ks = k >> 5, kr = k & 31, qq = kr >> 3, e = kr & 7;
    int lane = qq*16 + (col & 15), nt = col >> 4;
    int pos = li*65536 + (ks*16 + nt)*512 + lane*8 + e;
    Wfh[pos] = cvth(v);
  } else {
    int t = idx - 327680;            // 0..4095: [ks(8)][lane(64)][e(8)]
    int ks = t >> 9, lane = (t & 511) >> 3, e = t & 7;
    int k = ks*32 + (lane >> 4)*8 + e;
    int col = lane & 15;
    float v = (col < 4) ? W6[k*4 + col] : 0.f;
    W6fh[t] = cvth(v);
  }
}

// ---------------- fused main kernel: 512 thr = 8 waves ----------------
// pde: 16 pts, M=80 (5 m-tiles = streams). fwd: 48 pts, M=48 (3 m-tiles).
// 1-term fp16 + ping-pong A dbuf + hoisted swizzle + B software pipeline.
__global__ __launch_bounds__(512,4) void fused_kernel(KP P, int nbP){
  __shared__ unsigned char Abuf[81920];   // 2 x 40960 fp16 A [80][256]
  const int tid  = threadIdx.x;
  const int lane = tid & 63;
  const int wv   = tid >> 6;          // 0..7
  const int q    = lane >> 4;         // 0..3
  const int lrow = lane & 15;
  const bool isP = (int)blockIdx.x < nbP;
  const int bid  = isP ? (int)blockIdx.x : (int)blockIdx.x - nbP;

  // hoisted swizzle pieces (identical address mapping; bit-fields disjoint)
  const int fr    = ((lrow & 7) ^ ((lrow & 8) >> 2)) << 4;   // f(row) for row&15==lrow
  const int abase = lrow*512 + q*16;                          // + ks*64, ^fr, + m*8192
  const int qa = (q & 1) * 4, qb = (q >> 1) * 2;              // f pieces for rw=q*4+r

  // ---- layer 0 (2 -> 256), write A into buf0 ----
  {
    const int pt = tid >> 5;      // 0..15
    const int jg = tid & 31;      // 8-col group
    const int j0 = jg*8;
    const int f0 = ((pt & 7) ^ ((pt & 8) >> 2)) << 4;
    const int b0 = (pt*512 + jg*16) ^ f0;     // + plane*8192
    float wz[8], wr[8], bb[8];
    #pragma unroll
    for (int jj=0;jj<8;++jj){ wz[jj]=P.W0[j0+jj]; wr[jj]=P.W0[256+j0+jj]; bb[jj]=P.b0[j0+jj]; }
    if (isP){
      int g = bid*16 + pt;
      float x0 = P.f1[2*g], x1 = P.f1[2*g+1];
      u16x8 hv[5];
      #pragma unroll
      for (int jj=0;jj<8;++jj){
        float a = x0*wz[jj] + x1*wr[jj] + bb[jj];
        float t = ftanh(a), s = 1.f - t*t, cc = -2.f*t*s;
        float o[5] = {t, s*wz[jj], s*wr[jj], cc*wz[jj]*wz[jj], cc*wr[jj]*wr[jj]};
        #pragma unroll
        for (int s_=0;s_<5;++s_) hv[s_][jj] = cvth(o[s_]);
      }
      #pragma unroll
      for (int s_=0;s_<5;++s_)
        *(u16x8*)(Abuf + b0 + s_*8192) = hv[s_];
    } else {
      #pragma unroll
      for (int pp=0;pp<3;++pp){
        int g = bid*48 + pt + 16*pp;
        float x0 = 0.f, x1 = 0.f;
        if (g < 37000){
          const float* src; int li2;
          if      (g <  1000){ src=P.bc1; li2=g; }
          else if (g <  2000){ src=P.bc2; li2=g-1000; }
          else if (g <  7000){ src=P.bc3; li2=g-2000; }
          else if (g < 12000){ src=P.bc4; li2=g-7000; }
          else if (g < 17000){ src=P.bc5; li2=g-12000; }
          else               { src=P.inp; li2=g-17000; }
          x0 = src[2*li2]; x1 = src[2*li2+1];
        }
        u16x8 hv;
        #pragma unroll
        for (int jj=0;jj<8;++jj)
          hv[jj] = cvth(ftanh(x0*wz[jj] + x1*wr[jj] + bb[jj]));
        *(u16x8*)(Abuf + b0 + pp*8192) = hv;
      }
    }
  }

  // ---- layers 1..5: read buf[li&1], write buf[(li+1)&1]; ONE barrier/layer ----
  if (isP){
    for (int li=0; li<5; ++li){
      const float* bl = (li==0)?P.b1:(li==1)?P.b2:(li==2)?P.b3:(li==3)?P.b4:P.b5;
      const unsigned short* WH = P.Wfh + li*65536;
      unsigned char* rb = Abuf + (li&1)*40960;
      unsigned char* wb = Abuf + ((li+1)&1)*40960;
      f32x4 acc[5][2];
      #pragma unroll
      for (int m=0;m<5;++m)
        #pragma unroll
        for (int n=0;n<2;++n){ acc[m][n][0]=0.f; acc[m][n][1]=0.f; acc[m][n][2]=0.f; acc[m][n][3]=0.f; }

      auto loadB = [&](int ks, f16x8& h0, f16x8& h1){
        int idx = (ks*16 + wv*2)*512 + lane*8;
        h0 = *(const f16x8*)(WH + idx);
        h1 = *(const f16x8*)(WH + idx + 512);
      };
      auto mm = [&](int ks, f16x8& h0, f16x8& h1){
        const int aaddr = (abase + ks*64) ^ fr;
        __builtin_amdgcn_s_setprio(1);
        #pragma unroll
        for (int m=0;m<5;++m){
          f16x8 ah = *(const f16x8*)(rb + aaddr + m*8192);
          acc[m][0] = __builtin_amdgcn_mfma_f32_16x16x32_f16(ah, h0, acc[m][0], 0,0,0);
          acc[m][1] = __builtin_amdgcn_mfma_f32_16x16x32_f16(ah, h1, acc[m][1], 0,0,0);
        }
        __builtin_amdgcn_s_setprio(0);
      };

      __syncthreads();
      f16x8 Ah0{}, Ah1{}, Bh0{}, Bh1{};
      loadB(0, Ah0, Ah1);
      #pragma unroll 1
      for (int ks=0; ks<8; ks+=2){
        loadB(ks+1, Bh0, Bh1);
        mm(ks, Ah0, Ah1);
        if (ks+2 < 8) loadB(ks+2, Ah0, Ah1);
        mm(ks+1, Bh0, Bh1);
      }

      #pragma unroll
      for (int n=0;n<2;++n){
        const int col  = (wv*2+n)*16 + lrow;
        const int col2 = col*2;
        const float bias = bl[col];
        #pragma unroll
        for (int r=0;r<4;++r){
          const int fe  = ((qa + r) ^ qb) << 4;
          const int snr = q*2048 + r*512 + (col2 ^ fe);
          float a  = acc[0][n][r] + bias;
          float Dz = acc[1][n][r], Dr = acc[2][n][r];
          float Dzz= acc[3][n][r], Drr= acc[4][n][r];
          float t = ftanh(a), s = 1.f - t*t, cc = -2.f*t*s;
          float o[5] = {t, s*Dz, s*Dr, s*Dzz + cc*Dz*Dz, s*Drr + cc*Dr*Dr};
          #pragma unroll
          for (int s_=0;s_<5;++s_)
            *(unsigned short*)(wb + snr + s_*8192) = cvth(o[s_]);
        }
      }
    }
  } else {
    for (int li=0; li<5; ++li){
      const float* bl = (li==0)?P.b1:(li==1)?P.b2:(li==2)?P.b3:(li==3)?P.b4:P.b5;
      const unsigned short* WH = P.Wfh + li*65536;
      unsigned char* rb = Abuf + (li&1)*40960;
      unsigned char* wb = Abuf + ((li+1)&1)*40960;
      f32x4 acc[3][2];
      #pragma unroll
      for (int m=0;m<3;++m)
        #pragma unroll
        for (int n=0;n<2;++n){ acc[m][n][0]=0.f; acc[m][n][1]=0.f; acc[m][n][2]=0.f; acc[m][n][3]=0.f; }

      auto loadB = [&](int ks, f16x8& h0, f16x8& h1){
        int idx = (ks*16 + wv*2)*512 + lane*8;
        h0 = *(const f16x8*)(WH + idx);
        h1 = *(const f16x8*)(WH + idx + 512);
      };
      auto mm = [&](int ks, f16x8& h0, f16x8& h1){
        const int aaddr = (abase + ks*64) ^ fr;
        __builtin_amdgcn_s_setprio(1);
        #pragma unroll
        for (int m=0;m<3;++m){
          f16x8 ah = *(const f16x8*)(rb + aaddr + m*8192);
          acc[m][0] = __builtin_amdgcn_mfma_f32_16x16x32_f16(ah, h0, acc[m][0], 0,0,0);
          acc[m][1] = __builtin_amdgcn_mfma_f32_16x16x32_f16(ah, h1, acc[m][1], 0,0,0);
        }
        __builtin_amdgcn_s_setprio(0);
      };

      __syncthreads();
      f16x8 Ah0{}, Ah1{}, Bh0{}, Bh1{};
      loadB(0, Ah0, Ah1);
      #pragma unroll 1
      for (int ks=0; ks<8; ks+=2){
        loadB(ks+1, Bh0, Bh1);
        mm(ks, Ah0, Ah1);
        if (ks+2 < 8) loadB(ks+2, Ah0, Ah1);
        mm(ks+1, Bh0, Bh1);
      }

      #pragma unroll
      for (int n=0;n<2;++n){
        const int col  = (wv*2+n)*16 + lrow;
        const int col2 = col*2;
        const float bias = bl[col];
        #pragma unroll
        for (int r=0;r<4;++r){
          const int fe  = ((qa + r) ^ qb) << 4;
          const int snr = q*2048 + r*512 + (col2 ^ fe);
          #pragma unroll
          for (int m=0;m<3;++m){
            float t = ftanh(acc[m][n][r] + bias);
            *(unsigned short*)(wb + snr + m*8192) = cvth(t);
          }
        }
      }
    }
  }
  __syncthreads();   // layer-5 A (buf1) visible

  // ---- layer 6 via MFMA: wave m owns M-tile m; reads buf1 ----
  const unsigned char* fb = Abuf + 40960;
  const int nmt = isP ? 5 : 3;
  f32x4 a6; a6[0]=0.f; a6[1]=0.f; a6[2]=0.f; a6[3]=0.f;
  if (wv < nmt){
    const int b6 = wv*8192;
    #pragma unroll 1
    for (int ks=0; ks<8; ++ks){
      f16x8 bh = *(const f16x8*)(P.W6fh + ks*512 + lane*8);
      f16x8 ah = *(const f16x8*)(fb + (((abase + ks*64) ^ fr) + b6));
      a6 = __builtin_amdgcn_mfma_f32_16x16x32_f16(ah, bh, a6, 0,0,0);
    }
  }

  float* fin  = (float*)Abuf;            // buf0 region: pde [16][20]; fwd [48][4]
  float* red  = (float*)(Abuf + 4096);
  float* redB = (float*)(Abuf + 6144);

  if (wv < nmt && lrow < 4){
    #pragma unroll
    for (int r=0;r<4;++r){
      if (isP){
        int pt = q*4 + r;
        float v = a6[r] + ((wv==0) ? P.b6[lrow] : 0.f);
        fin[pt*20 + wv*4 + lrow] = v;
      } else {
        int row = wv*16 + q*4 + r;
        fin[row*4 + lrow] = a6[r] + P.b6[lrow];
      }
    }
  }
  __syncthreads();

  // ---- loss terms ----
  if (isP){
    if (tid < 16){
      const float* F = &fin[tid*20];
      float r = P.f1[2*(bid*16 + tid) + 1];
      float uz=F[0],  us=F[1],  ur=F[2];
      float uz_z=F[4],us_z=F[5],ur_z=F[6],p_z=F[7];
      float uz_r=F[8],us_r=F[9],ur_r=F[10],p_r=F[11];
      float uz_zz=F[12],us_zz=F[13],ur_zz=F[14];
      float uz_rr=F[16],us_rr=F[17],ur_rr=F[18];
      float invr = 1.f/r;
      float eq1 = ur*ur_r + uz*ur_z - us*us*invr + p_r
                - NUC*invr*ur_r - NUC*ur_rr - NUC*ur_zz + NUC*ur*invr*invr;
      float eq2 = ur*us_r + uz*us_z + ur*us*invr
                - NUC*invr*us_r - NUC*us_rr - NUC*us_zz + NUC*us*invr*invr;
      float eq3 = ur*uz_r + uz*uz_z + p_z
                - NUC*invr*uz_r - NUC*uz_rr - NUC*uz_zz;
      float eq4 = ur + r*ur_r + r*uz_z;
      red[tid] = (eq1*eq1 + eq2*eq2 + eq3*eq3 + eq4*eq4) * (1.0f/80000.f);
    }
    __syncthreads();
    if (tid == 0){
      float s = 0.f;
      #pragma unroll
      for (int i=0;i<16;++i) s += red[i];
      P.wsF[bid] = s;
    }
  } else {
    if (tid < 48){
      float dj0 = fin[tid*4+0], dj1 = fin[tid*4+1];
      float dj2 = fin[tid*4+2], dj3 = fin[tid*4+3];
      float bcp = 0.f, dap = 0.f;
      int g = bid*48 + tid;
      if (g < 37000){
        if      (g <  2000){ bcp = (dj0*dj0 + dj1*dj1 + dj2*dj2)*(1.0f/1000.f); }
        else if (g <  7000){ float d1 = dj1 - 1.f;
                             bcp = (dj0*dj0 + d1*d1 + dj2*dj2)*(1.0f/5000.f); }
        else if (g < 12000){ bcp = (dj0*dj0 + dj1*dj1 + dj2*dj2)*(1.0f/5000.f); }
        else if (g < 17000){ bcp = dj3*dj3*(1.0f/5000.f); }
        else { const float* rr = P.real + (g-17000)*4;
               float e0=dj0-rr[0], e1=dj1-rr[1], e2=dj2-rr[2], e3=dj3-rr[3];
               dap = (e0*e0 + e1*e1 + e2*e2 + e3*e3)*(1.0f/80000.f); }
      }
      red[tid] = bcp; redB[tid] = dap;
    }
    __syncthreads();
    if (tid == 0){
      float sA=0.f, sB=0.f;
      #pragma unroll
      for (int i=0;i<48;++i){ sA += red[i]; sB += redB[i]; }
      P.wsBC[bid] = sA; P.wsDA[bid] = sB;
    }
  }
}

// ---------------- final deterministic reduction ----------------
__global__ void reduce_kernel(const float* wsBC, const float* wsDA, const float* wsF,
                              float* out, int nbBC, int nbP){
  __shared__ float sm[256];
  const int tid = threadIdx.x;
  float a;

  a = 0.f; for (int i=tid;i<nbBC;i+=256) a += wsBC[i];
  sm[tid]=a; __syncthreads();
  for (int off=128; off>0; off>>=1){ if (tid<off) sm[tid]+=sm[tid+off]; __syncthreads(); }
  if (tid==0) out[0]=sm[0];
  __syncthreads();

  a = 0.f; for (int i=tid;i<nbBC;i+=256) a += wsDA[i];
  sm[tid]=a; __syncthreads();
  for (int off=128; off>0; off>>=1){ if (tid<off) sm[tid]+=sm[tid+off]; __syncthreads(); }
  if (tid==0) out[1]=sm[0];
  __syncthreads();

  a = 0.f; for (int i=tid;i<nbP;i+=256) a += wsF[i];
  sm[tid]=a; __syncthreads();
  for (int off=128; off>0; off>>=1){ if (tid<off) sm[tid]+=sm[tid+off]; __syncthreads(); }
  if (tid==0) out[2]=sm[0];
}

extern "C" void kernel_launch(void* const* d_in, const int* in_sizes, int n_in,
                              void* d_out, int out_size, void* d_ws, size_t ws_size,
                              hipStream_t stream){
  KP P;
  P.W0=(const float*)d_in[0];  P.b0=(const float*)d_in[1];
  P.W1=(const float*)d_in[2];  P.b1=(const float*)d_in[3];
  P.W2=(const float*)d_in[4];  P.b2=(const float*)d_in[5];
  P.W3=(const float*)d_in[6];  P.b3=(const float*)d_in[7];
  P.W4=(const float*)d_in[8];  P.b4=(const float*)d_in[9];
  P.W5=(const float*)d_in[10]; P.b5=(const float*)d_in[11];
  P.W6=(const float*)d_in[12]; P.b6=(const float*)d_in[13];
  P.bc1=(const float*)d_in[14]; P.bc2=(const float*)d_in[15];
  P.bc3=(const float*)d_in[16]; P.bc4=(const float*)d_in[17];
  P.bc5=(const float*)d_in[18]; P.f1=(const float*)d_in[19];
  P.inp=(const float*)d_in[20]; P.real=(const float*)d_in[21];

  unsigned short* wf = (unsigned short*)d_ws;
  P.Wfh  = wf;                  // 327680 ush
  P.W6fh = wf + 327680;         // 4096 ush
  float* pb = (float*)((char*)d_ws + 663552);
  P.wsBC = pb; P.wsDA = pb + 1024; P.wsF = pb + 2048;   // 771,771,1250 used

  const int nbP  = 20000 / 16;           // 1250 pde blocks (16 pts)
  const int nbBC = (37000 + 47) / 48;    // 771 fwd blocks (48 pts) -> 2021 total ≈ 3.95 rounds

  prep_kernel<<<dim3(1296), dim3(256), 0, stream>>>(
      P.W1, P.W2, P.W3, P.W4, P.W5, P.W6,
      (unsigned short*)wf, (unsigned short*)(wf + 327680));
  fused_kernel<<<dim3(nbP + nbBC), dim3(512), 0, stream>>>(P, nbP);
  reduce_kernel<<<dim3(1), dim3(256), 0, stream>>>(P.wsBC, P.wsDA, P.wsF,
                                                   (float*)d_out, nbBC, nbP);
}

// Round 19
// 116.508 us; speedup vs baseline: 4.2062x; 1.0173x over previous
//
#include <hip/hip_runtime.h>

#define NUC 8.0e-4f   // MIU/(U*L)

typedef _Float16 __attribute__((ext_vector_type(8))) f16x8;
typedef __fp16   __attribute__((ext_vector_type(2))) h16x2;   // matches cvt_pkrtz return type
typedef __attribute__((ext_vector_type(8))) unsigned short u16x8;
typedef __attribute__((ext_vector_type(4))) float   f32x4;

struct KP {
  const float *W0,*b0,*W1,*b1,*W2,*b2,*W3,*b3,*W4,*b4,*W5,*b5,*W6,*b6;
  const float *bc1,*bc2,*bc3,*bc4,*bc5,*f1,*inp,*real;
  const unsigned short *Wfh;     // frag-ordered fp16 W1..W5 (1-term)
  const unsigned short *W6fh;    // frag-ordered fp16 W6 (N padded to 16)
  float *wsBC,*wsDA,*wsF;
};

// fast tanh: t = 1 - 2*rcp(exp2(a*2log2e)+1); a=+inf->1, a=-inf->-1
__device__ __forceinline__ float ftanh(float a){
  float e = __builtin_amdgcn_exp2f(a * 2.88539008177792681472f);
  return 1.0f - 2.0f*__builtin_amdgcn_rcpf(e + 1.0f);
}
__device__ __forceinline__ unsigned short cvth(float v){
  _Float16 hh = (_Float16)v;
  return __builtin_bit_cast(unsigned short, hh);
}

// ---------------- prep: W1..W5 (+W6 padded) into frag-ordered fp16 (1-term) ----------------
// frag order: [ks(8)][ntile][lane(64)][e(8)]; lane=((k&31)>>3)*16+(col&15), e=k&7
__global__ void prep_kernel(const float* W1, const float* W2, const float* W3,
                            const float* W4, const float* W5, const float* W6,
                            unsigned short* Wfh, unsigned short* W6fh){
  int idx = blockIdx.x*256 + threadIdx.x;      // 0..331775
  if (idx < 327680){
    int li  = idx >> 16;
    int rem = idx & 65535;
    int k   = rem >> 8;
    int col = rem & 255;
    const float* Ws[5] = {W1,W2,W3,W4,W5};
    float v = Ws[li][k*256 + col];
    int ks = k >> 5, kr = k & 31, qq = kr >> 3, e = kr & 7;
    int lane = qq*16 + (col & 15), nt = col >> 4;
    int pos = li*65536 + (ks*16 + nt)*512 + lane*8 + e;
    Wfh[pos] = cvth(v);
  } else {
    int t = idx - 327680;            // 0..4095: [ks(8)][lane(64)][e(8)]
    int ks = t >> 9, lane = (t & 511) >> 3, e = t & 7;
    int k = ks*32 + (lane >> 4)*8 + e;
    int col = lane & 15;
    float v = (col < 4) ? W6[k*4 + col] : 0.f;
    W6fh[t] = cvth(v);
  }
}

// ---------------- fused main kernel: 512 thr = 8 waves ----------------
// pde: 16 pts, M=80 (5 m-tiles = streams). fwd: 48 pts, M=48 (3 m-tiles).
// 1-term fp16 + ping-pong A dbuf + hoisted swizzle + B pipeline + packed epilogue.
__global__ __launch_bounds__(512,4) void fused_kernel(KP P, int nbP){
  __shared__ unsigned char Abuf[81920];   // 2 x 40960 fp16 A [80][256]
  const int tid  = threadIdx.x;
  const int lane = tid & 63;
  const int wv   = tid >> 6;          // 0..7
  const int q    = lane >> 4;         // 0..3
  const int lrow = lane & 15;
  const bool isP = (int)blockIdx.x < nbP;
  const int bid  = isP ? (int)blockIdx.x : (int)blockIdx.x - nbP;

  // hoisted swizzle pieces (identical address mapping; bit-fields disjoint)
  const int fr    = ((lrow & 7) ^ ((lrow & 8) >> 2)) << 4;   // f(row) for row&15==lrow
  const int abase = lrow*512 + q*16;                          // + ks*64, ^fr, + m*8192
  const int qa = (q & 1) * 4, qb = (q >> 1) * 2;              // f pieces for rw=q*4+r

  // ---- layer 0 (2 -> 256), write A into buf0 ----
  {
    const int pt = tid >> 5;      // 0..15
    const int jg = tid & 31;      // 8-col group
    const int j0 = jg*8;
    const int f0 = ((pt & 7) ^ ((pt & 8) >> 2)) << 4;
    const int b0 = (pt*512 + jg*16) ^ f0;     // + plane*8192
    float wz[8], wr[8], bb[8];
    #pragma unroll
    for (int jj=0;jj<8;++jj){ wz[jj]=P.W0[j0+jj]; wr[jj]=P.W0[256+j0+jj]; bb[jj]=P.b0[j0+jj]; }
    if (isP){
      int g = bid*16 + pt;
      float x0 = P.f1[2*g], x1 = P.f1[2*g+1];
      u16x8 hv[5];
      #pragma unroll
      for (int jj=0;jj<8;++jj){
        float a = x0*wz[jj] + x1*wr[jj] + bb[jj];
        float t = ftanh(a), s = 1.f - t*t, cc = -2.f*t*s;
        float o[5] = {t, s*wz[jj], s*wr[jj], cc*wz[jj]*wz[jj], cc*wr[jj]*wr[jj]};
        #pragma unroll
        for (int s_=0;s_<5;++s_) hv[s_][jj] = cvth(o[s_]);
      }
      #pragma unroll
      for (int s_=0;s_<5;++s_)
        *(u16x8*)(Abuf + b0 + s_*8192) = hv[s_];
    } else {
      #pragma unroll
      for (int pp=0;pp<3;++pp){
        int g = bid*48 + pt + 16*pp;
        float x0 = 0.f, x1 = 0.f;
        if (g < 37000){
          const float* src; int li2;
          if      (g <  1000){ src=P.bc1; li2=g; }
          else if (g <  2000){ src=P.bc2; li2=g-1000; }
          else if (g <  7000){ src=P.bc3; li2=g-2000; }
          else if (g < 12000){ src=P.bc4; li2=g-7000; }
          else if (g < 17000){ src=P.bc5; li2=g-12000; }
          else               { src=P.inp; li2=g-17000; }
          x0 = src[2*li2]; x1 = src[2*li2+1];
        }
        u16x8 hv;
        #pragma unroll
        for (int jj=0;jj<8;++jj)
          hv[jj] = cvth(ftanh(x0*wz[jj] + x1*wr[jj] + bb[jj]));
        *(u16x8*)(Abuf + b0 + pp*8192) = hv;
      }
    }
  }

  // ---- layers 1..5: read buf[li&1], write buf[(li+1)&1]; ONE barrier/layer ----
  if (isP){
    for (int li=0; li<5; ++li){
      const float* bl = (li==0)?P.b1:(li==1)?P.b2:(li==2)?P.b3:(li==3)?P.b4:P.b5;
      const unsigned short* WH = P.Wfh + li*65536;
      unsigned char* rb = Abuf + (li&1)*40960;
      unsigned char* wb = Abuf + ((li+1)&1)*40960;
      f32x4 acc[5][2];
      // bias pre-init for h-stream; derivative streams start at 0
      #pragma unroll
      for (int n=0;n<2;++n){
        float bias = bl[(wv*2+n)*16 + lrow];
        acc[0][n][0]=bias; acc[0][n][1]=bias; acc[0][n][2]=bias; acc[0][n][3]=bias;
      }
      #pragma unroll
      for (int m=1;m<5;++m)
        #pragma unroll
        for (int n=0;n<2;++n){ acc[m][n][0]=0.f; acc[m][n][1]=0.f; acc[m][n][2]=0.f; acc[m][n][3]=0.f; }

      auto loadB = [&](int ks, f16x8& h0, f16x8& h1){
        int idx = (ks*16 + wv*2)*512 + lane*8;
        h0 = *(const f16x8*)(WH + idx);
        h1 = *(const f16x8*)(WH + idx + 512);
      };
      auto mm = [&](int ks, f16x8& h0, f16x8& h1){
        const int aaddr = (abase + ks*64) ^ fr;
        __builtin_amdgcn_s_setprio(1);
        #pragma unroll
        for (int m=0;m<5;++m){
          f16x8 ah = *(const f16x8*)(rb + aaddr + m*8192);
          acc[m][0] = __builtin_amdgcn_mfma_f32_16x16x32_f16(ah, h0, acc[m][0], 0,0,0);
          acc[m][1] = __builtin_amdgcn_mfma_f32_16x16x32_f16(ah, h1, acc[m][1], 0,0,0);
        }
        __builtin_amdgcn_s_setprio(0);
      };

      __syncthreads();
      f16x8 Ah0{}, Ah1{}, Bh0{}, Bh1{};
      loadB(0, Ah0, Ah1);
      #pragma unroll 1
      for (int ks=0; ks<8; ks+=2){
        loadB(ks+1, Bh0, Bh1);
        mm(ks, Ah0, Ah1);
        if (ks+2 < 8) loadB(ks+2, Ah0, Ah1);
        mm(ks+1, Bh0, Bh1);
      }

      // packed-f16 epilogue
      #pragma unroll
      for (int n=0;n<2;++n){
        const int col2 = ((wv*2+n)*16 + lrow)*2;
        #pragma unroll
        for (int r=0;r<4;++r){
          const int fe  = ((qa + r) ^ qb) << 4;
          const int snr = q*2048 + r*512 + (col2 ^ fe);
          float a  = acc[0][n][r];                 // bias pre-applied
          float Dz = acc[1][n][r], Dr = acc[2][n][r];
          float Dzz= acc[3][n][r], Drr= acc[4][n][r];
          float t = ftanh(a);
          float s = __builtin_fmaf(-t, t, 1.f);
          float cc = -(t+t)*s;
          h16x2 sh  = __builtin_amdgcn_cvt_pkrtz(s, s);
          h16x2 cch = __builtin_amdgcn_cvt_pkrtz(cc, cc);
          h16x2 P1  = __builtin_amdgcn_cvt_pkrtz(Dz, Dr);
          h16x2 P2  = __builtin_amdgcn_cvt_pkrtz(Dzz, Drr);
          h16x2 o12 = P1 * sh;                       // (s*Dz, s*Dr)
          h16x2 o34 = P2 * sh + (P1 * P1) * cch;     // (s*Dzz+cc*Dz^2, s*Drr+cc*Dr^2)
          unsigned int u12 = __builtin_bit_cast(unsigned int, o12);
          unsigned int u34 = __builtin_bit_cast(unsigned int, o34);
          *(unsigned short*)(wb + snr          ) = cvth(t);
          *(unsigned short*)(wb + snr + 1*8192) = (unsigned short)u12;
          *(unsigned short*)(wb + snr + 2*8192) = (unsigned short)(u12 >> 16);
          *(unsigned short*)(wb + snr + 3*8192) = (unsigned short)u34;
          *(unsigned short*)(wb + snr + 4*8192) = (unsigned short)(u34 >> 16);
        }
      }
    }
  } else {
    for (int li=0; li<5; ++li){
      const float* bl = (li==0)?P.b1:(li==1)?P.b2:(li==2)?P.b3:(li==3)?P.b4:P.b5;
      const unsigned short* WH = P.Wfh + li*65536;
      unsigned char* rb = Abuf + (li&1)*40960;
      unsigned char* wb = Abuf + ((li+1)&1)*40960;
      f32x4 acc[3][2];
      #pragma unroll
      for (int n=0;n<2;++n){
        float bias = bl[(wv*2+n)*16 + lrow];
        #pragma unroll
        for (int m=0;m<3;++m){
          acc[m][n][0]=bias; acc[m][n][1]=bias; acc[m][n][2]=bias; acc[m][n][3]=bias;
        }
      }

      auto loadB = [&](int ks, f16x8& h0, f16x8& h1){
        int idx = (ks*16 + wv*2)*512 + lane*8;
        h0 = *(const f16x8*)(WH + idx);
        h1 = *(const f16x8*)(WH + idx + 512);
      };
      auto mm = [&](int ks, f16x8& h0, f16x8& h1){
        const int aaddr = (abase + ks*64) ^ fr;
        __builtin_amdgcn_s_setprio(1);
        #pragma unroll
        for (int m=0;m<3;++m){
          f16x8 ah = *(const f16x8*)(rb + aaddr + m*8192);
          acc[m][0] = __builtin_amdgcn_mfma_f32_16x16x32_f16(ah, h0, acc[m][0], 0,0,0);
          acc[m][1] = __builtin_amdgcn_mfma_f32_16x16x32_f16(ah, h1, acc[m][1], 0,0,0);
        }
        __builtin_amdgcn_s_setprio(0);
      };

      __syncthreads();
      f16x8 Ah0{}, Ah1{}, Bh0{}, Bh1{};
      loadB(0, Ah0, Ah1);
      #pragma unroll 1
      for (int ks=0; ks<8; ks+=2){
        loadB(ks+1, Bh0, Bh1);
        mm(ks, Ah0, Ah1);
        if (ks+2 < 8) loadB(ks+2, Ah0, Ah1);
        mm(ks+1, Bh0, Bh1);
      }

      #pragma unroll
      for (int n=0;n<2;++n){
        const int col2 = ((wv*2+n)*16 + lrow)*2;
        #pragma unroll
        for (int r=0;r<4;++r){
          const int fe  = ((qa + r) ^ qb) << 4;
          const int snr = q*2048 + r*512 + (col2 ^ fe);
          #pragma unroll
          for (int m=0;m<3;++m){
            float t = ftanh(acc[m][n][r]);     // bias pre-applied
            *(unsigned short*)(wb + snr + m*8192) = cvth(t);
          }
        }
      }
    }
  }
  __syncthreads();   // layer-5 A (buf1) visible

  // ---- layer 6 via MFMA: wave m owns M-tile m; reads buf1 ----
  const unsigned char* fb = Abuf + 40960;
  const int nmt = isP ? 5 : 3;
  f32x4 a6; a6[0]=0.f; a6[1]=0.f; a6[2]=0.f; a6[3]=0.f;
  if (wv < nmt){
    const int b6 = wv*8192;
    #pragma unroll 1
    for (int ks=0; ks<8; ++ks){
      f16x8 bh = *(const f16x8*)(P.W6fh + ks*512 + lane*8);
      f16x8 ah = *(const f16x8*)(fb + (((abase + ks*64) ^ fr) + b6));
      a6 = __builtin_amdgcn_mfma_f32_16x16x32_f16(ah, bh, a6, 0,0,0);
    }
  }

  float* fin  = (float*)Abuf;            // buf0 region: pde [16][20]; fwd [48][4]
  float* red  = (float*)(Abuf + 4096);
  float* redB = (float*)(Abuf + 6144);

  if (wv < nmt && lrow < 4){
    #pragma unroll
    for (int r=0;r<4;++r){
      if (isP){
        int pt = q*4 + r;
        float v = a6[r] + ((wv==0) ? P.b6[lrow] : 0.f);
        fin[pt*20 + wv*4 + lrow] = v;
      } else {
        int row = wv*16 + q*4 + r;
        fin[row*4 + lrow] = a6[r] + P.b6[lrow];
      }
    }
  }
  __syncthreads();

  // ---- loss terms ----
  if (isP){
    if (tid < 16){
      const float* F = &fin[tid*20];
      float r = P.f1[2*(bid*16 + tid) + 1];
      float uz=F[0],  us=F[1],  ur=F[2];
      float uz_z=F[4],us_z=F[5],ur_z=F[6],p_z=F[7];
      float uz_r=F[8],us_r=F[9],ur_r=F[10],p_r=F[11];
      float uz_zz=F[12],us_zz=F[13],ur_zz=F[14];
      float uz_rr=F[16],us_rr=F[17],ur_rr=F[18];
      float invr = 1.f/r;
      float eq1 = ur*ur_r + uz*ur_z - us*us*invr + p_r
                - NUC*invr*ur_r - NUC*ur_rr - NUC*ur_zz + NUC*ur*invr*invr;
      float eq2 = ur*us_r + uz*us_z + ur*us*invr
                - NUC*invr*us_r - NUC*us_rr - NUC*us_zz + NUC*us*invr*invr;
      float eq3 = ur*uz_r + uz*uz_z + p_z
                - NUC*invr*uz_r - NUC*uz_rr - NUC*uz_zz;
      float eq4 = ur + r*ur_r + r*uz_z;
      red[tid] = (eq1*eq1 + eq2*eq2 + eq3*eq3 + eq4*eq4) * (1.0f/80000.f);
    }
    __syncthreads();
    if (tid == 0){
      float s = 0.f;
      #pragma unroll
      for (int i=0;i<16;++i) s += red[i];
      P.wsF[bid] = s;
    }
  } else {
    if (tid < 48){
      float dj0 = fin[tid*4+0], dj1 = fin[tid*4+1];
      float dj2 = fin[tid*4+2], dj3 = fin[tid*4+3];
      float bcp = 0.f, dap = 0.f;
      int g = bid*48 + tid;
      if (g < 37000){
        if      (g <  2000){ bcp = (dj0*dj0 + dj1*dj1 + dj2*dj2)*(1.0f/1000.f); }
        else if (g <  7000){ float d1 = dj1 - 1.f;
                             bcp = (dj0*dj0 + d1*d1 + dj2*dj2)*(1.0f/5000.f); }
        else if (g < 12000){ bcp = (dj0*dj0 + dj1*dj1 + dj2*dj2)*(1.0f/5000.f); }
        else if (g < 17000){ bcp = dj3*dj3*(1.0f/5000.f); }
        else { const float* rr = P.real + (g-17000)*4;
               float e0=dj0-rr[0], e1=dj1-rr[1], e2=dj2-rr[2], e3=dj3-rr[3];
               dap = (e0*e0 + e1*e1 + e2*e2 + e3*e3)*(1.0f/80000.f); }
      }
      red[tid] = bcp; redB[tid] = dap;
    }
    __syncthreads();
    if (tid == 0){
      float sA=0.f, sB=0.f;
      #pragma unroll
      for (int i=0;i<48;++i){ sA += red[i]; sB += redB[i]; }
      P.wsBC[bid] = sA; P.wsDA[bid] = sB;
    }
  }
}

// ---------------- final deterministic reduction ----------------
__global__ void reduce_kernel(const float* wsBC, const float* wsDA, const float* wsF,
                              float* out, int nbBC, int nbP){
  __shared__ float sm[256];
  const int tid = threadIdx.x;
  float a;

  a = 0.f; for (int i=tid;i<nbBC;i+=256) a += wsBC[i];
  sm[tid]=a; __syncthreads();
  for (int off=128; off>0; off>>=1){ if (tid<off) sm[tid]+=sm[tid+off]; __syncthreads(); }
  if (tid==0) out[0]=sm[0];
  __syncthreads();

  a = 0.f; for (int i=tid;i<nbBC;i+=256) a += wsDA[i];
  sm[tid]=a; __syncthreads();
  for (int off=128; off>0; off>>=1){ if (tid<off) sm[tid]+=sm[tid+off]; __syncthreads(); }
  if (tid==0) out[1]=sm[0];
  __syncthreads();

  a = 0.f; for (int i=tid;i<nbP;i+=256) a += wsF[i];
  sm[tid]=a; __syncthreads();
  for (int off=128; off>0; off>>=1){ if (tid<off) sm[tid]+=sm[tid+off]; __syncthreads(); }
  if (tid==0) out[2]=sm[0];
}

extern "C" void kernel_launch(void* const* d_in, const int* in_sizes, int n_in,
                              void* d_out, int out_size, void* d_ws, size_t ws_size,
                              hipStream_t stream){
  KP P;
  P.W0=(const float*)d_in[0];  P.b0=(const float*)d_in[1];
  P.W1=(const float*)d_in[2];  P.b1=(const float*)d_in[3];
  P.W2=(const float*)d_in[4];  P.b2=(const float*)d_in[5];
  P.W3=(const float*)d_in[6];  P.b3=(const float*)d_in[7];
  P.W4=(const float*)d_in[8];  P.b4=(const float*)d_in[9];
  P.W5=(const float*)d_in[10]; P.b5=(const float*)d_in[11];
  P.W6=(const float*)d_in[12]; P.b6=(const float*)d_in[13];
  P.bc1=(const float*)d_in[14]; P.bc2=(const float*)d_in[15];
  P.bc3=(const float*)d_in[16]; P.bc4=(const float*)d_in[17];
  P.bc5=(const float*)d_in[18]; P.f1=(const float*)d_in[19];
  P.inp=(const float*)d_in[20]; P.real=(const float*)d_in[21];

  unsigned short* wf = (unsigned short*)d_ws;
  P.Wfh  = wf;                  // 327680 ush
  P.W6fh = wf + 327680;         // 4096 ush
  float* pb = (float*)((char*)d_ws + 663552);
  P.wsBC = pb; P.wsDA = pb + 1024; P.wsF = pb + 2048;   // 771,771,1250 used

  const int nbP  = 20000 / 16;           // 1250 pde blocks (16 pts)
  const int nbBC = (37000 + 47) / 48;    // 771 fwd blocks (48 pts) -> 2021 total ≈ 3.95 rounds

  prep_kernel<<<dim3(1296), dim3(256), 0, stream>>>(
      P.W1, P.W2, P.W3, P.W4, P.W5, P.W6,
      (unsigned short*)wf, (unsigned short*)(wf + 327680));
  fused_kernel<<<dim3(nbP + nbBC), dim3(512), 0, stream>>>(P, nbP);
  reduce_kernel<<<dim3(1), dim3(256), 0, stream>>>(P.wsBC, P.wsDA, P.wsF,
                                                   (float*)d_out, nbBC, nbP);
}